// Round 3
// 1156.234 us; speedup vs baseline: 1.0439x; 1.0439x over previous
//
#include <hip/hip_runtime.h>
#include <hip/hip_bf16.h>

typedef __hip_bfloat16 bf16;
typedef __attribute__((ext_vector_type(8))) short short8;
typedef __attribute__((ext_vector_type(4))) float f32x4;

constexpr int kHW = 96 * 96;   // 9216

__device__ __forceinline__ float b2f(bf16 x){ return __bfloat162float(x); }
__device__ __forceinline__ bf16  f2b(float x){ return __float2bfloat16(x); }

// ---------------------------------------------------------------------------
// zero s1/s2 (1024 contiguous floats)
__global__ void k_zero(float* __restrict__ p){
  int i = blockIdx.x*256 + threadIdx.x;
  if (i < 1024) p[i] = 0.0f;
}

// fp32 -> bf16 weight conversion
__global__ void k_cvt(const float* __restrict__ s, bf16* __restrict__ d, int n){
  int i = blockIdx.x*256 + threadIdx.x;
  if (i < n) d[i] = f2b(s[i]);
}

// ---------------------------------------------------------------------------
// bilinear 2x upsample: high (b,512,48,48) fp32 -> hf_t (b, x96*96+y, c512) bf16
// grid (y=96, b=8), 256 thr
__global__ __launch_bounds__(256) void k_upsample(const float* __restrict__ hi,
                                                  bf16* __restrict__ hf_t){
  int y = blockIdx.x, b = blockIdx.y, t = threadIdx.x;
  int j = y >> 1;
  int j0, j1; float wy0, wy1;
  if ((y & 1) == 0){ j0 = j - 1; if (j0 < 0) j0 = 0; j1 = j; wy0 = 0.25f; wy1 = 0.75f; }
  else             { j0 = j; j1 = j + 1; if (j1 > 47) j1 = 47; wy0 = 0.75f; wy1 = 0.25f; }
  __shared__ __align__(16) float sm[2][128][49];
  for (int c0 = 0; c0 < 512; c0 += 128){
    for (int e = t; e < 2*128*48; e += 256){
      int cl = e / 96; int r = e % 96; int jj = r / 48; int i = r % 48;
      int row = jj ? j1 : j0;
      sm[jj][cl][i] = hi[(((size_t)b*512 + c0 + cl)*48 + row)*48 + i];
    }
    __syncthreads();
    for (int e = t; e < 96*128; e += 256){
      int x = e >> 7; int cl = e & 127;
      int i = x >> 1; int i0, i1; float wx0, wx1;
      if ((x & 1) == 0){ i0 = i - 1; if (i0 < 0) i0 = 0; i1 = i; wx0 = 0.25f; wx1 = 0.75f; }
      else             { i0 = i; i1 = i + 1; if (i1 > 47) i1 = 47; wx0 = 0.75f; wx1 = 0.25f; }
      float v = wy0*(wx0*sm[0][cl][i0] + wx1*sm[0][cl][i1])
              + wy1*(wx0*sm[1][cl][i0] + wx1*sm[1][cl][i1]);
      hf_t[(((size_t)b*96 + x)*96 + y)*512 + c0 + cl] = f2b(v);
    }
    __syncthreads();
  }
}

// ---------------------------------------------------------------------------
// fold q path: qq_w[o,c] = sum_k q_w[o,k]*conv1_w[k,c]  (32x512, fp32)
__global__ void k_qqw(const float* __restrict__ q_w, const float* __restrict__ c1_w,
                      float* __restrict__ qq_w){
  int gid = blockIdx.x*256 + threadIdx.x;      // 16384
  int o = gid >> 9, c = gid & 511;
  float acc = 0.f;
  for (int k = 0; k < 256; k++) acc += q_w[o*256 + k] * c1_w[k*512 + c];
  qq_w[gid] = acc;
}
__global__ void k_qqb(const float* __restrict__ q_w, const float* __restrict__ c1_b,
                      const float* __restrict__ q_b, float* __restrict__ qq_b){
  int o = threadIdx.x; if (o >= 32) return;
  float acc = q_b[o];
  for (int k = 0; k < 256; k++) acc += q_w[o*256 + k] * c1_b[k];
  qq_b[o] = acc;
}

// ---------------------------------------------------------------------------
// MFMA GEMM: out[b,n,o] = sum_k A[b,n,k]*Wb[o,k] (+bias[o])
// A bf16 (b,9216,K) row-major; Wb bf16 (O,K); out bf16 (b,9216,O)
// 128x128 block tile, 4 waves of 64x64 (4x4 16x16x32 mfma tiles), BK=32
__global__ __launch_bounds__(256) void k_mfma_gemm(const bf16* __restrict__ A,
                                                   const bf16* __restrict__ Wb,
                                                   const float* __restrict__ bias,
                                                   bf16* __restrict__ out,
                                                   int K, int O){
  int b = blockIdx.z, n0 = blockIdx.x*128, o0 = blockIdx.y*128;
  int t = threadIdx.x, lane = t & 63, wv = t >> 6;
  int m_off = (wv & 1)*64, o_off = (wv >> 1)*64;
  int lm = lane & 15, lk = lane >> 4;
  __shared__ __align__(16) bf16 As[128*40];
  __shared__ __align__(16) bf16 Ws[128*40];
  f32x4 acc[4][4] = {};
  const bf16* Ab = A + (size_t)b*kHW*K;
  for (int c0 = 0; c0 < K; c0 += 32){
    for (int e = t; e < 512; e += 256){
      int nl = e >> 2, p = e & 3;
      *(uint4*)&As[nl*40 + p*8] = *(const uint4*)&Ab[(size_t)(n0+nl)*K + c0 + p*8];
    }
    for (int e = t; e < 512; e += 256){
      int ol = e >> 2, p = e & 3;
      *(uint4*)&Ws[ol*40 + p*8] = *(const uint4*)&Wb[(size_t)(o0+ol)*K + c0 + p*8];
    }
    __syncthreads();
    short8 af[4], bfr[4];
    #pragma unroll
    for (int i = 0; i < 4; i++){
      af[i]  = *(const short8*)&As[(m_off + i*16 + lm)*40 + lk*8];
      bfr[i] = *(const short8*)&Ws[(o_off + i*16 + lm)*40 + lk*8];
    }
    #pragma unroll
    for (int i = 0; i < 4; i++)
      #pragma unroll
      for (int j = 0; j < 4; j++)
        acc[i][j] = __builtin_amdgcn_mfma_f32_16x16x32_bf16(af[i], bfr[j], acc[i][j], 0, 0, 0);
    __syncthreads();
  }
  #pragma unroll
  for (int j = 0; j < 4; j++){
    int oc = o0 + o_off + j*16 + lm;
    float bs = bias ? bias[oc] : 0.0f;
    #pragma unroll
    for (int i = 0; i < 4; i++){
      int rbase = n0 + m_off + i*16 + lk*4;
      #pragma unroll
      for (int r = 0; r < 4; r++)
        out[((size_t)b*kHW + rbase + r)*(size_t)O + oc] = f2b(acc[i][j][r] + bs);
    }
  }
}

// bottleneck MFMA: K=768 split A-source (k<256: vf_t stride 256; k>=256: hf_t stride 512)
__global__ __launch_bounds__(256) void k_bneck_mfma(const bf16* __restrict__ vf,
                                                    const bf16* __restrict__ hf,
                                                    const bf16* __restrict__ Wb,
                                                    bf16* __restrict__ out){
  int b = blockIdx.z, n0 = blockIdx.x*128, o0 = blockIdx.y*128;
  int t = threadIdx.x, lane = t & 63, wv = t >> 6;
  int m_off = (wv & 1)*64, o_off = (wv >> 1)*64;
  int lm = lane & 15, lk = lane >> 4;
  __shared__ __align__(16) bf16 As[128*40];
  __shared__ __align__(16) bf16 Ws[128*40];
  f32x4 acc[4][4] = {};
  for (int c0 = 0; c0 < 768; c0 += 32){
    const bf16* src; int strd, cc;
    if (c0 < 256){ src = vf + (size_t)b*kHW*256; strd = 256; cc = c0; }
    else         { src = hf + (size_t)b*kHW*512; strd = 512; cc = c0 - 256; }
    for (int e = t; e < 512; e += 256){
      int nl = e >> 2, p = e & 3;
      *(uint4*)&As[nl*40 + p*8] = *(const uint4*)&src[(size_t)(n0+nl)*strd + cc + p*8];
    }
    for (int e = t; e < 512; e += 256){
      int ol = e >> 2, p = e & 3;
      *(uint4*)&Ws[ol*40 + p*8] = *(const uint4*)&Wb[(size_t)(o0+ol)*768 + c0 + p*8];
    }
    __syncthreads();
    short8 af[4], bfr[4];
    #pragma unroll
    for (int i = 0; i < 4; i++){
      af[i]  = *(const short8*)&As[(m_off + i*16 + lm)*40 + lk*8];
      bfr[i] = *(const short8*)&Ws[(o_off + i*16 + lm)*40 + lk*8];
    }
    #pragma unroll
    for (int i = 0; i < 4; i++)
      #pragma unroll
      for (int j = 0; j < 4; j++)
        acc[i][j] = __builtin_amdgcn_mfma_f32_16x16x32_bf16(af[i], bfr[j], acc[i][j], 0, 0, 0);
    __syncthreads();
  }
  #pragma unroll
  for (int j = 0; j < 4; j++){
    int oc = o0 + o_off + j*16 + lm;
    #pragma unroll
    for (int i = 0; i < 4; i++){
      int rbase = n0 + m_off + i*16 + lk*4;
      #pragma unroll
      for (int r = 0; r < 4; r++)
        out[((size_t)b*kHW + rbase + r)*512 + oc] = f2b(acc[i][j][r]);
    }
  }
}

// per-channel sum/sumsq over bt (b,9216,512); grid (36, 8), 256 rows/block
__global__ __launch_bounds__(256) void k_stats(const bf16* __restrict__ bt,
                                               float* __restrict__ s1,
                                               float* __restrict__ s2){
  int n0 = blockIdx.x*256, b = blockIdx.y, t = threadIdx.x;
  __shared__ float l1[512];
  __shared__ float l2[512];
  for (int e = t; e < 512; e += 256){ l1[e] = 0.f; l2[e] = 0.f; }
  __syncthreads();
  int og = (t & 63)*8;
  int r0 = t >> 6;
  float a1[8] = {}, a2[8] = {};
  for (int r = r0; r < 256; r += 4){
    const bf16* p = bt + ((size_t)b*kHW + n0 + r)*512 + og;
    uint4 d = *(const uint4*)p;
    const unsigned short* us = (const unsigned short*)&d;
    #pragma unroll
    for (int j = 0; j < 8; j++){
      float v = __uint_as_float(((unsigned)us[j]) << 16);
      a1[j] += v; a2[j] += v*v;
    }
  }
  #pragma unroll
  for (int j = 0; j < 8; j++){
    atomicAdd(&l1[og + j], a1[j]);
    atomicAdd(&l2[og + j], a2[j]);
  }
  __syncthreads();
  for (int e = t; e < 512; e += 256){
    atomicAdd(&s1[e], l1[e]);
    atomicAdd(&s2[e], l2[e]);
  }
}

// ---------------------------------------------------------------------------
// q directly from low (NCHW fp32): q_t[b,x,h,32] bf16 ; grid (96 h, 8 b)
__global__ __launch_bounds__(256) void k_qlow(const float* __restrict__ low,
                                              const float* __restrict__ qq_w,
                                              const float* __restrict__ qq_b,
                                              bf16* __restrict__ q_t){
  int h = blockIdx.x, b = blockIdx.y, t = threadIdx.x;
  int tw = t % 32, to = t / 32;
  __shared__ __align__(16) float Al[64][98];
  __shared__ __align__(16) float Wl[64][36];
  float acc[3][4] = {};
  for (int c0 = 0; c0 < 512; c0 += 64){
    for (int e = t; e < 64*96; e += 256){
      int cl = e / 96, x = e % 96;
      Al[cl][x] = low[(((size_t)b*512 + c0 + cl)*96 + h)*96 + x];
    }
    for (int e = t; e < 32*64; e += 256){
      int o = e >> 6, k = e & 63;
      Wl[k][o] = qq_w[(size_t)o*512 + c0 + k];
    }
    __syncthreads();
    #pragma unroll 4
    for (int k = 0; k < 64; k++){
      float a_[3];
      #pragma unroll
      for (int i = 0; i < 3; i++) a_[i] = Al[k][tw*3 + i];
      float4 wv = *(const float4*)&Wl[k][to*4];
      float w_[4] = {wv.x, wv.y, wv.z, wv.w};
      #pragma unroll
      for (int i = 0; i < 3; i++)
        #pragma unroll
        for (int jj = 0; jj < 4; jj++) acc[i][jj] += a_[i]*w_[jj];
    }
    __syncthreads();
  }
  #pragma unroll
  for (int i = 0; i < 3; i++){
    int x = tw*3 + i;
    size_t base = (((size_t)b*96 + x)*96 + h)*32 + to*4;
    #pragma unroll
    for (int jj = 0; jj < 4; jj++) q_t[base + jj] = f2b(acc[i][jj] + qq_b[to*4 + jj]);
  }
}

// bf16-A (n,c) @ fp32-W (o,c)^T + fp32 bias -> bf16 (small-O path, used for k)
template<int BN, int OT>
__global__ __launch_bounds__(256) void k_gemm_bb(const bf16* __restrict__ A,
                                                 const float* __restrict__ Wt,
                                                 const float* __restrict__ bias,
                                                 bf16* __restrict__ out,
                                                 int Cin, int O){
  constexpr int TN = BN/4;
  int b = blockIdx.z, n0 = blockIdx.x*BN, o0 = blockIdx.y*OT, t = threadIdx.x;
  int tn = t % TN, to = t / TN;
  __shared__ __align__(16) float As[32][BN+4];
  __shared__ __align__(16) float Ws[32][OT+4];
  float acc[4][4] = {};
  const bf16* Ab = A + (size_t)b*kHW*Cin;
  for (int c0 = 0; c0 < Cin; c0 += 32){
    for (int e = t; e < BN*32; e += 256){
      int nl = e >> 5, kk = e & 31;
      As[kk][nl] = b2f(Ab[(size_t)(n0+nl)*Cin + c0 + kk]);
    }
    for (int e = t; e < OT*32; e += 256){
      int ol = e >> 5, kk = e & 31;
      Ws[kk][ol] = Wt[(size_t)(o0+ol)*Cin + c0 + kk];
    }
    __syncthreads();
    #pragma unroll
    for (int kk = 0; kk < 32; kk++){
      float4 av = *(const float4*)&As[kk][tn*4];
      float4 wv = *(const float4*)&Ws[kk][to*4];
      float a_[4] = {av.x, av.y, av.z, av.w};
      float w_[4] = {wv.x, wv.y, wv.z, wv.w};
      #pragma unroll
      for (int i = 0; i < 4; i++)
        #pragma unroll
        for (int jj = 0; jj < 4; jj++) acc[i][jj] += a_[i]*w_[jj];
    }
    __syncthreads();
  }
  #pragma unroll
  for (int i = 0; i < 4; i++){
    size_t base = ((size_t)b*kHW + n0 + tn*4 + i)*(size_t)O + o0 + to*4;
    #pragma unroll
    for (int jj = 0; jj < 4; jj++) out[base + jj] = f2b(acc[i][jj] + bias[o0 + to*4 + jj]);
  }
}

// ---------------------------------------------------------------------------
// eH: att[b,h,w,j] = sum_c q_t[b,w,h,c]*k_t[b,w,j,c]  (-1e9 if j==h); grid (96 w, 8 b)
__global__ __launch_bounds__(256) void k_eH(const bf16* __restrict__ q_t,
                                            const bf16* __restrict__ k_t,
                                            bf16* __restrict__ att){
  int w = blockIdx.x, b = blockIdx.y, t = threadIdx.x;
  __shared__ float Qs[96][33];
  __shared__ float Ks[96][33];
  const bf16* Qp = q_t + (((size_t)b*96 + w)*96)*32;
  const bf16* Kp = k_t + (((size_t)b*96 + w)*96)*32;
  for (int e = t; e < 3072; e += 256){ Qs[e>>5][e&31] = b2f(Qp[e]); Ks[e>>5][e&31] = b2f(Kp[e]); }
  __syncthreads();
  int tj = t % 16, th = t / 16;
  float acc[6][6] = {};
  #pragma unroll 4
  for (int c = 0; c < 32; c++){
    float qa[6], kb[6];
    #pragma unroll
    for (int i = 0; i < 6; i++) qa[i] = Qs[th*6 + i][c];
    #pragma unroll
    for (int jj = 0; jj < 6; jj++) kb[jj] = Ks[tj*6 + jj][c];
    #pragma unroll
    for (int i = 0; i < 6; i++)
      #pragma unroll
      for (int jj = 0; jj < 6; jj++) acc[i][jj] += qa[i]*kb[jj];
  }
  #pragma unroll
  for (int i = 0; i < 6; i++){
    int h = th*6 + i;
    size_t base = (((size_t)b*96 + h)*96 + w)*192;
    #pragma unroll
    for (int jj = 0; jj < 6; jj++){
      int jg = tj*6 + jj;
      float e = acc[i][jj];
      if (jg == h) e += -1000000000.0f;
      att[base + jg] = f2b(e);
    }
  }
}

// eW: att[b,h,w,96+j] = sum_c q_t[b,w,h,c]*k_t[b,j,h,c]; grid (96 h, 8 b)
__global__ __launch_bounds__(256) void k_eW(const bf16* __restrict__ q_t,
                                            const bf16* __restrict__ k_t,
                                            bf16* __restrict__ att){
  int h = blockIdx.x, b = blockIdx.y, t = threadIdx.x;
  __shared__ float Qs[96][33];
  __shared__ float Ks[96][33];
  for (int e = t; e < 3072; e += 256){
    int wl = e >> 5, c = e & 31;
    size_t idx = (((size_t)b*96 + wl)*96 + h)*32 + c;
    Qs[wl][c] = b2f(q_t[idx]);
    Ks[wl][c] = b2f(k_t[idx]);
  }
  __syncthreads();
  int tj = t % 16, tw = t / 16;
  float acc[6][6] = {};
  #pragma unroll 4
  for (int c = 0; c < 32; c++){
    float qa[6], kb[6];
    #pragma unroll
    for (int i = 0; i < 6; i++) qa[i] = Qs[tw*6 + i][c];
    #pragma unroll
    for (int jj = 0; jj < 6; jj++) kb[jj] = Ks[tj*6 + jj][c];
    #pragma unroll
    for (int i = 0; i < 6; i++)
      #pragma unroll
      for (int jj = 0; jj < 6; jj++) acc[i][jj] += qa[i]*kb[jj];
  }
  #pragma unroll
  for (int i = 0; i < 6; i++){
    int wl = tw*6 + i;
    size_t base = (((size_t)b*96 + h)*96 + wl)*192 + 96;
    #pragma unroll
    for (int jj = 0; jj < 6; jj++) att[base + tj*6 + jj] = f2b(acc[i][jj]);
  }
}

// softmax over 192, one wave per row; grid 18432
__global__ __launch_bounds__(256) void k_softmax(bf16* __restrict__ att){
  int t = threadIdx.x;
  int row = blockIdx.x*4 + (t >> 6);
  int lane = t & 63;
  size_t base = (size_t)row * 192;
  float x0 = b2f(att[base + lane]);
  float x1 = b2f(att[base + 64 + lane]);
  float x2 = b2f(att[base + 128 + lane]);
  float m = fmaxf(x0, fmaxf(x1, x2));
  #pragma unroll
  for (int off = 32; off; off >>= 1) m = fmaxf(m, __shfl_xor(m, off));
  float e0 = __expf(x0 - m), e1 = __expf(x1 - m), e2 = __expf(x2 - m);
  float s = e0 + e1 + e2;
  #pragma unroll
  for (int off = 32; off; off >>= 1) s += __shfl_xor(s, off);
  float inv = 1.0f / s;
  att[base + lane]       = f2b(e0 * inv);
  att[base + 64 + lane]  = f2b(e1 * inv);
  att[base + 128 + lane] = f2b(e2 * inv);
}

// ---------------------------------------------------------------------------
// outH via MFMA: accb[b,w,h,c] = sum_j att[b,h,w,j]*v_t[b,w,j,c]; grid (96 w, 8 b)
// per block: out 96(h) x 256(c), K=96(j). 4 waves: (wv&1)->h half (48), (wv>>1)->c half (128).
// LDS: As[96][36] att tile (j contig); Vt[256][36] = V^T tile (transposed during staging).
__global__ __launch_bounds__(256) void k_outH_mfma(const bf16* __restrict__ att,
                                                   const bf16* __restrict__ v_t,
                                                   bf16* __restrict__ accb){
  int w = blockIdx.x, b = blockIdx.y, t = threadIdx.x;
  int lane = t & 63, wv = t >> 6;
  int m_off = (wv & 1)*48, o_off = (wv >> 1)*128;
  int lm = lane & 15, lk = lane >> 4;
  __shared__ __align__(16) bf16 As[96*36];
  __shared__ __align__(16) bf16 Vt[256*36];
  f32x4 acc[3][8] = {};
  const bf16* Vb = v_t + ((size_t)b*96 + w)*96*256;
  for (int j0 = 0; j0 < 96; j0 += 32){
    // att tile: rows h (global stride 96*192), 32 j's contiguous
    for (int e = t; e < 384; e += 256){
      int h = e >> 2, p = e & 3;
      *(uint4*)&As[h*36 + p*8] =
        *(const uint4*)&att[(((size_t)b*96 + h)*96 + w)*192 + j0 + p*8];
    }
    // V^T tile: read 2 j-rows coalesced, write ushort2 pairs (2-way conflicts = free)
    for (int e = t; e < 512; e += 256){
      int jj2 = (e & 15)*2, cg = e >> 4;   // cg 0..31 (8 c's each)
      const bf16* p = Vb + (size_t)(j0 + jj2)*256 + cg*8;
      uint4 a0 = *(const uint4*)p;
      uint4 a1 = *(const uint4*)(p + 256);
      const unsigned short* u0 = (const unsigned short*)&a0;
      const unsigned short* u1 = (const unsigned short*)&a1;
      #pragma unroll
      for (int u = 0; u < 8; u++){
        ushort2 pr; pr.x = u0[u]; pr.y = u1[u];
        *(ushort2*)&Vt[(cg*8 + u)*36 + jj2] = pr;
      }
    }
    __syncthreads();
    short8 af[3], bfr[8];
    #pragma unroll
    for (int i = 0; i < 3; i++)
      af[i] = *(const short8*)&As[(m_off + i*16 + lm)*36 + lk*8];
    #pragma unroll
    for (int j = 0; j < 8; j++)
      bfr[j] = *(const short8*)&Vt[(o_off + j*16 + lm)*36 + lk*8];
    #pragma unroll
    for (int i = 0; i < 3; i++)
      #pragma unroll
      for (int j = 0; j < 8; j++)
        acc[i][j] = __builtin_amdgcn_mfma_f32_16x16x32_bf16(af[i], bfr[j], acc[i][j], 0, 0, 0);
    __syncthreads();
  }
  #pragma unroll
  for (int j = 0; j < 8; j++){
    int c = o_off + j*16 + lm;
    #pragma unroll
    for (int i = 0; i < 3; i++){
      int hbase = m_off + i*16 + lk*4;
      #pragma unroll
      for (int r = 0; r < 4; r++)
        accb[(((size_t)b*96 + w)*96 + hbase + r)*256 + c] = f2b(acc[i][j][r]);
    }
  }
}

// outW via MFMA + residual: vf_t[b,w,h,c] += g*(accb[b,w,h,c] + sum_j attW[h,w,j]*v_t[b,j,h,c])
// grid (96 h, 8 b). out 96(w) x 256(c), K=96(j).
__global__ __launch_bounds__(256) void k_outW_mfma(const bf16* __restrict__ att,
                                                   const bf16* __restrict__ v_t,
                                                   const bf16* __restrict__ accb,
                                                   const float* __restrict__ gamma_p,
                                                   bf16* __restrict__ vf_t){
  int h = blockIdx.x, b = blockIdx.y, t = threadIdx.x;
  int lane = t & 63, wv = t >> 6;
  int m_off = (wv & 1)*48, o_off = (wv >> 1)*128;
  int lm = lane & 15, lk = lane >> 4;
  __shared__ __align__(16) bf16 As[96*36];
  __shared__ __align__(16) bf16 Vt[256*36];
  f32x4 acc[3][8] = {};
  for (int j0 = 0; j0 < 96; j0 += 32){
    // attW tile: rows w' (global stride 192), +96 offset, 32 j's contiguous
    for (int e = t; e < 384; e += 256){
      int wl = e >> 2, p = e & 3;
      *(uint4*)&As[wl*36 + p*8] =
        *(const uint4*)&att[(((size_t)b*96 + h)*96 + wl)*192 + 96 + j0 + p*8];
    }
    // V2^T tile: V2[j,c] = v_t[((b*96+j)*96+h)*256 + c], j-rows stride 96*256
    for (int e = t; e < 512; e += 256){
      int jj2 = (e & 15)*2, cg = e >> 4;
      const bf16* p = v_t + (((size_t)b*96 + j0 + jj2)*96 + h)*256 + cg*8;
      uint4 a0 = *(const uint4*)p;
      uint4 a1 = *(const uint4*)(p + 96*256);
      const unsigned short* u0 = (const unsigned short*)&a0;
      const unsigned short* u1 = (const unsigned short*)&a1;
      #pragma unroll
      for (int u = 0; u < 8; u++){
        ushort2 pr; pr.x = u0[u]; pr.y = u1[u];
        *(ushort2*)&Vt[(cg*8 + u)*36 + jj2] = pr;
      }
    }
    __syncthreads();
    short8 af[3], bfr[8];
    #pragma unroll
    for (int i = 0; i < 3; i++)
      af[i] = *(const short8*)&As[(m_off + i*16 + lm)*36 + lk*8];
    #pragma unroll
    for (int j = 0; j < 8; j++)
      bfr[j] = *(const short8*)&Vt[(o_off + j*16 + lm)*36 + lk*8];
    #pragma unroll
    for (int i = 0; i < 3; i++)
      #pragma unroll
      for (int j = 0; j < 8; j++)
        acc[i][j] = __builtin_amdgcn_mfma_f32_16x16x32_bf16(af[i], bfr[j], acc[i][j], 0, 0, 0);
    __syncthreads();
  }
  float g = gamma_p[0];
  #pragma unroll
  for (int j = 0; j < 8; j++){
    int c = o_off + j*16 + lm;
    #pragma unroll
    for (int i = 0; i < 3; i++){
      int wbase = m_off + i*16 + lk*4;
      #pragma unroll
      for (int r = 0; r < 4; r++){
        size_t idx = (((size_t)b*96 + wbase + r)*96 + h)*256 + c;
        vf_t[idx] = f2b(b2f(vf_t[idx]) + g*(acc[i][j][r] + b2f(accb[idx])));
      }
    }
  }
}

// ---------------------------------------------------------------------------
__global__ void k_bnprep(const float* __restrict__ s1, const float* __restrict__ s2,
                         const float* __restrict__ sc, const float* __restrict__ bi,
                         float2* __restrict__ ab){
  int co = blockIdx.x*256 + threadIdx.x;
  if (co >= 512) return;
  const float N = 73728.0f;
  float mean = s1[co] / N;
  float var  = s2[co] / N - mean*mean;
  if (var < 0.f) var = 0.f;
  float a = rsqrtf(var + 1e-5f) * sc[co];
  ab[co] = make_float2(a, bi[co] - mean*a);
}

// BN + relu + transpose (b,w,h,co) -> (b,co,h,w) fp32; grid (3, 96, 8)
__global__ __launch_bounds__(256) void k_bnout(const bf16* __restrict__ bt,
                                               const float2* __restrict__ ab,
                                               float* __restrict__ out){
  int w0 = blockIdx.x*32, h = blockIdx.y, b = blockIdx.z, t = threadIdx.x;
  __shared__ float Tl[32][33];
  for (int co0 = 0; co0 < 512; co0 += 32){
    for (int e = t; e < 1024; e += 256){
      int wl = e >> 5, co = e & 31;
      Tl[wl][co] = b2f(bt[(((size_t)b*96 + w0 + wl)*96 + h)*512 + co0 + co]);
    }
    __syncthreads();
    for (int e = t; e < 1024; e += 256){
      int co = e >> 5, wl = e & 31;
      float2 s = ab[co0 + co];
      float v = fmaxf(Tl[wl][co]*s.x + s.y, 0.0f);
      out[(((size_t)b*512 + co0 + co)*96 + h)*96 + w0 + wl] = v;
    }
    __syncthreads();
  }
}

// ---------------------------------------------------------------------------
extern "C" void kernel_launch(void* const* d_in, const int* in_sizes, int n_in,
                              void* d_out, int out_size, void* d_ws, size_t ws_size,
                              hipStream_t stream){
  (void)in_sizes; (void)n_in; (void)out_size; (void)ws_size;
  const float* low   = (const float*)d_in[0];
  const float* high  = (const float*)d_in[1];
  const float* c1w   = (const float*)d_in[2];
  const float* c1b   = (const float*)d_in[3];
  const float* c2w   = (const float*)d_in[4];
  const float* c2b   = (const float*)d_in[5];
  const float* qw    = (const float*)d_in[6];
  const float* qb    = (const float*)d_in[7];
  const float* kw    = (const float*)d_in[8];
  const float* kb    = (const float*)d_in[9];
  const float* vw    = (const float*)d_in[10];
  const float* vb    = (const float*)d_in[11];
  const float* gamma = (const float*)d_in[12];
  const float* bw    = (const float*)d_in[13];
  const float* bns   = (const float*)d_in[14];
  const float* bnb   = (const float*)d_in[15];
  float* out = (float*)d_out;

  char* wsb = (char*)d_ws;
  // workspace layout — total 223,027,328 bytes (~212.7 MB)
  bf16*   hf_t = (bf16*) (wsb + 0);            // 75,497,472  (b, x*96+y, 512)
  bf16*   vf_t = (bf16*) (wsb + 75497472);     // 37,748,736  (b, x*96+y, 256)
  bf16*   q_t  = (bf16*) (wsb + 113246208);    //  4,718,592
  float*  qq_w = (float*)(wsb + 117964800);    //     65,536
  float*  qq_b = (float*)(wsb + 118030336);    //        128
  float*  s1   = (float*)(wsb + 118030464);    //      2,048
  float*  s2   = (float*)(wsb + 118032512);    //      2,048
  float2* ab   = (float2*)(wsb + 118034560);   //      4,096
  bf16*   wbb  = (bf16*) (wsb + 118038656);    //    786,432  (bneck W bf16, 512x768)
  bf16*   wc2  = (bf16*) (wsb + 118825088);    //    262,144  (conv2 W bf16, 256x512)
  bf16*   wv   = (bf16*) (wsb + 119087232);    //    131,072  (v W bf16, 256x256)
  bf16*   v_t  = (bf16*) (wsb + 119218304);    // 37,748,736
  bf16*   att  = (bf16*) (wsb + 156967040);    // 28,311,552
  bf16*   accb = (bf16*) (wsb + 185278592);    // 37,748,736 -> ends 223,027,328
  bf16*   k_t  = (bf16*) (wsb + 185278592);    //  4,718,592 (aliases accb head; dead before accb written)
  bf16*   bt   = (bf16*) (wsb + 119218304);    // 75,497,472 (aliases v_t/att/accb-head; all dead at bneck)

  k_zero<<<4, 256, 0, stream>>>(s1);
  k_cvt<<<1536, 256, 0, stream>>>(bw,  wbb, 393216);
  k_cvt<<<512,  256, 0, stream>>>(c2w, wc2, 131072);
  k_cvt<<<256,  256, 0, stream>>>(vw,  wv,  65536);
  k_upsample<<<dim3(96, 8), 256, 0, stream>>>(high, hf_t);
  k_qqw<<<64, 256, 0, stream>>>(qw, c1w, qq_w);
  k_qqb<<<1, 64, 0, stream>>>(qw, c1b, qb, qq_b);
  k_mfma_gemm<<<dim3(72, 2, 8), 256, 0, stream>>>(hf_t, wc2, c2b, vf_t, 512, 256);
  k_qlow<<<dim3(96, 8), 256, 0, stream>>>(low, qq_w, qq_b, q_t);

  for (int r = 0; r < 2; r++){
    k_gemm_bb<128, 32><<<dim3(72, 1, 8), 256, 0, stream>>>(vf_t, kw, kb, k_t, 256, 32);
    k_mfma_gemm<<<dim3(72, 2, 8), 256, 0, stream>>>(vf_t, wv, vb, v_t, 256, 256);
    k_eH<<<dim3(96, 8), 256, 0, stream>>>(q_t, k_t, att);
    k_eW<<<dim3(96, 8), 256, 0, stream>>>(q_t, k_t, att);
    k_softmax<<<18432, 256, 0, stream>>>(att);
    k_outH_mfma<<<dim3(96, 8), 256, 0, stream>>>(att, v_t, accb);
    k_outW_mfma<<<dim3(96, 8), 256, 0, stream>>>(att, v_t, accb, gamma, vf_t);
  }

  k_bneck_mfma<<<dim3(72, 4, 8), 256, 0, stream>>>(vf_t, hf_t, wbb, bt);
  k_stats<<<dim3(36, 8), 256, 0, stream>>>(bt, s1, s2);
  k_bnprep<<<2, 256, 0, stream>>>(s1, s2, bns, bnb, ab);
  k_bnout<<<dim3(3, 96, 8), 256, 0, stream>>>(bt, ab, out);
}

// Round 5
// 1063.376 us; speedup vs baseline: 1.1350x; 1.0873x over previous
//
#include <hip/hip_runtime.h>
#include <hip/hip_bf16.h>

typedef __hip_bfloat16 bf16;
typedef __attribute__((ext_vector_type(8))) short short8;
typedef __attribute__((ext_vector_type(4))) float f32x4;

constexpr int kHW = 96 * 96;   // 9216

__device__ __forceinline__ float b2f(bf16 x){ return __bfloat162float(x); }
__device__ __forceinline__ bf16  f2b(float x){ return __float2bfloat16(x); }

// NOTE: __builtin_amdgcn_global_load_lds is permanently abandoned in this
// session: 3/3 container failures with it, 2/2 passes without.

// ---------------------------------------------------------------------------
// zero s1/s2 (1024 contiguous floats)
__global__ void k_zero(float* __restrict__ p){
  int i = blockIdx.x*256 + threadIdx.x;
  if (i < 1024) p[i] = 0.0f;
}

// fp32 -> bf16 weight conversion
__global__ void k_cvt(const float* __restrict__ s, bf16* __restrict__ d, int n){
  int i = blockIdx.x*256 + threadIdx.x;
  if (i < n) d[i] = f2b(s[i]);
}

// ---------------------------------------------------------------------------
// bilinear 2x upsample: high (b,512,48,48) fp32 -> hf_t (b, x96*96+y, c512) bf16
// grid (y=96, b=8), 256 thr
__global__ __launch_bounds__(256) void k_upsample(const float* __restrict__ hi,
                                                  bf16* __restrict__ hf_t){
  int y = blockIdx.x, b = blockIdx.y, t = threadIdx.x;
  int j = y >> 1;
  int j0, j1; float wy0, wy1;
  if ((y & 1) == 0){ j0 = j - 1; if (j0 < 0) j0 = 0; j1 = j; wy0 = 0.25f; wy1 = 0.75f; }
  else             { j0 = j; j1 = j + 1; if (j1 > 47) j1 = 47; wy0 = 0.75f; wy1 = 0.25f; }
  __shared__ __align__(16) float sm[2][128][49];
  for (int c0 = 0; c0 < 512; c0 += 128){
    for (int e = t; e < 2*128*48; e += 256){
      int cl = e / 96; int r = e % 96; int jj = r / 48; int i = r % 48;
      int row = jj ? j1 : j0;
      sm[jj][cl][i] = hi[(((size_t)b*512 + c0 + cl)*48 + row)*48 + i];
    }
    __syncthreads();
    for (int e = t; e < 96*128; e += 256){
      int x = e >> 7; int cl = e & 127;
      int i = x >> 1; int i0, i1; float wx0, wx1;
      if ((x & 1) == 0){ i0 = i - 1; if (i0 < 0) i0 = 0; i1 = i; wx0 = 0.25f; wx1 = 0.75f; }
      else             { i0 = i; i1 = i + 1; if (i1 > 47) i1 = 47; wx0 = 0.75f; wx1 = 0.25f; }
      float v = wy0*(wx0*sm[0][cl][i0] + wx1*sm[0][cl][i1])
              + wy1*(wx0*sm[1][cl][i0] + wx1*sm[1][cl][i1]);
      hf_t[(((size_t)b*96 + x)*96 + y)*512 + c0 + cl] = f2b(v);
    }
    __syncthreads();
  }
}

// ---------------------------------------------------------------------------
// fold q path: qq_w[o,c] = sum_k q_w[o,k]*conv1_w[k,c]  (32x512, fp32)
__global__ void k_qqw(const float* __restrict__ q_w, const float* __restrict__ c1_w,
                      float* __restrict__ qq_w){
  int gid = blockIdx.x*256 + threadIdx.x;      // 16384
  int o = gid >> 9, c = gid & 511;
  float acc = 0.f;
  for (int k = 0; k < 256; k++) acc += q_w[o*256 + k] * c1_w[k*512 + c];
  qq_w[gid] = acc;
}
__global__ void k_qqb(const float* __restrict__ q_w, const float* __restrict__ c1_b,
                      const float* __restrict__ q_b, float* __restrict__ qq_b){
  int o = threadIdx.x; if (o >= 32) return;
  float acc = q_b[o];
  for (int k = 0; k < 256; k++) acc += q_w[o*256 + k] * c1_b[k];
  qq_b[o] = acc;
}

// ---------------------------------------------------------------------------
// MFMA GEMM: out[b,n,o] = sum_k A[b,n,k]*Wb[o,k] (+bias[o])
// A bf16 (b,9216,K) row-major; Wb bf16 (O,K); out bf16 (b,9216,O)
// 128x128 block tile, 4 waves of 64x64 (4x4 16x16x32 mfma tiles), BK=32
// double-buffered LDS + register prefetch: one barrier per K-step, global
// load latency hidden under MFMA of the previous step.
__global__ __launch_bounds__(256) void k_mfma_gemm(const bf16* __restrict__ A,
                                                   const bf16* __restrict__ Wb,
                                                   const float* __restrict__ bias,
                                                   bf16* __restrict__ out,
                                                   int K, int O){
  int b = blockIdx.z, n0 = blockIdx.x*128, o0 = blockIdx.y*128;
  int t = threadIdx.x, lane = t & 63, wv = t >> 6;
  int m_off = (wv & 1)*64, o_off = (wv >> 1)*64;
  int lm = lane & 15, lk = lane >> 4;
  __shared__ __align__(16) bf16 As[2][128*40];
  __shared__ __align__(16) bf16 Ws[2][128*40];
  f32x4 acc[4][4] = {};
  const bf16* Ab = A + (size_t)b*kHW*K;
  int nl0 = t >> 2, p0 = (t & 3)*8;    // rows nl0, nl0+64; col offset p0
  uint4 pa0, pa1, pw0, pw1;
  // prologue: load + store K-step 0
  pa0 = *(const uint4*)&Ab[(size_t)(n0+nl0)*K + p0];
  pa1 = *(const uint4*)&Ab[(size_t)(n0+nl0+64)*K + p0];
  pw0 = *(const uint4*)&Wb[(size_t)(o0+nl0)*K + p0];
  pw1 = *(const uint4*)&Wb[(size_t)(o0+nl0+64)*K + p0];
  *(uint4*)&As[0][nl0*40 + p0]      = pa0;
  *(uint4*)&As[0][(nl0+64)*40 + p0] = pa1;
  *(uint4*)&Ws[0][nl0*40 + p0]      = pw0;
  *(uint4*)&Ws[0][(nl0+64)*40 + p0] = pw1;
  int cur = 0;
  int NS = K >> 5;
  for (int s = 0; s < NS; s++){
    if (s+1 < NS){
      int c0 = (s+1)*32;
      pa0 = *(const uint4*)&Ab[(size_t)(n0+nl0)*K + c0 + p0];
      pa1 = *(const uint4*)&Ab[(size_t)(n0+nl0+64)*K + c0 + p0];
      pw0 = *(const uint4*)&Wb[(size_t)(o0+nl0)*K + c0 + p0];
      pw1 = *(const uint4*)&Wb[(size_t)(o0+nl0+64)*K + c0 + p0];
    }
    __syncthreads();
    short8 af[4], bfr[4];
    #pragma unroll
    for (int i = 0; i < 4; i++){
      af[i]  = *(const short8*)&As[cur][(m_off + i*16 + lm)*40 + lk*8];
      bfr[i] = *(const short8*)&Ws[cur][(o_off + i*16 + lm)*40 + lk*8];
    }
    #pragma unroll
    for (int i = 0; i < 4; i++)
      #pragma unroll
      for (int j = 0; j < 4; j++)
        acc[i][j] = __builtin_amdgcn_mfma_f32_16x16x32_bf16(af[i], bfr[j], acc[i][j], 0, 0, 0);
    if (s+1 < NS){
      int nx = cur ^ 1;
      *(uint4*)&As[nx][nl0*40 + p0]      = pa0;
      *(uint4*)&As[nx][(nl0+64)*40 + p0] = pa1;
      *(uint4*)&Ws[nx][nl0*40 + p0]      = pw0;
      *(uint4*)&Ws[nx][(nl0+64)*40 + p0] = pw1;
      cur = nx;
    }
  }
  #pragma unroll
  for (int j = 0; j < 4; j++){
    int oc = o0 + o_off + j*16 + lm;
    float bs = bias ? bias[oc] : 0.0f;
    #pragma unroll
    for (int i = 0; i < 4; i++){
      int rbase = n0 + m_off + i*16 + lk*4;
      #pragma unroll
      for (int r = 0; r < 4; r++)
        out[((size_t)b*kHW + rbase + r)*(size_t)O + oc] = f2b(acc[i][j][r] + bs);
    }
  }
}

// bottleneck MFMA: K=768 split A-source (k<256: vf_t stride 256; k>=256: hf_t stride 512)
// double-buffered + register prefetch; fused per-channel sum/sumsq (BN stats)
__global__ __launch_bounds__(256) void k_bneck_mfma(const bf16* __restrict__ vf,
                                                    const bf16* __restrict__ hf,
                                                    const bf16* __restrict__ Wb,
                                                    bf16* __restrict__ out,
                                                    float* __restrict__ s1,
                                                    float* __restrict__ s2){
  int b = blockIdx.z, n0 = blockIdx.x*128, o0 = blockIdx.y*128;
  int t = threadIdx.x, lane = t & 63, wv = t >> 6;
  int m_off = (wv & 1)*64, o_off = (wv >> 1)*64;
  int lm = lane & 15, lk = lane >> 4;
  __shared__ __align__(16) bf16 As[2][128*40];
  __shared__ __align__(16) bf16 Ws[2][128*40];
  __shared__ float l1[128];
  __shared__ float l2[128];
  if (t < 128){ l1[t] = 0.f; l2[t] = 0.f; }
  f32x4 acc[4][4] = {};
  int nl0 = t >> 2, p0 = (t & 3)*8;
  const bf16* vfb = vf + (size_t)b*kHW*256;
  const bf16* hfb = hf + (size_t)b*kHW*512;
  uint4 pa0, pa1, pw0, pw1;
  // prologue c0 = 0 (vf source)
  pa0 = *(const uint4*)&vfb[(size_t)(n0+nl0)*256 + p0];
  pa1 = *(const uint4*)&vfb[(size_t)(n0+nl0+64)*256 + p0];
  pw0 = *(const uint4*)&Wb[(size_t)(o0+nl0)*768 + p0];
  pw1 = *(const uint4*)&Wb[(size_t)(o0+nl0+64)*768 + p0];
  *(uint4*)&As[0][nl0*40 + p0]      = pa0;
  *(uint4*)&As[0][(nl0+64)*40 + p0] = pa1;
  *(uint4*)&Ws[0][nl0*40 + p0]      = pw0;
  *(uint4*)&Ws[0][(nl0+64)*40 + p0] = pw1;
  int cur = 0;
  for (int s = 0; s < 24; s++){
    if (s+1 < 24){
      int c0 = (s+1)*32;
      if (c0 < 256){
        pa0 = *(const uint4*)&vfb[(size_t)(n0+nl0)*256 + c0 + p0];
        pa1 = *(const uint4*)&vfb[(size_t)(n0+nl0+64)*256 + c0 + p0];
      } else {
        int cc = c0 - 256;
        pa0 = *(const uint4*)&hfb[(size_t)(n0+nl0)*512 + cc + p0];
        pa1 = *(const uint4*)&hfb[(size_t)(n0+nl0+64)*512 + cc + p0];
      }
      pw0 = *(const uint4*)&Wb[(size_t)(o0+nl0)*768 + c0 + p0];
      pw1 = *(const uint4*)&Wb[(size_t)(o0+nl0+64)*768 + c0 + p0];
    }
    __syncthreads();
    short8 af[4], bfr[4];
    #pragma unroll
    for (int i = 0; i < 4; i++){
      af[i]  = *(const short8*)&As[cur][(m_off + i*16 + lm)*40 + lk*8];
      bfr[i] = *(const short8*)&Ws[cur][(o_off + i*16 + lm)*40 + lk*8];
    }
    #pragma unroll
    for (int i = 0; i < 4; i++)
      #pragma unroll
      for (int j = 0; j < 4; j++)
        acc[i][j] = __builtin_amdgcn_mfma_f32_16x16x32_bf16(af[i], bfr[j], acc[i][j], 0, 0, 0);
    if (s+1 < 24){
      int nx = cur ^ 1;
      *(uint4*)&As[nx][nl0*40 + p0]      = pa0;
      *(uint4*)&As[nx][(nl0+64)*40 + p0] = pa1;
      *(uint4*)&Ws[nx][nl0*40 + p0]      = pw0;
      *(uint4*)&Ws[nx][(nl0+64)*40 + p0] = pw1;
      cur = nx;
    }
  }
  // epilogue: C-write + fused BN stats (fp32, pre-rounding)
  #pragma unroll
  for (int j = 0; j < 4; j++){
    int oc = o0 + o_off + j*16 + lm;
    float p1 = 0.f, p2 = 0.f;
    #pragma unroll
    for (int i = 0; i < 4; i++){
      int rbase = n0 + m_off + i*16 + lk*4;
      #pragma unroll
      for (int r = 0; r < 4; r++){
        float v = acc[i][j][r];
        p1 += v; p2 += v*v;
        out[((size_t)b*kHW + rbase + r)*512 + oc] = f2b(v);
      }
    }
    int cl = o_off + j*16 + lm;          // local channel in [0,128)
    atomicAdd(&l1[cl], p1);
    atomicAdd(&l2[cl], p2);
  }
  __syncthreads();
  if (t < 128){
    atomicAdd(&s1[o0 + t], l1[t]);
    atomicAdd(&s2[o0 + t], l2[t]);
  }
}

// ---------------------------------------------------------------------------
// q directly from low (NCHW fp32): q_t[b,x,h,32] bf16 ; grid (96 h, 8 b)
__global__ __launch_bounds__(256) void k_qlow(const float* __restrict__ low,
                                              const float* __restrict__ qq_w,
                                              const float* __restrict__ qq_b,
                                              bf16* __restrict__ q_t){
  int h = blockIdx.x, b = blockIdx.y, t = threadIdx.x;
  int tw = t % 32, to = t / 32;
  __shared__ __align__(16) float Al[64][98];
  __shared__ __align__(16) float Wl[64][36];
  float acc[3][4] = {};
  for (int c0 = 0; c0 < 512; c0 += 64){
    for (int e = t; e < 64*96; e += 256){
      int cl = e / 96, x = e % 96;
      Al[cl][x] = low[(((size_t)b*512 + c0 + cl)*96 + h)*96 + x];
    }
    for (int e = t; e < 32*64; e += 256){
      int o = e >> 6, k = e & 63;
      Wl[k][o] = qq_w[(size_t)o*512 + c0 + k];
    }
    __syncthreads();
    #pragma unroll 4
    for (int k = 0; k < 64; k++){
      float a_[3];
      #pragma unroll
      for (int i = 0; i < 3; i++) a_[i] = Al[k][tw*3 + i];
      float4 wv = *(const float4*)&Wl[k][to*4];
      float w_[4] = {wv.x, wv.y, wv.z, wv.w};
      #pragma unroll
      for (int i = 0; i < 3; i++)
        #pragma unroll
        for (int jj = 0; jj < 4; jj++) acc[i][jj] += a_[i]*w_[jj];
    }
    __syncthreads();
  }
  #pragma unroll
  for (int i = 0; i < 3; i++){
    int x = tw*3 + i;
    size_t base = (((size_t)b*96 + x)*96 + h)*32 + to*4;
    #pragma unroll
    for (int jj = 0; jj < 4; jj++) q_t[base + jj] = f2b(acc[i][jj] + qq_b[to*4 + jj]);
  }
}

// bf16-A (n,c) @ fp32-W (o,c)^T + fp32 bias -> bf16 (small-O path, used for k)
template<int BN, int OT>
__global__ __launch_bounds__(256) void k_gemm_bb(const bf16* __restrict__ A,
                                                 const float* __restrict__ Wt,
                                                 const float* __restrict__ bias,
                                                 bf16* __restrict__ out,
                                                 int Cin, int O){
  constexpr int TN = BN/4;
  int b = blockIdx.z, n0 = blockIdx.x*BN, o0 = blockIdx.y*OT, t = threadIdx.x;
  int tn = t % TN, to = t / TN;
  __shared__ __align__(16) float As[32][BN+4];
  __shared__ __align__(16) float Ws[32][OT+4];
  float acc[4][4] = {};
  const bf16* Ab = A + (size_t)b*kHW*Cin;
  for (int c0 = 0; c0 < Cin; c0 += 32){
    for (int e = t; e < BN*32; e += 256){
      int nl = e >> 5, kk = e & 31;
      As[kk][nl] = b2f(Ab[(size_t)(n0+nl)*Cin + c0 + kk]);
    }
    for (int e = t; e < OT*32; e += 256){
      int ol = e >> 5, kk = e & 31;
      Ws[kk][ol] = Wt[(size_t)(o0+ol)*Cin + c0 + kk];
    }
    __syncthreads();
    #pragma unroll
    for (int kk = 0; kk < 32; kk++){
      float4 av = *(const float4*)&As[kk][tn*4];
      float4 wv = *(const float4*)&Ws[kk][to*4];
      float a_[4] = {av.x, av.y, av.z, av.w};
      float w_[4] = {wv.x, wv.y, wv.z, wv.w};
      #pragma unroll
      for (int i = 0; i < 4; i++)
        #pragma unroll
        for (int jj = 0; jj < 4; jj++) acc[i][jj] += a_[i]*w_[jj];
    }
    __syncthreads();
  }
  #pragma unroll
  for (int i = 0; i < 4; i++){
    size_t base = ((size_t)b*kHW + n0 + tn*4 + i)*(size_t)O + o0 + to*4;
    #pragma unroll
    for (int jj = 0; jj < 4; jj++) out[base + jj] = f2b(acc[i][jj] + bias[o0 + to*4 + jj]);
  }
}

// ---------------------------------------------------------------------------
// eH: att[b,h,w,j] = sum_c q_t[b,w,h,c]*k_t[b,w,j,c]  (-1e9 if j==h); grid (96 w, 8 b)
__global__ __launch_bounds__(256) void k_eH(const bf16* __restrict__ q_t,
                                            const bf16* __restrict__ k_t,
                                            bf16* __restrict__ att){
  int w = blockIdx.x, b = blockIdx.y, t = threadIdx.x;
  __shared__ float Qs[96][33];
  __shared__ float Ks[96][33];
  const bf16* Qp = q_t + (((size_t)b*96 + w)*96)*32;
  const bf16* Kp = k_t + (((size_t)b*96 + w)*96)*32;
  for (int e = t; e < 3072; e += 256){ Qs[e>>5][e&31] = b2f(Qp[e]); Ks[e>>5][e&31] = b2f(Kp[e]); }
  __syncthreads();
  int tj = t % 16, th = t / 16;
  float acc[6][6] = {};
  #pragma unroll 4
  for (int c = 0; c < 32; c++){
    float qa[6], kb[6];
    #pragma unroll
    for (int i = 0; i < 6; i++) qa[i] = Qs[th*6 + i][c];
    #pragma unroll
    for (int jj = 0; jj < 6; jj++) kb[jj] = Ks[tj*6 + jj][c];
    #pragma unroll
    for (int i = 0; i < 6; i++)
      #pragma unroll
      for (int jj = 0; jj < 6; jj++) acc[i][jj] += qa[i]*kb[jj];
  }
  #pragma unroll
  for (int i = 0; i < 6; i++){
    int h = th*6 + i;
    size_t base = (((size_t)b*96 + h)*96 + w)*192;
    #pragma unroll
    for (int jj = 0; jj < 6; jj++){
      int jg = tj*6 + jj;
      float e = acc[i][jj];
      if (jg == h) e += -1000000000.0f;
      att[base + jg] = f2b(e);
    }
  }
}

// eW: att[b,h,w,96+j] = sum_c q_t[b,w,h,c]*k_t[b,j,h,c]; grid (96 h, 8 b)
__global__ __launch_bounds__(256) void k_eW(const bf16* __restrict__ q_t,
                                            const bf16* __restrict__ k_t,
                                            bf16* __restrict__ att){
  int h = blockIdx.x, b = blockIdx.y, t = threadIdx.x;
  __shared__ float Qs[96][33];
  __shared__ float Ks[96][33];
  for (int e = t; e < 3072; e += 256){
    int wl = e >> 5, c = e & 31;
    size_t idx = (((size_t)b*96 + wl)*96 + h)*32 + c;
    Qs[wl][c] = b2f(q_t[idx]);
    Ks[wl][c] = b2f(k_t[idx]);
  }
  __syncthreads();
  int tj = t % 16, tw = t / 16;
  float acc[6][6] = {};
  #pragma unroll 4
  for (int c = 0; c < 32; c++){
    float qa[6], kb[6];
    #pragma unroll
    for (int i = 0; i < 6; i++) qa[i] = Qs[tw*6 + i][c];
    #pragma unroll
    for (int jj = 0; jj < 6; jj++) kb[jj] = Ks[tj*6 + jj][c];
    #pragma unroll
    for (int i = 0; i < 6; i++)
      #pragma unroll
      for (int jj = 0; jj < 6; jj++) acc[i][jj] += qa[i]*kb[jj];
  }
  #pragma unroll
  for (int i = 0; i < 6; i++){
    int wl = tw*6 + i;
    size_t base = (((size_t)b*96 + h)*96 + wl)*192 + 96;
    #pragma unroll
    for (int jj = 0; jj < 6; jj++) att[base + tj*6 + jj] = f2b(acc[i][jj]);
  }
}

// softmax over 192, one wave per row; grid 18432
__global__ __launch_bounds__(256) void k_softmax(bf16* __restrict__ att){
  int t = threadIdx.x;
  int row = blockIdx.x*4 + (t >> 6);
  int lane = t & 63;
  size_t base = (size_t)row * 192;
  float x0 = b2f(att[base + lane]);
  float x1 = b2f(att[base + 64 + lane]);
  float x2 = b2f(att[base + 128 + lane]);
  float m = fmaxf(x0, fmaxf(x1, x2));
  #pragma unroll
  for (int off = 32; off; off >>= 1) m = fmaxf(m, __shfl_xor(m, off));
  float e0 = __expf(x0 - m), e1 = __expf(x1 - m), e2 = __expf(x2 - m);
  float s = e0 + e1 + e2;
  #pragma unroll
  for (int off = 32; off; off >>= 1) s += __shfl_xor(s, off);
  float inv = 1.0f / s;
  att[base + lane]       = f2b(e0 * inv);
  att[base + 64 + lane]  = f2b(e1 * inv);
  att[base + 128 + lane] = f2b(e2 * inv);
}

// ---------------------------------------------------------------------------
// outH via MFMA: accb[b,w,h,c] = sum_j att[b,h,w,j]*v_t[b,w,j,c]; grid (96 w, 8 b)
__global__ __launch_bounds__(256) void k_outH_mfma(const bf16* __restrict__ att,
                                                   const bf16* __restrict__ v_t,
                                                   bf16* __restrict__ accb){
  int w = blockIdx.x, b = blockIdx.y, t = threadIdx.x;
  int lane = t & 63, wv = t >> 6;
  int m_off = (wv & 1)*48, o_off = (wv >> 1)*128;
  int lm = lane & 15, lk = lane >> 4;
  __shared__ __align__(16) bf16 As[96*36];
  __shared__ __align__(16) bf16 Vt[256*36];
  f32x4 acc[3][8] = {};
  const bf16* Vb = v_t + ((size_t)b*96 + w)*96*256;
  for (int j0 = 0; j0 < 96; j0 += 32){
    for (int e = t; e < 384; e += 256){
      int h = e >> 2, p = e & 3;
      *(uint4*)&As[h*36 + p*8] =
        *(const uint4*)&att[(((size_t)b*96 + h)*96 + w)*192 + j0 + p*8];
    }
    for (int e = t; e < 512; e += 256){
      int jj2 = (e & 15)*2, cg = e >> 4;   // cg 0..31 (8 c's each)
      const bf16* p = Vb + (size_t)(j0 + jj2)*256 + cg*8;
      uint4 a0 = *(const uint4*)p;
      uint4 a1 = *(const uint4*)(p + 256);
      const unsigned short* u0 = (const unsigned short*)&a0;
      const unsigned short* u1 = (const unsigned short*)&a1;
      #pragma unroll
      for (int u = 0; u < 8; u++){
        ushort2 pr; pr.x = u0[u]; pr.y = u1[u];
        *(ushort2*)&Vt[(cg*8 + u)*36 + jj2] = pr;
      }
    }
    __syncthreads();
    short8 af[3], bfr[8];
    #pragma unroll
    for (int i = 0; i < 3; i++)
      af[i] = *(const short8*)&As[(m_off + i*16 + lm)*36 + lk*8];
    #pragma unroll
    for (int j = 0; j < 8; j++)
      bfr[j] = *(const short8*)&Vt[(o_off + j*16 + lm)*36 + lk*8];
    #pragma unroll
    for (int i = 0; i < 3; i++)
      #pragma unroll
      for (int j = 0; j < 8; j++)
        acc[i][j] = __builtin_amdgcn_mfma_f32_16x16x32_bf16(af[i], bfr[j], acc[i][j], 0, 0, 0);
    __syncthreads();
  }
  #pragma unroll
  for (int j = 0; j < 8; j++){
    int c = o_off + j*16 + lm;
    #pragma unroll
    for (int i = 0; i < 3; i++){
      int hbase = m_off + i*16 + lk*4;
      #pragma unroll
      for (int r = 0; r < 4; r++)
        accb[(((size_t)b*96 + w)*96 + hbase + r)*256 + c] = f2b(acc[i][j][r]);
    }
  }
}

// outW via MFMA + residual: vf_t[b,w,h,c] += g*(accb[b,w,h,c] + sum_j attW[h,w,j]*v_t[b,j,h,c])
// grid (96 h, 8 b). out 96(w) x 256(c), K=96(j).
__global__ __launch_bounds__(256) void k_outW_mfma(const bf16* __restrict__ att,
                                                   const bf16* __restrict__ v_t,
                                                   const bf16* __restrict__ accb,
                                                   const float* __restrict__ gamma_p,
                                                   bf16* __restrict__ vf_t){
  int h = blockIdx.x, b = blockIdx.y, t = threadIdx.x;
  int lane = t & 63, wv = t >> 6;
  int m_off = (wv & 1)*48, o_off = (wv >> 1)*128;
  int lm = lane & 15, lk = lane >> 4;
  __shared__ __align__(16) bf16 As[96*36];
  __shared__ __align__(16) bf16 Vt[256*36];
  f32x4 acc[3][8] = {};
  for (int j0 = 0; j0 < 96; j0 += 32){
    for (int e = t; e < 384; e += 256){
      int wl = e >> 2, p = e & 3;
      *(uint4*)&As[wl*36 + p*8] =
        *(const uint4*)&att[(((size_t)b*96 + h)*96 + wl)*192 + 96 + j0 + p*8];
    }
    for (int e = t; e < 512; e += 256){
      int jj2 = (e & 15)*2, cg = e >> 4;
      const bf16* p = v_t + (((size_t)b*96 + j0 + jj2)*96 + h)*256 + cg*8;
      uint4 a0 = *(const uint4*)p;
      uint4 a1 = *(const uint4*)(p + 96*256);
      const unsigned short* u0 = (const unsigned short*)&a0;
      const unsigned short* u1 = (const unsigned short*)&a1;
      #pragma unroll
      for (int u = 0; u < 8; u++){
        ushort2 pr; pr.x = u0[u]; pr.y = u1[u];
        *(ushort2*)&Vt[(cg*8 + u)*36 + jj2] = pr;
      }
    }
    __syncthreads();
    short8 af[3], bfr[8];
    #pragma unroll
    for (int i = 0; i < 3; i++)
      af[i] = *(const short8*)&As[(m_off + i*16 + lm)*36 + lk*8];
    #pragma unroll
    for (int j = 0; j < 8; j++)
      bfr[j] = *(const short8*)&Vt[(o_off + j*16 + lm)*36 + lk*8];
    #pragma unroll
    for (int i = 0; i < 3; i++)
      #pragma unroll
      for (int j = 0; j < 8; j++)
        acc[i][j] = __builtin_amdgcn_mfma_f32_16x16x32_bf16(af[i], bfr[j], acc[i][j], 0, 0, 0);
    __syncthreads();
  }
  float g = gamma_p[0];
  #pragma unroll
  for (int j = 0; j < 8; j++){
    int c = o_off + j*16 + lm;
    #pragma unroll
    for (int i = 0; i < 3; i++){
      int wbase = m_off + i*16 + lk*4;
      #pragma unroll
      for (int r = 0; r < 4; r++){
        size_t idx = (((size_t)b*96 + wbase + r)*96 + h)*256 + c;
        vf_t[idx] = f2b(b2f(vf_t[idx]) + g*(acc[i][j][r] + b2f(accb[idx])));
      }
    }
  }
}

// ---------------------------------------------------------------------------
__global__ void k_bnprep(const float* __restrict__ s1, const float* __restrict__ s2,
                         const float* __restrict__ sc, const float* __restrict__ bi,
                         float2* __restrict__ ab){
  int co = blockIdx.x*256 + threadIdx.x;
  if (co >= 512) return;
  const float N = 73728.0f;
  float mean = s1[co] / N;
  float var  = s2[co] / N - mean*mean;
  if (var < 0.f) var = 0.f;
  float a = rsqrtf(var + 1e-5f) * sc[co];
  ab[co] = make_float2(a, bi[co] - mean*a);
}

// BN + relu + transpose (b,w,h,co) -> (b,co,h,w) fp32; grid (3, 96, 8)
__global__ __launch_bounds__(256) void k_bnout(const bf16* __restrict__ bt,
                                               const float2* __restrict__ ab,
                                               float* __restrict__ out){
  int w0 = blockIdx.x*32, h = blockIdx.y, b = blockIdx.z, t = threadIdx.x;
  __shared__ float Tl[32][33];
  for (int co0 = 0; co0 < 512; co0 += 32){
    for (int e = t; e < 1024; e += 256){
      int wl = e >> 5, co = e & 31;
      Tl[wl][co] = b2f(bt[(((size_t)b*96 + w0 + wl)*96 + h)*512 + co0 + co]);
    }
    __syncthreads();
    for (int e = t; e < 1024; e += 256){
      int co = e >> 5, wl = e & 31;
      float2 s = ab[co0 + co];
      float v = fmaxf(Tl[wl][co]*s.x + s.y, 0.0f);
      out[(((size_t)b*512 + co0 + co)*96 + h)*96 + w0 + wl] = v;
    }
    __syncthreads();
  }
}

// ---------------------------------------------------------------------------
extern "C" void kernel_launch(void* const* d_in, const int* in_sizes, int n_in,
                              void* d_out, int out_size, void* d_ws, size_t ws_size,
                              hipStream_t stream){
  (void)in_sizes; (void)n_in; (void)out_size; (void)ws_size;
  const float* low   = (const float*)d_in[0];
  const float* high  = (const float*)d_in[1];
  const float* c1w   = (const float*)d_in[2];
  const float* c1b   = (const float*)d_in[3];
  const float* c2w   = (const float*)d_in[4];
  const float* c2b   = (const float*)d_in[5];
  const float* qw    = (const float*)d_in[6];
  const float* qb    = (const float*)d_in[7];
  const float* kw    = (const float*)d_in[8];
  const float* kb    = (const float*)d_in[9];
  const float* vw    = (const float*)d_in[10];
  const float* vb    = (const float*)d_in[11];
  const float* gamma = (const float*)d_in[12];
  const float* bw    = (const float*)d_in[13];
  const float* bns   = (const float*)d_in[14];
  const float* bnb   = (const float*)d_in[15];
  float* out = (float*)d_out;

  char* wsb = (char*)d_ws;
  // workspace layout — total 223,027,328 bytes (~212.7 MB)
  bf16*   hf_t = (bf16*) (wsb + 0);            // 75,497,472  (b, x*96+y, 512)
  bf16*   vf_t = (bf16*) (wsb + 75497472);     // 37,748,736  (b, x*96+y, 256)
  bf16*   q_t  = (bf16*) (wsb + 113246208);    //  4,718,592
  float*  qq_w = (float*)(wsb + 117964800);    //     65,536
  float*  qq_b = (float*)(wsb + 118030336);    //        128
  float*  s1   = (float*)(wsb + 118030464);    //      2,048
  float*  s2   = (float*)(wsb + 118032512);    //      2,048
  float2* ab   = (float2*)(wsb + 118034560);   //      4,096
  bf16*   wbb  = (bf16*) (wsb + 118038656);    //    786,432  (bneck W bf16, 512x768)
  bf16*   wc2  = (bf16*) (wsb + 118825088);    //    262,144  (conv2 W bf16, 256x512)
  bf16*   wv   = (bf16*) (wsb + 119087232);    //    131,072  (v W bf16, 256x256)
  bf16*   v_t  = (bf16*) (wsb + 119218304);    // 37,748,736
  bf16*   att  = (bf16*) (wsb + 156967040);    // 28,311,552
  bf16*   accb = (bf16*) (wsb + 185278592);    // 37,748,736 -> ends 223,027,328
  bf16*   k_t  = (bf16*) (wsb + 185278592);    //  4,718,592 (aliases accb head; dead before accb written)
  bf16*   bt   = (bf16*) (wsb + 119218304);    // 75,497,472 (aliases v_t/att/accb-head; all dead at bneck)

  k_zero<<<4, 256, 0, stream>>>(s1);
  k_cvt<<<1536, 256, 0, stream>>>(bw,  wbb, 393216);
  k_cvt<<<512,  256, 0, stream>>>(c2w, wc2, 131072);
  k_cvt<<<256,  256, 0, stream>>>(vw,  wv,  65536);
  k_upsample<<<dim3(96, 8), 256, 0, stream>>>(high, hf_t);
  k_qqw<<<64, 256, 0, stream>>>(qw, c1w, qq_w);
  k_qqb<<<1, 64, 0, stream>>>(qw, c1b, qb, qq_b);
  k_mfma_gemm<<<dim3(72, 2, 8), 256, 0, stream>>>(hf_t, wc2, c2b, vf_t, 512, 256);
  k_qlow<<<dim3(96, 8), 256, 0, stream>>>(low, qq_w, qq_b, q_t);

  for (int r = 0; r < 2; r++){
    k_gemm_bb<128, 32><<<dim3(72, 1, 8), 256, 0, stream>>>(vf_t, kw, kb, k_t, 256, 32);
    k_mfma_gemm<<<dim3(72, 2, 8), 256, 0, stream>>>(vf_t, wv, vb, v_t, 256, 256);
    k_eH<<<dim3(96, 8), 256, 0, stream>>>(q_t, k_t, att);
    k_eW<<<dim3(96, 8), 256, 0, stream>>>(q_t, k_t, att);
    k_softmax<<<18432, 256, 0, stream>>>(att);
    k_outH_mfma<<<dim3(96, 8), 256, 0, stream>>>(att, v_t, accb);
    k_outW_mfma<<<dim3(96, 8), 256, 0, stream>>>(att, v_t, accb, gamma, vf_t);
  }

  k_bneck_mfma<<<dim3(72, 4, 8), 256, 0, stream>>>(vf_t, hf_t, wbb, bt, s1, s2);
  k_bnprep<<<2, 256, 0, stream>>>(s1, s2, bns, bnb, ab);
  k_bnout<<<dim3(3, 96, 8), 256, 0, stream>>>(bt, ab, out);
}

// Round 6
// 1014.326 us; speedup vs baseline: 1.1899x; 1.0484x over previous
//
#include <hip/hip_runtime.h>
#include <hip/hip_bf16.h>

typedef __hip_bfloat16 bf16;
typedef __attribute__((ext_vector_type(8))) short short8;
typedef __attribute__((ext_vector_type(4))) float f32x4;

constexpr int kHW = 96 * 96;   // 9216

__device__ __forceinline__ float b2f(bf16 x){ return __bfloat162float(x); }
__device__ __forceinline__ bf16  f2b(float x){ return __float2bfloat16(x); }
__device__ __forceinline__ unsigned short b2u(bf16 x){ return *(unsigned short*)&x; }

// NOTE: __builtin_amdgcn_global_load_lds is permanently abandoned in this
// session: 3/3 container failures with it, 2/2 passes without.

// ---------------------------------------------------------------------------
// zero s1/s2 (1024 contiguous floats)
__global__ void k_zero(float* __restrict__ p){
  int i = blockIdx.x*256 + threadIdx.x;
  if (i < 1024) p[i] = 0.0f;
}

// fp32 -> bf16 weight conversion
__global__ void k_cvt(const float* __restrict__ s, bf16* __restrict__ d, int n){
  int i = blockIdx.x*256 + threadIdx.x;
  if (i < n) d[i] = f2b(s[i]);
}

// ---------------------------------------------------------------------------
// bilinear 2x upsample: high (b,512,48,48) fp32 -> hf_t (b, x96*96+y, c512) bf16
// grid (y=96, b=8), 256 thr
__global__ __launch_bounds__(256) void k_upsample(const float* __restrict__ hi,
                                                  bf16* __restrict__ hf_t){
  int y = blockIdx.x, b = blockIdx.y, t = threadIdx.x;
  int j = y >> 1;
  int j0, j1; float wy0, wy1;
  if ((y & 1) == 0){ j0 = j - 1; if (j0 < 0) j0 = 0; j1 = j; wy0 = 0.25f; wy1 = 0.75f; }
  else             { j0 = j; j1 = j + 1; if (j1 > 47) j1 = 47; wy0 = 0.75f; wy1 = 0.25f; }
  __shared__ __align__(16) float sm[2][128][49];
  for (int c0 = 0; c0 < 512; c0 += 128){
    for (int e = t; e < 2*128*48; e += 256){
      int cl = e / 96; int r = e % 96; int jj = r / 48; int i = r % 48;
      int row = jj ? j1 : j0;
      sm[jj][cl][i] = hi[(((size_t)b*512 + c0 + cl)*48 + row)*48 + i];
    }
    __syncthreads();
    for (int e = t; e < 96*128; e += 256){
      int x = e >> 7; int cl = e & 127;
      int i = x >> 1; int i0, i1; float wx0, wx1;
      if ((x & 1) == 0){ i0 = i - 1; if (i0 < 0) i0 = 0; i1 = i; wx0 = 0.25f; wx1 = 0.75f; }
      else             { i0 = i; i1 = i + 1; if (i1 > 47) i1 = 47; wx0 = 0.75f; wx1 = 0.25f; }
      float v = wy0*(wx0*sm[0][cl][i0] + wx1*sm[0][cl][i1])
              + wy1*(wx0*sm[1][cl][i0] + wx1*sm[1][cl][i1]);
      hf_t[(((size_t)b*96 + x)*96 + y)*512 + c0 + cl] = f2b(v);
    }
    __syncthreads();
  }
}

// ---------------------------------------------------------------------------
// fold q path: qq_wb[o,c] = bf16( sum_k q_w[o,k]*conv1_w[k,c] )  (32x512)
__global__ void k_qqw(const float* __restrict__ q_w, const float* __restrict__ c1_w,
                      bf16* __restrict__ qq_wb){
  int gid = blockIdx.x*256 + threadIdx.x;      // 16384
  int o = gid >> 9, c = gid & 511;
  float acc = 0.f;
  for (int k = 0; k < 256; k++) acc += q_w[o*256 + k] * c1_w[k*512 + c];
  qq_wb[gid] = f2b(acc);
}
__global__ void k_qqb(const float* __restrict__ q_w, const float* __restrict__ c1_b,
                      const float* __restrict__ q_b, float* __restrict__ qq_b){
  int o = threadIdx.x; if (o >= 32) return;
  float acc = q_b[o];
  for (int k = 0; k < 256; k++) acc += q_w[o*256 + k] * c1_b[k];
  qq_b[o] = acc;
}

// ---------------------------------------------------------------------------
// MFMA GEMM: out[b,n,o] = sum_k A[b,n,k]*Wb[o,k] (+bias[o])
// 128x128 block tile, 4 waves of 64x64, BK=32, double-buffered LDS + reg prefetch
__global__ __launch_bounds__(256) void k_mfma_gemm(const bf16* __restrict__ A,
                                                   const bf16* __restrict__ Wb,
                                                   const float* __restrict__ bias,
                                                   bf16* __restrict__ out,
                                                   int K, int O){
  int b = blockIdx.z, n0 = blockIdx.x*128, o0 = blockIdx.y*128;
  int t = threadIdx.x, lane = t & 63, wv = t >> 6;
  int m_off = (wv & 1)*64, o_off = (wv >> 1)*64;
  int lm = lane & 15, lk = lane >> 4;
  __shared__ __align__(16) bf16 As[2][128*40];
  __shared__ __align__(16) bf16 Ws[2][128*40];
  f32x4 acc[4][4] = {};
  const bf16* Ab = A + (size_t)b*kHW*K;
  int nl0 = t >> 2, p0 = (t & 3)*8;    // rows nl0, nl0+64; col offset p0
  uint4 pa0, pa1, pw0, pw1;
  pa0 = *(const uint4*)&Ab[(size_t)(n0+nl0)*K + p0];
  pa1 = *(const uint4*)&Ab[(size_t)(n0+nl0+64)*K + p0];
  pw0 = *(const uint4*)&Wb[(size_t)(o0+nl0)*K + p0];
  pw1 = *(const uint4*)&Wb[(size_t)(o0+nl0+64)*K + p0];
  *(uint4*)&As[0][nl0*40 + p0]      = pa0;
  *(uint4*)&As[0][(nl0+64)*40 + p0] = pa1;
  *(uint4*)&Ws[0][nl0*40 + p0]      = pw0;
  *(uint4*)&Ws[0][(nl0+64)*40 + p0] = pw1;
  int cur = 0;
  int NS = K >> 5;
  for (int s = 0; s < NS; s++){
    if (s+1 < NS){
      int c0 = (s+1)*32;
      pa0 = *(const uint4*)&Ab[(size_t)(n0+nl0)*K + c0 + p0];
      pa1 = *(const uint4*)&Ab[(size_t)(n0+nl0+64)*K + c0 + p0];
      pw0 = *(const uint4*)&Wb[(size_t)(o0+nl0)*K + c0 + p0];
      pw1 = *(const uint4*)&Wb[(size_t)(o0+nl0+64)*K + c0 + p0];
    }
    __syncthreads();
    short8 af[4], bfr[4];
    #pragma unroll
    for (int i = 0; i < 4; i++){
      af[i]  = *(const short8*)&As[cur][(m_off + i*16 + lm)*40 + lk*8];
      bfr[i] = *(const short8*)&Ws[cur][(o_off + i*16 + lm)*40 + lk*8];
    }
    #pragma unroll
    for (int i = 0; i < 4; i++)
      #pragma unroll
      for (int j = 0; j < 4; j++)
        acc[i][j] = __builtin_amdgcn_mfma_f32_16x16x32_bf16(af[i], bfr[j], acc[i][j], 0, 0, 0);
    if (s+1 < NS){
      int nx = cur ^ 1;
      *(uint4*)&As[nx][nl0*40 + p0]      = pa0;
      *(uint4*)&As[nx][(nl0+64)*40 + p0] = pa1;
      *(uint4*)&Ws[nx][nl0*40 + p0]      = pw0;
      *(uint4*)&Ws[nx][(nl0+64)*40 + p0] = pw1;
      cur = nx;
    }
  }
  #pragma unroll
  for (int j = 0; j < 4; j++){
    int oc = o0 + o_off + j*16 + lm;
    float bs = bias ? bias[oc] : 0.0f;
    #pragma unroll
    for (int i = 0; i < 4; i++){
      int rbase = n0 + m_off + i*16 + lk*4;
      #pragma unroll
      for (int r = 0; r < 4; r++)
        out[((size_t)b*kHW + rbase + r)*(size_t)O + oc] = f2b(acc[i][j][r] + bs);
    }
  }
}

// bottleneck MFMA: K=768 split A-source; double-buffered; fused BN stats
__global__ __launch_bounds__(256) void k_bneck_mfma(const bf16* __restrict__ vf,
                                                    const bf16* __restrict__ hf,
                                                    const bf16* __restrict__ Wb,
                                                    bf16* __restrict__ out,
                                                    float* __restrict__ s1,
                                                    float* __restrict__ s2){
  int b = blockIdx.z, n0 = blockIdx.x*128, o0 = blockIdx.y*128;
  int t = threadIdx.x, lane = t & 63, wv = t >> 6;
  int m_off = (wv & 1)*64, o_off = (wv >> 1)*64;
  int lm = lane & 15, lk = lane >> 4;
  __shared__ __align__(16) bf16 As[2][128*40];
  __shared__ __align__(16) bf16 Ws[2][128*40];
  __shared__ float l1[128];
  __shared__ float l2[128];
  if (t < 128){ l1[t] = 0.f; l2[t] = 0.f; }
  f32x4 acc[4][4] = {};
  int nl0 = t >> 2, p0 = (t & 3)*8;
  const bf16* vfb = vf + (size_t)b*kHW*256;
  const bf16* hfb = hf + (size_t)b*kHW*512;
  uint4 pa0, pa1, pw0, pw1;
  pa0 = *(const uint4*)&vfb[(size_t)(n0+nl0)*256 + p0];
  pa1 = *(const uint4*)&vfb[(size_t)(n0+nl0+64)*256 + p0];
  pw0 = *(const uint4*)&Wb[(size_t)(o0+nl0)*768 + p0];
  pw1 = *(const uint4*)&Wb[(size_t)(o0+nl0+64)*768 + p0];
  *(uint4*)&As[0][nl0*40 + p0]      = pa0;
  *(uint4*)&As[0][(nl0+64)*40 + p0] = pa1;
  *(uint4*)&Ws[0][nl0*40 + p0]      = pw0;
  *(uint4*)&Ws[0][(nl0+64)*40 + p0] = pw1;
  int cur = 0;
  for (int s = 0; s < 24; s++){
    if (s+1 < 24){
      int c0 = (s+1)*32;
      if (c0 < 256){
        pa0 = *(const uint4*)&vfb[(size_t)(n0+nl0)*256 + c0 + p0];
        pa1 = *(const uint4*)&vfb[(size_t)(n0+nl0+64)*256 + c0 + p0];
      } else {
        int cc = c0 - 256;
        pa0 = *(const uint4*)&hfb[(size_t)(n0+nl0)*512 + cc + p0];
        pa1 = *(const uint4*)&hfb[(size_t)(n0+nl0+64)*512 + cc + p0];
      }
      pw0 = *(const uint4*)&Wb[(size_t)(o0+nl0)*768 + c0 + p0];
      pw1 = *(const uint4*)&Wb[(size_t)(o0+nl0+64)*768 + c0 + p0];
    }
    __syncthreads();
    short8 af[4], bfr[4];
    #pragma unroll
    for (int i = 0; i < 4; i++){
      af[i]  = *(const short8*)&As[cur][(m_off + i*16 + lm)*40 + lk*8];
      bfr[i] = *(const short8*)&Ws[cur][(o_off + i*16 + lm)*40 + lk*8];
    }
    #pragma unroll
    for (int i = 0; i < 4; i++)
      #pragma unroll
      for (int j = 0; j < 4; j++)
        acc[i][j] = __builtin_amdgcn_mfma_f32_16x16x32_bf16(af[i], bfr[j], acc[i][j], 0, 0, 0);
    if (s+1 < 24){
      int nx = cur ^ 1;
      *(uint4*)&As[nx][nl0*40 + p0]      = pa0;
      *(uint4*)&As[nx][(nl0+64)*40 + p0] = pa1;
      *(uint4*)&Ws[nx][nl0*40 + p0]      = pw0;
      *(uint4*)&Ws[nx][(nl0+64)*40 + p0] = pw1;
      cur = nx;
    }
  }
  #pragma unroll
  for (int j = 0; j < 4; j++){
    int oc = o0 + o_off + j*16 + lm;
    float p1 = 0.f, p2 = 0.f;
    #pragma unroll
    for (int i = 0; i < 4; i++){
      int rbase = n0 + m_off + i*16 + lk*4;
      #pragma unroll
      for (int r = 0; r < 4; r++){
        float v = acc[i][j][r];
        p1 += v; p2 += v*v;
        out[((size_t)b*kHW + rbase + r)*512 + oc] = f2b(v);
      }
    }
    int cl = o_off + j*16 + lm;
    atomicAdd(&l1[cl], p1);
    atomicAdd(&l2[cl], p2);
  }
  __syncthreads();
  if (t < 128){
    atomicAdd(&s1[o0 + t], l1[t]);
    atomicAdd(&s2[o0 + t], l2[t]);
  }
}

// ---------------------------------------------------------------------------
// q via MFMA: q_t[b,x,h,o] = sum_c low[b,c,n]*qqw[o,c] + qq_b[o], n = h*96+x
// grid (144 n-tiles of 64, 8 b), 256 thr = 4 waves x 16 rows; K=512 in 16 steps
__global__ __launch_bounds__(256) void k_qmfma(const float* __restrict__ low,
                                               const bf16* __restrict__ qq_wb,
                                               const float* __restrict__ qq_b,
                                               bf16* __restrict__ q_t){
  int n0 = blockIdx.x*64, b = blockIdx.y, t = threadIdx.x;
  int lane = t & 63, wv = t >> 6;
  int m_off = wv*16;
  int lm = lane & 15, lk = lane >> 4;
  __shared__ __align__(16) bf16 As[64*36];
  __shared__ __align__(16) bf16 Ws[32*40];
  f32x4 acc[2] = {};
  const float* low_b = low + (size_t)b*512*kHW;
  int c2 = (t & 15)*2;     // c-pair within 32-step
  int xg = t >> 4;         // x-group (4 each), 0..15
  for (int c0 = 0; c0 < 512; c0 += 32){
    // stage A: 32c x 64n fp32 -> bf16 transposed As[n][c] (ushort2 writes, 2-way free)
    const float* p0 = low_b + (size_t)(c0 + c2)*kHW + n0 + xg*4;
    float4 a0 = *(const float4*)p0;
    float4 a1 = *(const float4*)(p0 + kHW);
    float f0[4] = {a0.x, a0.y, a0.z, a0.w};
    float f1[4] = {a1.x, a1.y, a1.z, a1.w};
    #pragma unroll
    for (int u = 0; u < 4; u++){
      ushort2 pr;
      bf16 v0 = f2b(f0[u]), v1 = f2b(f1[u]);
      pr.x = b2u(v0); pr.y = b2u(v1);
      *(ushort2*)&As[(xg*4 + u)*36 + c2] = pr;
    }
    // stage W slice: 32o x 32c bf16
    if (t < 128){
      int ol = t >> 2, p = t & 3;
      *(uint4*)&Ws[ol*40 + p*8] = *(const uint4*)&qq_wb[(size_t)ol*512 + c0 + p*8];
    }
    __syncthreads();
    short8 af = *(const short8*)&As[(m_off + lm)*36 + lk*8];
    short8 b0 = *(const short8*)&Ws[lm*40 + lk*8];
    short8 b1 = *(const short8*)&Ws[(16 + lm)*40 + lk*8];
    acc[0] = __builtin_amdgcn_mfma_f32_16x16x32_bf16(af, b0, acc[0], 0, 0, 0);
    acc[1] = __builtin_amdgcn_mfma_f32_16x16x32_bf16(af, b1, acc[1], 0, 0, 0);
    __syncthreads();
  }
  #pragma unroll
  for (int j = 0; j < 2; j++){
    int oc = j*16 + lm;
    float bs = qq_b[oc];
    #pragma unroll
    for (int r = 0; r < 4; r++){
      int ng = n0 + m_off + lk*4 + r;
      int h = ng / 96, x = ng - h*96;
      q_t[(((size_t)b*96 + x)*96 + h)*32 + oc] = f2b(acc[j][r] + bs);
    }
  }
}

// bf16-A (n,c) @ fp32-W (o,c)^T + fp32 bias -> bf16 (small-O path, used for k)
template<int BN, int OT>
__global__ __launch_bounds__(256) void k_gemm_bb(const bf16* __restrict__ A,
                                                 const float* __restrict__ Wt,
                                                 const float* __restrict__ bias,
                                                 bf16* __restrict__ out,
                                                 int Cin, int O){
  constexpr int TN = BN/4;
  int b = blockIdx.z, n0 = blockIdx.x*BN, o0 = blockIdx.y*OT, t = threadIdx.x;
  int tn = t % TN, to = t / TN;
  __shared__ __align__(16) float As[32][BN+4];
  __shared__ __align__(16) float Ws[32][OT+4];
  float acc[4][4] = {};
  const bf16* Ab = A + (size_t)b*kHW*Cin;
  for (int c0 = 0; c0 < Cin; c0 += 32){
    for (int e = t; e < BN*32; e += 256){
      int nl = e >> 5, kk = e & 31;
      As[kk][nl] = b2f(Ab[(size_t)(n0+nl)*Cin + c0 + kk]);
    }
    for (int e = t; e < OT*32; e += 256){
      int ol = e >> 5, kk = e & 31;
      Ws[kk][ol] = Wt[(size_t)(o0+ol)*Cin + c0 + kk];
    }
    __syncthreads();
    #pragma unroll
    for (int kk = 0; kk < 32; kk++){
      float4 av = *(const float4*)&As[kk][tn*4];
      float4 wv = *(const float4*)&Ws[kk][to*4];
      float a_[4] = {av.x, av.y, av.z, av.w};
      float w_[4] = {wv.x, wv.y, wv.z, wv.w};
      #pragma unroll
      for (int i = 0; i < 4; i++)
        #pragma unroll
        for (int jj = 0; jj < 4; jj++) acc[i][jj] += a_[i]*w_[jj];
    }
    __syncthreads();
  }
  #pragma unroll
  for (int i = 0; i < 4; i++){
    size_t base = ((size_t)b*kHW + n0 + tn*4 + i)*(size_t)O + o0 + to*4;
    #pragma unroll
    for (int jj = 0; jj < 4; jj++) out[base + jj] = f2b(acc[i][jj] + bias[o0 + to*4 + jj]);
  }
}

// ---------------------------------------------------------------------------
// eH: att[b,h,w,j] = sum_c q_t[b,w,h,c]*k_t[b,w,j,c]  (-1e9 if j==h); grid (96 w, 8 b)
__global__ __launch_bounds__(256) void k_eH(const bf16* __restrict__ q_t,
                                            const bf16* __restrict__ k_t,
                                            bf16* __restrict__ att){
  int w = blockIdx.x, b = blockIdx.y, t = threadIdx.x;
  __shared__ float Qs[96][33];
  __shared__ float Ks[96][33];
  const bf16* Qp = q_t + (((size_t)b*96 + w)*96)*32;
  const bf16* Kp = k_t + (((size_t)b*96 + w)*96)*32;
  for (int e = t; e < 3072; e += 256){ Qs[e>>5][e&31] = b2f(Qp[e]); Ks[e>>5][e&31] = b2f(Kp[e]); }
  __syncthreads();
  int tj = t % 16, th = t / 16;
  float acc[6][6] = {};
  #pragma unroll 4
  for (int c = 0; c < 32; c++){
    float qa[6], kb[6];
    #pragma unroll
    for (int i = 0; i < 6; i++) qa[i] = Qs[th*6 + i][c];
    #pragma unroll
    for (int jj = 0; jj < 6; jj++) kb[jj] = Ks[tj*6 + jj][c];
    #pragma unroll
    for (int i = 0; i < 6; i++)
      #pragma unroll
      for (int jj = 0; jj < 6; jj++) acc[i][jj] += qa[i]*kb[jj];
  }
  #pragma unroll
  for (int i = 0; i < 6; i++){
    int h = th*6 + i;
    size_t base = (((size_t)b*96 + h)*96 + w)*192;
    #pragma unroll
    for (int jj = 0; jj < 6; jj++){
      int jg = tj*6 + jj;
      float e = acc[i][jj];
      if (jg == h) e += -1000000000.0f;
      att[base + jg] = f2b(e);
    }
  }
}

// eW: att[b,h,w,96+j] = sum_c q_t[b,w,h,c]*k_t[b,j,h,c]; grid (96 h, 8 b)
__global__ __launch_bounds__(256) void k_eW(const bf16* __restrict__ q_t,
                                            const bf16* __restrict__ k_t,
                                            bf16* __restrict__ att){
  int h = blockIdx.x, b = blockIdx.y, t = threadIdx.x;
  __shared__ float Qs[96][33];
  __shared__ float Ks[96][33];
  for (int e = t; e < 3072; e += 256){
    int wl = e >> 5, c = e & 31;
    size_t idx = (((size_t)b*96 + wl)*96 + h)*32 + c;
    Qs[wl][c] = b2f(q_t[idx]);
    Ks[wl][c] = b2f(k_t[idx]);
  }
  __syncthreads();
  int tj = t % 16, tw = t / 16;
  float acc[6][6] = {};
  #pragma unroll 4
  for (int c = 0; c < 32; c++){
    float qa[6], kb[6];
    #pragma unroll
    for (int i = 0; i < 6; i++) qa[i] = Qs[tw*6 + i][c];
    #pragma unroll
    for (int jj = 0; jj < 6; jj++) kb[jj] = Ks[tj*6 + jj][c];
    #pragma unroll
    for (int i = 0; i < 6; i++)
      #pragma unroll
      for (int jj = 0; jj < 6; jj++) acc[i][jj] += qa[i]*kb[jj];
  }
  #pragma unroll
  for (int i = 0; i < 6; i++){
    int wl = tw*6 + i;
    size_t base = (((size_t)b*96 + h)*96 + wl)*192 + 96;
    #pragma unroll
    for (int jj = 0; jj < 6; jj++) att[base + tj*6 + jj] = f2b(acc[i][jj]);
  }
}

// softmax over 192, one wave per row; grid 18432
__global__ __launch_bounds__(256) void k_softmax(bf16* __restrict__ att){
  int t = threadIdx.x;
  int row = blockIdx.x*4 + (t >> 6);
  int lane = t & 63;
  size_t base = (size_t)row * 192;
  float x0 = b2f(att[base + lane]);
  float x1 = b2f(att[base + 64 + lane]);
  float x2 = b2f(att[base + 128 + lane]);
  float m = fmaxf(x0, fmaxf(x1, x2));
  #pragma unroll
  for (int off = 32; off; off >>= 1) m = fmaxf(m, __shfl_xor(m, off));
  float e0 = __expf(x0 - m), e1 = __expf(x1 - m), e2 = __expf(x2 - m);
  float s = e0 + e1 + e2;
  #pragma unroll
  for (int off = 32; off; off >>= 1) s += __shfl_xor(s, off);
  float inv = 1.0f / s;
  att[base + lane]       = f2b(e0 * inv);
  att[base + 64 + lane]  = f2b(e1 * inv);
  att[base + 128 + lane] = f2b(e2 * inv);
}

// ---------------------------------------------------------------------------
// outH via MFMA: accb[b,w,h,c] = sum_j att[b,h,w,j]*v_t[b,w,j,c]; grid (96 w, 8 b)
__global__ __launch_bounds__(256) void k_outH_mfma(const bf16* __restrict__ att,
                                                   const bf16* __restrict__ v_t,
                                                   bf16* __restrict__ accb){
  int w = blockIdx.x, b = blockIdx.y, t = threadIdx.x;
  int lane = t & 63, wv = t >> 6;
  int m_off = (wv & 1)*48, o_off = (wv >> 1)*128;
  int lm = lane & 15, lk = lane >> 4;
  __shared__ __align__(16) bf16 As[96*36];
  __shared__ __align__(16) bf16 Vt[256*36];
  f32x4 acc[3][8] = {};
  const bf16* Vb = v_t + ((size_t)b*96 + w)*96*256;
  for (int j0 = 0; j0 < 96; j0 += 32){
    for (int e = t; e < 384; e += 256){
      int h = e >> 2, p = e & 3;
      *(uint4*)&As[h*36 + p*8] =
        *(const uint4*)&att[(((size_t)b*96 + h)*96 + w)*192 + j0 + p*8];
    }
    for (int e = t; e < 512; e += 256){
      int jj2 = (e & 15)*2, cg = e >> 4;   // cg 0..31 (8 c's each)
      const bf16* p = Vb + (size_t)(j0 + jj2)*256 + cg*8;
      uint4 a0 = *(const uint4*)p;
      uint4 a1 = *(const uint4*)(p + 256);
      const unsigned short* u0 = (const unsigned short*)&a0;
      const unsigned short* u1 = (const unsigned short*)&a1;
      #pragma unroll
      for (int u = 0; u < 8; u++){
        ushort2 pr; pr.x = u0[u]; pr.y = u1[u];
        *(ushort2*)&Vt[(cg*8 + u)*36 + jj2] = pr;
      }
    }
    __syncthreads();
    short8 af[3], bfr[8];
    #pragma unroll
    for (int i = 0; i < 3; i++)
      af[i] = *(const short8*)&As[(m_off + i*16 + lm)*36 + lk*8];
    #pragma unroll
    for (int j = 0; j < 8; j++)
      bfr[j] = *(const short8*)&Vt[(o_off + j*16 + lm)*36 + lk*8];
    #pragma unroll
    for (int i = 0; i < 3; i++)
      #pragma unroll
      for (int j = 0; j < 8; j++)
        acc[i][j] = __builtin_amdgcn_mfma_f32_16x16x32_bf16(af[i], bfr[j], acc[i][j], 0, 0, 0);
    __syncthreads();
  }
  #pragma unroll
  for (int j = 0; j < 8; j++){
    int c = o_off + j*16 + lm;
    #pragma unroll
    for (int i = 0; i < 3; i++){
      int hbase = m_off + i*16 + lk*4;
      #pragma unroll
      for (int r = 0; r < 4; r++)
        accb[(((size_t)b*96 + w)*96 + hbase + r)*256 + c] = f2b(acc[i][j][r]);
    }
  }
}

// outW via MFMA + residual: vf_t[b,w,h,c] += g*(accb[b,w,h,c] + sum_j attW[h,w,j]*v_t[b,j,h,c])
// grid (96 h, 8 b). out 96(w) x 256(c), K=96(j).
__global__ __launch_bounds__(256) void k_outW_mfma(const bf16* __restrict__ att,
                                                   const bf16* __restrict__ v_t,
                                                   const bf16* __restrict__ accb,
                                                   const float* __restrict__ gamma_p,
                                                   bf16* __restrict__ vf_t){
  int h = blockIdx.x, b = blockIdx.y, t = threadIdx.x;
  int lane = t & 63, wv = t >> 6;
  int m_off = (wv & 1)*48, o_off = (wv >> 1)*128;
  int lm = lane & 15, lk = lane >> 4;
  __shared__ __align__(16) bf16 As[96*36];
  __shared__ __align__(16) bf16 Vt[256*36];
  f32x4 acc[3][8] = {};
  for (int j0 = 0; j0 < 96; j0 += 32){
    for (int e = t; e < 384; e += 256){
      int wl = e >> 2, p = e & 3;
      *(uint4*)&As[wl*36 + p*8] =
        *(const uint4*)&att[(((size_t)b*96 + h)*96 + wl)*192 + 96 + j0 + p*8];
    }
    for (int e = t; e < 512; e += 256){
      int jj2 = (e & 15)*2, cg = e >> 4;
      const bf16* p = v_t + (((size_t)b*96 + j0 + jj2)*96 + h)*256 + cg*8;
      uint4 a0 = *(const uint4*)p;
      uint4 a1 = *(const uint4*)(p + 96*256);
      const unsigned short* u0 = (const unsigned short*)&a0;
      const unsigned short* u1 = (const unsigned short*)&a1;
      #pragma unroll
      for (int u = 0; u < 8; u++){
        ushort2 pr; pr.x = u0[u]; pr.y = u1[u];
        *(ushort2*)&Vt[(cg*8 + u)*36 + jj2] = pr;
      }
    }
    __syncthreads();
    short8 af[3], bfr[8];
    #pragma unroll
    for (int i = 0; i < 3; i++)
      af[i] = *(const short8*)&As[(m_off + i*16 + lm)*36 + lk*8];
    #pragma unroll
    for (int j = 0; j < 8; j++)
      bfr[j] = *(const short8*)&Vt[(o_off + j*16 + lm)*36 + lk*8];
    #pragma unroll
    for (int i = 0; i < 3; i++)
      #pragma unroll
      for (int j = 0; j < 8; j++)
        acc[i][j] = __builtin_amdgcn_mfma_f32_16x16x32_bf16(af[i], bfr[j], acc[i][j], 0, 0, 0);
    __syncthreads();
  }
  float g = gamma_p[0];
  #pragma unroll
  for (int j = 0; j < 8; j++){
    int c = o_off + j*16 + lm;
    #pragma unroll
    for (int i = 0; i < 3; i++){
      int wbase = m_off + i*16 + lk*4;
      #pragma unroll
      for (int r = 0; r < 4; r++){
        size_t idx = (((size_t)b*96 + wbase + r)*96 + h)*256 + c;
        vf_t[idx] = f2b(b2f(vf_t[idx]) + g*(acc[i][j][r] + b2f(accb[idx])));
      }
    }
  }
}

// ---------------------------------------------------------------------------
__global__ void k_bnprep(const float* __restrict__ s1, const float* __restrict__ s2,
                         const float* __restrict__ sc, const float* __restrict__ bi,
                         float2* __restrict__ ab){
  int co = blockIdx.x*256 + threadIdx.x;
  if (co >= 512) return;
  const float N = 73728.0f;
  float mean = s1[co] / N;
  float var  = s2[co] / N - mean*mean;
  if (var < 0.f) var = 0.f;
  float a = rsqrtf(var + 1e-5f) * sc[co];
  ab[co] = make_float2(a, bi[co] - mean*a);
}

// BN + relu + transpose (b,w,h,co) -> (b,co,h,w) fp32; grid (3, 96, 8)
__global__ __launch_bounds__(256) void k_bnout(const bf16* __restrict__ bt,
                                               const float2* __restrict__ ab,
                                               float* __restrict__ out){
  int w0 = blockIdx.x*32, h = blockIdx.y, b = blockIdx.z, t = threadIdx.x;
  __shared__ float Tl[32][33];
  for (int co0 = 0; co0 < 512; co0 += 32){
    for (int e = t; e < 1024; e += 256){
      int wl = e >> 5, co = e & 31;
      Tl[wl][co] = b2f(bt[(((size_t)b*96 + w0 + wl)*96 + h)*512 + co0 + co]);
    }
    __syncthreads();
    for (int e = t; e < 1024; e += 256){
      int co = e >> 5, wl = e & 31;
      float2 s = ab[co0 + co];
      float v = fmaxf(Tl[wl][co]*s.x + s.y, 0.0f);
      out[(((size_t)b*512 + co0 + co)*96 + h)*96 + w0 + wl] = v;
    }
    __syncthreads();
  }
}

// ---------------------------------------------------------------------------
extern "C" void kernel_launch(void* const* d_in, const int* in_sizes, int n_in,
                              void* d_out, int out_size, void* d_ws, size_t ws_size,
                              hipStream_t stream){
  (void)in_sizes; (void)n_in; (void)out_size; (void)ws_size;
  const float* low   = (const float*)d_in[0];
  const float* high  = (const float*)d_in[1];
  const float* c1w   = (const float*)d_in[2];
  const float* c1b   = (const float*)d_in[3];
  const float* c2w   = (const float*)d_in[4];
  const float* c2b   = (const float*)d_in[5];
  const float* qw    = (const float*)d_in[6];
  const float* qb    = (const float*)d_in[7];
  const float* kw    = (const float*)d_in[8];
  const float* kb    = (const float*)d_in[9];
  const float* vw    = (const float*)d_in[10];
  const float* vb    = (const float*)d_in[11];
  const float* gamma = (const float*)d_in[12];
  const float* bw    = (const float*)d_in[13];
  const float* bns   = (const float*)d_in[14];
  const float* bnb   = (const float*)d_in[15];
  float* out = (float*)d_out;

  char* wsb = (char*)d_ws;
  // workspace layout — total 223,027,328 bytes (~212.7 MB)
  bf16*   hf_t = (bf16*) (wsb + 0);            // 75,497,472  (b, x*96+y, 512)
  bf16*   vf_t = (bf16*) (wsb + 75497472);     // 37,748,736  (b, x*96+y, 256)
  bf16*   q_t  = (bf16*) (wsb + 113246208);    //  4,718,592
  bf16*   qq_wb= (bf16*) (wsb + 117964800);    //     32,768  (folded q weights, bf16 32x512)
  float*  qq_b = (float*)(wsb + 118030336);    //        128
  float*  s1   = (float*)(wsb + 118030464);    //      2,048
  float*  s2   = (float*)(wsb + 118032512);    //      2,048
  float2* ab   = (float2*)(wsb + 118034560);   //      4,096
  bf16*   wbb  = (bf16*) (wsb + 118038656);    //    786,432  (bneck W bf16, 512x768)
  bf16*   wc2  = (bf16*) (wsb + 118825088);    //    262,144  (conv2 W bf16, 256x512)
  bf16*   wv   = (bf16*) (wsb + 119087232);    //    131,072  (v W bf16, 256x256)
  bf16*   v_t  = (bf16*) (wsb + 119218304);    // 37,748,736
  bf16*   att  = (bf16*) (wsb + 156967040);    // 28,311,552
  bf16*   accb = (bf16*) (wsb + 185278592);    // 37,748,736 -> ends 223,027,328
  bf16*   k_t  = (bf16*) (wsb + 185278592);    //  4,718,592 (aliases accb head; dead before accb written)
  bf16*   bt   = (bf16*) (wsb + 119218304);    // 75,497,472 (aliases v_t/att/accb-head; all dead at bneck)

  k_zero<<<4, 256, 0, stream>>>(s1);
  k_cvt<<<1536, 256, 0, stream>>>(bw,  wbb, 393216);
  k_cvt<<<512,  256, 0, stream>>>(c2w, wc2, 131072);
  k_cvt<<<256,  256, 0, stream>>>(vw,  wv,  65536);
  k_upsample<<<dim3(96, 8), 256, 0, stream>>>(high, hf_t);
  k_qqw<<<64, 256, 0, stream>>>(qw, c1w, qq_wb);
  k_qqb<<<1, 64, 0, stream>>>(qw, c1b, qb, qq_b);
  k_mfma_gemm<<<dim3(72, 2, 8), 256, 0, stream>>>(hf_t, wc2, c2b, vf_t, 512, 256);
  k_qmfma<<<dim3(144, 8), 256, 0, stream>>>(low, qq_wb, qq_b, q_t);

  for (int r = 0; r < 2; r++){
    k_gemm_bb<128, 32><<<dim3(72, 1, 8), 256, 0, stream>>>(vf_t, kw, kb, k_t, 256, 32);
    k_mfma_gemm<<<dim3(72, 2, 8), 256, 0, stream>>>(vf_t, wv, vb, v_t, 256, 256);
    k_eH<<<dim3(96, 8), 256, 0, stream>>>(q_t, k_t, att);
    k_eW<<<dim3(96, 8), 256, 0, stream>>>(q_t, k_t, att);
    k_softmax<<<18432, 256, 0, stream>>>(att);
    k_outH_mfma<<<dim3(96, 8), 256, 0, stream>>>(att, v_t, accb);
    k_outW_mfma<<<dim3(96, 8), 256, 0, stream>>>(att, v_t, accb, gamma, vf_t);
  }

  k_bneck_mfma<<<dim3(72, 4, 8), 256, 0, stream>>>(vf_t, hf_t, wbb, bt, s1, s2);
  k_bnprep<<<2, 256, 0, stream>>>(s1, s2, bns, bnb, ab);
  k_bnout<<<dim3(3, 96, 8), 256, 0, stream>>>(bt, ab, out);
}

// Round 7
// 956.334 us; speedup vs baseline: 1.2621x; 1.0606x over previous
//
#include <hip/hip_runtime.h>
#include <hip/hip_bf16.h>

typedef __hip_bfloat16 bf16;
typedef __attribute__((ext_vector_type(8))) short short8;
typedef __attribute__((ext_vector_type(4))) float f32x4;

constexpr int kHW = 96 * 96;   // 9216

__device__ __forceinline__ float b2f(bf16 x){ return __bfloat162float(x); }
__device__ __forceinline__ bf16  f2b(float x){ return __float2bfloat16(x); }
__device__ __forceinline__ unsigned short b2u(bf16 x){ return *(unsigned short*)&x; }

// Swizzled LDS addressing for 32-element (64B) bf16 rows, 16B granules:
// element offset of granule g in row r, XOR-swizzled so each 16-lane
// quarter-wave covers all 8 bank-groups uniformly (2-way max = free).
#define SW(r, g) ((r)*32 + ((((g) ^ (((r) >> 1) & 3))) << 3))

// NOTE: __builtin_amdgcn_global_load_lds is permanently abandoned in this
// session: 3/3 container failures with it, 2/2 passes without.

// ---------------------------------------------------------------------------
// zero s1/s2 (1024 contiguous floats)
__global__ void k_zero(float* __restrict__ p){
  int i = blockIdx.x*256 + threadIdx.x;
  if (i < 1024) p[i] = 0.0f;
}

// fp32 -> bf16 weight conversion
__global__ void k_cvt(const float* __restrict__ s, bf16* __restrict__ d, int n){
  int i = blockIdx.x*256 + threadIdx.x;
  if (i < n) d[i] = f2b(s[i]);
}

// ---------------------------------------------------------------------------
// bilinear 2x upsample: high (b,512,48,48) fp32 -> hf_t (b, x96*96+y, c512) bf16
// grid (y=96, b=8), 256 thr
__global__ __launch_bounds__(256) void k_upsample(const float* __restrict__ hi,
                                                  bf16* __restrict__ hf_t){
  int y = blockIdx.x, b = blockIdx.y, t = threadIdx.x;
  int j = y >> 1;
  int j0, j1; float wy0, wy1;
  if ((y & 1) == 0){ j0 = j - 1; if (j0 < 0) j0 = 0; j1 = j; wy0 = 0.25f; wy1 = 0.75f; }
  else             { j0 = j; j1 = j + 1; if (j1 > 47) j1 = 47; wy0 = 0.75f; wy1 = 0.25f; }
  __shared__ __align__(16) float sm[2][128][49];
  for (int c0 = 0; c0 < 512; c0 += 128){
    for (int e = t; e < 2*128*48; e += 256){
      int cl = e / 96; int r = e % 96; int jj = r / 48; int i = r % 48;
      int row = jj ? j1 : j0;
      sm[jj][cl][i] = hi[(((size_t)b*512 + c0 + cl)*48 + row)*48 + i];
    }
    __syncthreads();
    for (int e = t; e < 96*128; e += 256){
      int x = e >> 7; int cl = e & 127;
      int i = x >> 1; int i0, i1; float wx0, wx1;
      if ((x & 1) == 0){ i0 = i - 1; if (i0 < 0) i0 = 0; i1 = i; wx0 = 0.25f; wx1 = 0.75f; }
      else             { i0 = i; i1 = i + 1; if (i1 > 47) i1 = 47; wx0 = 0.75f; wx1 = 0.25f; }
      float v = wy0*(wx0*sm[0][cl][i0] + wx1*sm[0][cl][i1])
              + wy1*(wx0*sm[1][cl][i0] + wx1*sm[1][cl][i1]);
      hf_t[(((size_t)b*96 + x)*96 + y)*512 + c0 + cl] = f2b(v);
    }
    __syncthreads();
  }
}

// ---------------------------------------------------------------------------
// fold q path: qq_wb[o,c] = bf16( sum_k q_w[o,k]*conv1_w[k,c] )  (32x512)
__global__ void k_qqw(const float* __restrict__ q_w, const float* __restrict__ c1_w,
                      bf16* __restrict__ qq_wb){
  int gid = blockIdx.x*256 + threadIdx.x;      // 16384
  int o = gid >> 9, c = gid & 511;
  float acc = 0.f;
  for (int k = 0; k < 256; k++) acc += q_w[o*256 + k] * c1_w[k*512 + c];
  qq_wb[gid] = f2b(acc);
}
__global__ void k_qqb(const float* __restrict__ q_w, const float* __restrict__ c1_b,
                      const float* __restrict__ q_b, float* __restrict__ qq_b){
  int o = threadIdx.x; if (o >= 32) return;
  float acc = q_b[o];
  for (int k = 0; k < 256; k++) acc += q_w[o*256 + k] * c1_b[k];
  qq_b[o] = acc;
}

// ---------------------------------------------------------------------------
// MFMA GEMM: out[b,n,o] = sum_k A[b,n,k]*Wb[o,k] (+bias[o])
// 128x128 block tile, 4 waves of 64x64, BK=32, double-buffered swizzled LDS
__global__ __launch_bounds__(256) void k_mfma_gemm(const bf16* __restrict__ A,
                                                   const bf16* __restrict__ Wb,
                                                   const float* __restrict__ bias,
                                                   bf16* __restrict__ out,
                                                   int K, int O){
  int b = blockIdx.z, n0 = blockIdx.x*128, o0 = blockIdx.y*128;
  int t = threadIdx.x, lane = t & 63, wv = t >> 6;
  int m_off = (wv & 1)*64, o_off = (wv >> 1)*64;
  int lm = lane & 15, lk = lane >> 4;
  __shared__ __align__(16) bf16 As[2][128*32];
  __shared__ __align__(16) bf16 Ws[2][128*32];
  f32x4 acc[4][4] = {};
  const bf16* Ab = A + (size_t)b*kHW*K;
  int nl0 = t >> 2, gp = t & 3, p0 = gp*8;
  uint4 pa0, pa1, pw0, pw1;
  pa0 = *(const uint4*)&Ab[(size_t)(n0+nl0)*K + p0];
  pa1 = *(const uint4*)&Ab[(size_t)(n0+nl0+64)*K + p0];
  pw0 = *(const uint4*)&Wb[(size_t)(o0+nl0)*K + p0];
  pw1 = *(const uint4*)&Wb[(size_t)(o0+nl0+64)*K + p0];
  *(uint4*)&As[0][SW(nl0, gp)]    = pa0;
  *(uint4*)&As[0][SW(nl0+64, gp)] = pa1;
  *(uint4*)&Ws[0][SW(nl0, gp)]    = pw0;
  *(uint4*)&Ws[0][SW(nl0+64, gp)] = pw1;
  int cur = 0;
  int NS = K >> 5;
  for (int s = 0; s < NS; s++){
    if (s+1 < NS){
      int c0 = (s+1)*32;
      pa0 = *(const uint4*)&Ab[(size_t)(n0+nl0)*K + c0 + p0];
      pa1 = *(const uint4*)&Ab[(size_t)(n0+nl0+64)*K + c0 + p0];
      pw0 = *(const uint4*)&Wb[(size_t)(o0+nl0)*K + c0 + p0];
      pw1 = *(const uint4*)&Wb[(size_t)(o0+nl0+64)*K + c0 + p0];
    }
    __syncthreads();
    short8 af[4], bfr[4];
    #pragma unroll
    for (int i = 0; i < 4; i++){
      af[i]  = *(const short8*)&As[cur][SW(m_off + i*16 + lm, lk)];
      bfr[i] = *(const short8*)&Ws[cur][SW(o_off + i*16 + lm, lk)];
    }
    #pragma unroll
    for (int i = 0; i < 4; i++)
      #pragma unroll
      for (int j = 0; j < 4; j++)
        acc[i][j] = __builtin_amdgcn_mfma_f32_16x16x32_bf16(af[i], bfr[j], acc[i][j], 0, 0, 0);
    if (s+1 < NS){
      int nx = cur ^ 1;
      *(uint4*)&As[nx][SW(nl0, gp)]    = pa0;
      *(uint4*)&As[nx][SW(nl0+64, gp)] = pa1;
      *(uint4*)&Ws[nx][SW(nl0, gp)]    = pw0;
      *(uint4*)&Ws[nx][SW(nl0+64, gp)] = pw1;
      cur = nx;
    }
  }
  #pragma unroll
  for (int j = 0; j < 4; j++){
    int oc = o0 + o_off + j*16 + lm;
    float bs = bias ? bias[oc] : 0.0f;
    #pragma unroll
    for (int i = 0; i < 4; i++){
      int rbase = n0 + m_off + i*16 + lk*4;
      #pragma unroll
      for (int r = 0; r < 4; r++)
        out[((size_t)b*kHW + rbase + r)*(size_t)O + oc] = f2b(acc[i][j][r] + bs);
    }
  }
}

// bottleneck MFMA: K=768 split A-source; double-buffered swizzled; fused BN stats
__global__ __launch_bounds__(256) void k_bneck_mfma(const bf16* __restrict__ vf,
                                                    const bf16* __restrict__ hf,
                                                    const bf16* __restrict__ Wb,
                                                    bf16* __restrict__ out,
                                                    float* __restrict__ s1,
                                                    float* __restrict__ s2){
  int b = blockIdx.z, n0 = blockIdx.x*128, o0 = blockIdx.y*128;
  int t = threadIdx.x, lane = t & 63, wv = t >> 6;
  int m_off = (wv & 1)*64, o_off = (wv >> 1)*64;
  int lm = lane & 15, lk = lane >> 4;
  __shared__ __align__(16) bf16 As[2][128*32];
  __shared__ __align__(16) bf16 Ws[2][128*32];
  __shared__ float l1[128];
  __shared__ float l2[128];
  if (t < 128){ l1[t] = 0.f; l2[t] = 0.f; }
  f32x4 acc[4][4] = {};
  int nl0 = t >> 2, gp = t & 3, p0 = gp*8;
  const bf16* vfb = vf + (size_t)b*kHW*256;
  const bf16* hfb = hf + (size_t)b*kHW*512;
  uint4 pa0, pa1, pw0, pw1;
  pa0 = *(const uint4*)&vfb[(size_t)(n0+nl0)*256 + p0];
  pa1 = *(const uint4*)&vfb[(size_t)(n0+nl0+64)*256 + p0];
  pw0 = *(const uint4*)&Wb[(size_t)(o0+nl0)*768 + p0];
  pw1 = *(const uint4*)&Wb[(size_t)(o0+nl0+64)*768 + p0];
  *(uint4*)&As[0][SW(nl0, gp)]    = pa0;
  *(uint4*)&As[0][SW(nl0+64, gp)] = pa1;
  *(uint4*)&Ws[0][SW(nl0, gp)]    = pw0;
  *(uint4*)&Ws[0][SW(nl0+64, gp)] = pw1;
  int cur = 0;
  for (int s = 0; s < 24; s++){
    if (s+1 < 24){
      int c0 = (s+1)*32;
      if (c0 < 256){
        pa0 = *(const uint4*)&vfb[(size_t)(n0+nl0)*256 + c0 + p0];
        pa1 = *(const uint4*)&vfb[(size_t)(n0+nl0+64)*256 + c0 + p0];
      } else {
        int cc = c0 - 256;
        pa0 = *(const uint4*)&hfb[(size_t)(n0+nl0)*512 + cc + p0];
        pa1 = *(const uint4*)&hfb[(size_t)(n0+nl0+64)*512 + cc + p0];
      }
      pw0 = *(const uint4*)&Wb[(size_t)(o0+nl0)*768 + c0 + p0];
      pw1 = *(const uint4*)&Wb[(size_t)(o0+nl0+64)*768 + c0 + p0];
    }
    __syncthreads();
    short8 af[4], bfr[4];
    #pragma unroll
    for (int i = 0; i < 4; i++){
      af[i]  = *(const short8*)&As[cur][SW(m_off + i*16 + lm, lk)];
      bfr[i] = *(const short8*)&Ws[cur][SW(o_off + i*16 + lm, lk)];
    }
    #pragma unroll
    for (int i = 0; i < 4; i++)
      #pragma unroll
      for (int j = 0; j < 4; j++)
        acc[i][j] = __builtin_amdgcn_mfma_f32_16x16x32_bf16(af[i], bfr[j], acc[i][j], 0, 0, 0);
    if (s+1 < 24){
      int nx = cur ^ 1;
      *(uint4*)&As[nx][SW(nl0, gp)]    = pa0;
      *(uint4*)&As[nx][SW(nl0+64, gp)] = pa1;
      *(uint4*)&Ws[nx][SW(nl0, gp)]    = pw0;
      *(uint4*)&Ws[nx][SW(nl0+64, gp)] = pw1;
      cur = nx;
    }
  }
  #pragma unroll
  for (int j = 0; j < 4; j++){
    int oc = o0 + o_off + j*16 + lm;
    float p1 = 0.f, p2 = 0.f;
    #pragma unroll
    for (int i = 0; i < 4; i++){
      int rbase = n0 + m_off + i*16 + lk*4;
      #pragma unroll
      for (int r = 0; r < 4; r++){
        float v = acc[i][j][r];
        p1 += v; p2 += v*v;
        out[((size_t)b*kHW + rbase + r)*512 + oc] = f2b(v);
      }
    }
    int cl = o_off + j*16 + lm;
    atomicAdd(&l1[cl], p1);
    atomicAdd(&l2[cl], p2);
  }
  __syncthreads();
  if (t < 128){
    atomicAdd(&s1[o0 + t], l1[t]);
    atomicAdd(&s2[o0 + t], l2[t]);
  }
}

// ---------------------------------------------------------------------------
// q via MFMA: q_t[b,x,h,o] = sum_c low[b,c,n]*qqw[o,c] + qq_b[o], n = h*96+x
// grid (144 n-tiles of 64, 8 b), 256 thr = 4 waves x 16 rows; K=512 in 16 steps
__global__ __launch_bounds__(256) void k_qmfma(const float* __restrict__ low,
                                               const bf16* __restrict__ qq_wb,
                                               const float* __restrict__ qq_b,
                                               bf16* __restrict__ q_t){
  int n0 = blockIdx.x*64, b = blockIdx.y, t = threadIdx.x;
  int lane = t & 63, wv = t >> 6;
  int m_off = wv*16;
  int lm = lane & 15, lk = lane >> 4;
  __shared__ __align__(16) bf16 As[64*36];
  __shared__ __align__(16) bf16 Ws[32*40];
  f32x4 acc[2] = {};
  const float* low_b = low + (size_t)b*512*kHW;
  int c2 = (t & 15)*2;     // c-pair within 32-step
  int xg = t >> 4;         // x-group (4 each), 0..15
  for (int c0 = 0; c0 < 512; c0 += 32){
    const float* p0 = low_b + (size_t)(c0 + c2)*kHW + n0 + xg*4;
    float4 a0 = *(const float4*)p0;
    float4 a1 = *(const float4*)(p0 + kHW);
    float f0[4] = {a0.x, a0.y, a0.z, a0.w};
    float f1[4] = {a1.x, a1.y, a1.z, a1.w};
    #pragma unroll
    for (int u = 0; u < 4; u++){
      ushort2 pr;
      bf16 v0 = f2b(f0[u]), v1 = f2b(f1[u]);
      pr.x = b2u(v0); pr.y = b2u(v1);
      *(ushort2*)&As[(xg*4 + u)*36 + c2] = pr;
    }
    if (t < 128){
      int ol = t >> 2, p = t & 3;
      *(uint4*)&Ws[ol*40 + p*8] = *(const uint4*)&qq_wb[(size_t)ol*512 + c0 + p*8];
    }
    __syncthreads();
    short8 af = *(const short8*)&As[(m_off + lm)*36 + lk*8];
    short8 b0 = *(const short8*)&Ws[lm*40 + lk*8];
    short8 b1 = *(const short8*)&Ws[(16 + lm)*40 + lk*8];
    acc[0] = __builtin_amdgcn_mfma_f32_16x16x32_bf16(af, b0, acc[0], 0, 0, 0);
    acc[1] = __builtin_amdgcn_mfma_f32_16x16x32_bf16(af, b1, acc[1], 0, 0, 0);
    __syncthreads();
  }
  #pragma unroll
  for (int j = 0; j < 2; j++){
    int oc = j*16 + lm;
    float bs = qq_b[oc];
    #pragma unroll
    for (int r = 0; r < 4; r++){
      int ng = n0 + m_off + lk*4 + r;
      int h = ng / 96, x = ng - h*96;
      q_t[(((size_t)b*96 + x)*96 + h)*32 + oc] = f2b(acc[j][r] + bs);
    }
  }
}

// ---------------------------------------------------------------------------
// k-projection via MFMA: k_t[b,n,o] = sum_c vf[b,n,c]*wk[o,c] + kb[o]; O=32, K=256
// grid (72 n-tiles of 128, 8 b), 256 thr, 4 waves of 32 rows; swizzled dbuf LDS
__global__ __launch_bounds__(256) void k_kmfma(const bf16* __restrict__ A,
                                               const bf16* __restrict__ Wk,
                                               const float* __restrict__ bias,
                                               bf16* __restrict__ out){
  int n0 = blockIdx.x*128, b = blockIdx.y;
  int t = threadIdx.x, lane = t & 63, wv = t >> 6;
  int m_off = wv*32;
  int lm = lane & 15, lk = lane >> 4;
  __shared__ __align__(16) bf16 As[2][128*32];
  __shared__ __align__(16) bf16 Ws[2][32*32];
  f32x4 acc[2][2] = {};
  const bf16* Ab = A + (size_t)b*kHW*256;
  int nl0 = t >> 2, gp = t & 3, p0 = gp*8;
  int ol = t >> 2;   // for W staging (t<128): rows 0..31
  uint4 pa0, pa1, pw;
  pa0 = *(const uint4*)&Ab[(size_t)(n0+nl0)*256 + p0];
  pa1 = *(const uint4*)&Ab[(size_t)(n0+nl0+64)*256 + p0];
  if (t < 128) pw = *(const uint4*)&Wk[(size_t)ol*256 + p0];
  *(uint4*)&As[0][SW(nl0, gp)]    = pa0;
  *(uint4*)&As[0][SW(nl0+64, gp)] = pa1;
  if (t < 128) *(uint4*)&Ws[0][SW(ol, gp)] = pw;
  int cur = 0;
  for (int s = 0; s < 8; s++){
    if (s+1 < 8){
      int c0 = (s+1)*32;
      pa0 = *(const uint4*)&Ab[(size_t)(n0+nl0)*256 + c0 + p0];
      pa1 = *(const uint4*)&Ab[(size_t)(n0+nl0+64)*256 + c0 + p0];
      if (t < 128) pw = *(const uint4*)&Wk[(size_t)ol*256 + c0 + p0];
    }
    __syncthreads();
    short8 af[2], bfr[2];
    #pragma unroll
    for (int i = 0; i < 2; i++)
      af[i] = *(const short8*)&As[cur][SW(m_off + i*16 + lm, lk)];
    #pragma unroll
    for (int j = 0; j < 2; j++)
      bfr[j] = *(const short8*)&Ws[cur][SW(j*16 + lm, lk)];
    #pragma unroll
    for (int i = 0; i < 2; i++)
      #pragma unroll
      for (int j = 0; j < 2; j++)
        acc[i][j] = __builtin_amdgcn_mfma_f32_16x16x32_bf16(af[i], bfr[j], acc[i][j], 0, 0, 0);
    if (s+1 < 8){
      int nx = cur ^ 1;
      *(uint4*)&As[nx][SW(nl0, gp)]    = pa0;
      *(uint4*)&As[nx][SW(nl0+64, gp)] = pa1;
      if (t < 128) *(uint4*)&Ws[nx][SW(ol, gp)] = pw;
      cur = nx;
    }
  }
  #pragma unroll
  for (int j = 0; j < 2; j++){
    int oc = j*16 + lm;
    float bs = bias[oc];
    #pragma unroll
    for (int i = 0; i < 2; i++){
      int rbase = n0 + m_off + i*16 + lk*4;
      #pragma unroll
      for (int r = 0; r < 4; r++)
        out[((size_t)b*kHW + rbase + r)*32 + oc] = f2b(acc[i][j][r] + bs);
    }
  }
}

// ---------------------------------------------------------------------------
// eH: att[b,h,w,j] = sum_c q_t[b,w,h,c]*k_t[b,w,j,c]  (-1e9 if j==h); grid (96 w, 8 b)
__global__ __launch_bounds__(256) void k_eH(const bf16* __restrict__ q_t,
                                            const bf16* __restrict__ k_t,
                                            bf16* __restrict__ att){
  int w = blockIdx.x, b = blockIdx.y, t = threadIdx.x;
  __shared__ float Qs[96][33];
  __shared__ float Ks[96][33];
  const bf16* Qp = q_t + (((size_t)b*96 + w)*96)*32;
  const bf16* Kp = k_t + (((size_t)b*96 + w)*96)*32;
  for (int e = t; e < 3072; e += 256){ Qs[e>>5][e&31] = b2f(Qp[e]); Ks[e>>5][e&31] = b2f(Kp[e]); }
  __syncthreads();
  int tj = t % 16, th = t / 16;
  float acc[6][6] = {};
  #pragma unroll 4
  for (int c = 0; c < 32; c++){
    float qa[6], kb[6];
    #pragma unroll
    for (int i = 0; i < 6; i++) qa[i] = Qs[th*6 + i][c];
    #pragma unroll
    for (int jj = 0; jj < 6; jj++) kb[jj] = Ks[tj*6 + jj][c];
    #pragma unroll
    for (int i = 0; i < 6; i++)
      #pragma unroll
      for (int jj = 0; jj < 6; jj++) acc[i][jj] += qa[i]*kb[jj];
  }
  #pragma unroll
  for (int i = 0; i < 6; i++){
    int h = th*6 + i;
    size_t base = (((size_t)b*96 + h)*96 + w)*192;
    #pragma unroll
    for (int jj = 0; jj < 6; jj++){
      int jg = tj*6 + jj;
      float e = acc[i][jj];
      if (jg == h) e += -1000000000.0f;
      att[base + jg] = f2b(e);
    }
  }
}

// eW: att[b,h,w,96+j] = sum_c q_t[b,w,h,c]*k_t[b,j,h,c]; grid (96 h, 8 b)
__global__ __launch_bounds__(256) void k_eW(const bf16* __restrict__ q_t,
                                            const bf16* __restrict__ k_t,
                                            bf16* __restrict__ att){
  int h = blockIdx.x, b = blockIdx.y, t = threadIdx.x;
  __shared__ float Qs[96][33];
  __shared__ float Ks[96][33];
  for (int e = t; e < 3072; e += 256){
    int wl = e >> 5, c = e & 31;
    size_t idx = (((size_t)b*96 + wl)*96 + h)*32 + c;
    Qs[wl][c] = b2f(q_t[idx]);
    Ks[wl][c] = b2f(k_t[idx]);
  }
  __syncthreads();
  int tj = t % 16, tw = t / 16;
  float acc[6][6] = {};
  #pragma unroll 4
  for (int c = 0; c < 32; c++){
    float qa[6], kb[6];
    #pragma unroll
    for (int i = 0; i < 6; i++) qa[i] = Qs[tw*6 + i][c];
    #pragma unroll
    for (int jj = 0; jj < 6; jj++) kb[jj] = Ks[tj*6 + jj][c];
    #pragma unroll
    for (int i = 0; i < 6; i++)
      #pragma unroll
      for (int jj = 0; jj < 6; jj++) acc[i][jj] += qa[i]*kb[jj];
  }
  #pragma unroll
  for (int i = 0; i < 6; i++){
    int wl = tw*6 + i;
    size_t base = (((size_t)b*96 + h)*96 + wl)*192 + 96;
    #pragma unroll
    for (int jj = 0; jj < 6; jj++) att[base + tj*6 + jj] = f2b(acc[i][jj]);
  }
}

// softmax over 192, one wave per row; grid 18432
__global__ __launch_bounds__(256) void k_softmax(bf16* __restrict__ att){
  int t = threadIdx.x;
  int row = blockIdx.x*4 + (t >> 6);
  int lane = t & 63;
  size_t base = (size_t)row * 192;
  float x0 = b2f(att[base + lane]);
  float x1 = b2f(att[base + 64 + lane]);
  float x2 = b2f(att[base + 128 + lane]);
  float m = fmaxf(x0, fmaxf(x1, x2));
  #pragma unroll
  for (int off = 32; off; off >>= 1) m = fmaxf(m, __shfl_xor(m, off));
  float e0 = __expf(x0 - m), e1 = __expf(x1 - m), e2 = __expf(x2 - m);
  float s = e0 + e1 + e2;
  #pragma unroll
  for (int off = 32; off; off >>= 1) s += __shfl_xor(s, off);
  float inv = 1.0f / s;
  att[base + lane]       = f2b(e0 * inv);
  att[base + 64 + lane]  = f2b(e1 * inv);
  att[base + 128 + lane] = f2b(e2 * inv);
}

// ---------------------------------------------------------------------------
// outH via MFMA: accb[b,w,h,c] = sum_j att[b,h,w,j]*v_t[b,w,j,c]; grid (96 w, 8 b)
__global__ __launch_bounds__(256) void k_outH_mfma(const bf16* __restrict__ att,
                                                   const bf16* __restrict__ v_t,
                                                   bf16* __restrict__ accb){
  int w = blockIdx.x, b = blockIdx.y, t = threadIdx.x;
  int lane = t & 63, wv = t >> 6;
  int m_off = (wv & 1)*48, o_off = (wv >> 1)*128;
  int lm = lane & 15, lk = lane >> 4;
  __shared__ __align__(16) bf16 As[96*36];
  __shared__ __align__(16) bf16 Vt[256*36];
  f32x4 acc[3][8] = {};
  const bf16* Vb = v_t + ((size_t)b*96 + w)*96*256;
  for (int j0 = 0; j0 < 96; j0 += 32){
    for (int e = t; e < 384; e += 256){
      int h = e >> 2, p = e & 3;
      *(uint4*)&As[h*36 + p*8] =
        *(const uint4*)&att[(((size_t)b*96 + h)*96 + w)*192 + j0 + p*8];
    }
    for (int e = t; e < 512; e += 256){
      int jj2 = (e & 15)*2, cg = e >> 4;   // cg 0..31 (8 c's each)
      const bf16* p = Vb + (size_t)(j0 + jj2)*256 + cg*8;
      uint4 a0 = *(const uint4*)p;
      uint4 a1 = *(const uint4*)(p + 256);
      const unsigned short* u0 = (const unsigned short*)&a0;
      const unsigned short* u1 = (const unsigned short*)&a1;
      #pragma unroll
      for (int u = 0; u < 8; u++){
        ushort2 pr; pr.x = u0[u]; pr.y = u1[u];
        *(ushort2*)&Vt[(cg*8 + u)*36 + jj2] = pr;
      }
    }
    __syncthreads();
    short8 af[3], bfr[8];
    #pragma unroll
    for (int i = 0; i < 3; i++)
      af[i] = *(const short8*)&As[(m_off + i*16 + lm)*36 + lk*8];
    #pragma unroll
    for (int j = 0; j < 8; j++)
      bfr[j] = *(const short8*)&Vt[(o_off + j*16 + lm)*36 + lk*8];
    #pragma unroll
    for (int i = 0; i < 3; i++)
      #pragma unroll
      for (int j = 0; j < 8; j++)
        acc[i][j] = __builtin_amdgcn_mfma_f32_16x16x32_bf16(af[i], bfr[j], acc[i][j], 0, 0, 0);
    __syncthreads();
  }
  #pragma unroll
  for (int j = 0; j < 8; j++){
    int c = o_off + j*16 + lm;
    #pragma unroll
    for (int i = 0; i < 3; i++){
      int hbase = m_off + i*16 + lk*4;
      #pragma unroll
      for (int r = 0; r < 4; r++)
        accb[(((size_t)b*96 + w)*96 + hbase + r)*256 + c] = f2b(acc[i][j][r]);
    }
  }
}

// outW via MFMA + residual: vf_t[b,w,h,c] += g*(accb[b,w,h,c] + sum_j attW[h,w,j]*v_t[b,j,h,c])
// grid (96 h, 8 b). out 96(w) x 256(c), K=96(j).
__global__ __launch_bounds__(256) void k_outW_mfma(const bf16* __restrict__ att,
                                                   const bf16* __restrict__ v_t,
                                                   const bf16* __restrict__ accb,
                                                   const float* __restrict__ gamma_p,
                                                   bf16* __restrict__ vf_t){
  int h = blockIdx.x, b = blockIdx.y, t = threadIdx.x;
  int lane = t & 63, wv = t >> 6;
  int m_off = (wv & 1)*48, o_off = (wv >> 1)*128;
  int lm = lane & 15, lk = lane >> 4;
  __shared__ __align__(16) bf16 As[96*36];
  __shared__ __align__(16) bf16 Vt[256*36];
  f32x4 acc[3][8] = {};
  for (int j0 = 0; j0 < 96; j0 += 32){
    for (int e = t; e < 384; e += 256){
      int wl = e >> 2, p = e & 3;
      *(uint4*)&As[wl*36 + p*8] =
        *(const uint4*)&att[(((size_t)b*96 + h)*96 + wl)*192 + 96 + j0 + p*8];
    }
    for (int e = t; e < 512; e += 256){
      int jj2 = (e & 15)*2, cg = e >> 4;
      const bf16* p = v_t + (((size_t)b*96 + j0 + jj2)*96 + h)*256 + cg*8;
      uint4 a0 = *(const uint4*)p;
      uint4 a1 = *(const uint4*)(p + 96*256);
      const unsigned short* u0 = (const unsigned short*)&a0;
      const unsigned short* u1 = (const unsigned short*)&a1;
      #pragma unroll
      for (int u = 0; u < 8; u++){
        ushort2 pr; pr.x = u0[u]; pr.y = u1[u];
        *(ushort2*)&Vt[(cg*8 + u)*36 + jj2] = pr;
      }
    }
    __syncthreads();
    short8 af[3], bfr[8];
    #pragma unroll
    for (int i = 0; i < 3; i++)
      af[i] = *(const short8*)&As[(m_off + i*16 + lm)*36 + lk*8];
    #pragma unroll
    for (int j = 0; j < 8; j++)
      bfr[j] = *(const short8*)&Vt[(o_off + j*16 + lm)*36 + lk*8];
    #pragma unroll
    for (int i = 0; i < 3; i++)
      #pragma unroll
      for (int j = 0; j < 8; j++)
        acc[i][j] = __builtin_amdgcn_mfma_f32_16x16x32_bf16(af[i], bfr[j], acc[i][j], 0, 0, 0);
    __syncthreads();
  }
  float g = gamma_p[0];
  #pragma unroll
  for (int j = 0; j < 8; j++){
    int c = o_off + j*16 + lm;
    #pragma unroll
    for (int i = 0; i < 3; i++){
      int wbase = m_off + i*16 + lk*4;
      #pragma unroll
      for (int r = 0; r < 4; r++){
        size_t idx = (((size_t)b*96 + wbase + r)*96 + h)*256 + c;
        vf_t[idx] = f2b(b2f(vf_t[idx]) + g*(acc[i][j][r] + b2f(accb[idx])));
      }
    }
  }
}

// ---------------------------------------------------------------------------
__global__ void k_bnprep(const float* __restrict__ s1, const float* __restrict__ s2,
                         const float* __restrict__ sc, const float* __restrict__ bi,
                         float2* __restrict__ ab){
  int co = blockIdx.x*256 + threadIdx.x;
  if (co >= 512) return;
  const float N = 73728.0f;
  float mean = s1[co] / N;
  float var  = s2[co] / N - mean*mean;
  if (var < 0.f) var = 0.f;
  float a = rsqrtf(var + 1e-5f) * sc[co];
  ab[co] = make_float2(a, bi[co] - mean*a);
}

// BN + relu + transpose (b,w,h,co) -> (b,co,h,w) fp32; grid (3, 96, 8)
__global__ __launch_bounds__(256) void k_bnout(const bf16* __restrict__ bt,
                                               const float2* __restrict__ ab,
                                               float* __restrict__ out){
  int w0 = blockIdx.x*32, h = blockIdx.y, b = blockIdx.z, t = threadIdx.x;
  __shared__ float Tl[32][33];
  for (int co0 = 0; co0 < 512; co0 += 32){
    for (int e = t; e < 1024; e += 256){
      int wl = e >> 5, co = e & 31;
      Tl[wl][co] = b2f(bt[(((size_t)b*96 + w0 + wl)*96 + h)*512 + co0 + co]);
    }
    __syncthreads();
    for (int e = t; e < 1024; e += 256){
      int co = e >> 5, wl = e & 31;
      float2 s = ab[co0 + co];
      float v = fmaxf(Tl[wl][co]*s.x + s.y, 0.0f);
      out[(((size_t)b*512 + co0 + co)*96 + h)*96 + w0 + wl] = v;
    }
    __syncthreads();
  }
}

// ---------------------------------------------------------------------------
extern "C" void kernel_launch(void* const* d_in, const int* in_sizes, int n_in,
                              void* d_out, int out_size, void* d_ws, size_t ws_size,
                              hipStream_t stream){
  (void)in_sizes; (void)n_in; (void)out_size; (void)ws_size;
  const float* low   = (const float*)d_in[0];
  const float* high  = (const float*)d_in[1];
  const float* c1w   = (const float*)d_in[2];
  const float* c1b   = (const float*)d_in[3];
  const float* c2w   = (const float*)d_in[4];
  const float* c2b   = (const float*)d_in[5];
  const float* qw    = (const float*)d_in[6];
  const float* qb    = (const float*)d_in[7];
  const float* kw    = (const float*)d_in[8];
  const float* kb    = (const float*)d_in[9];
  const float* vw    = (const float*)d_in[10];
  const float* vb    = (const float*)d_in[11];
  const float* gamma = (const float*)d_in[12];
  const float* bw    = (const float*)d_in[13];
  const float* bns   = (const float*)d_in[14];
  const float* bnb   = (const float*)d_in[15];
  float* out = (float*)d_out;

  char* wsb = (char*)d_ws;
  // workspace layout — total 223,027,328 bytes (~212.7 MB)
  bf16*   hf_t = (bf16*) (wsb + 0);            // 75,497,472  (b, x*96+y, 512)
  bf16*   vf_t = (bf16*) (wsb + 75497472);     // 37,748,736  (b, x*96+y, 256)
  bf16*   q_t  = (bf16*) (wsb + 113246208);    //  4,718,592
  bf16*   qq_wb= (bf16*) (wsb + 117964800);    //     32,768  (folded q weights, bf16 32x512)
  bf16*   wk   = (bf16*) (wsb + 117997568);    //     16,384  (k weights bf16, 32x256)
  float*  qq_b = (float*)(wsb + 118030336);    //        128
  float*  s1   = (float*)(wsb + 118030464);    //      2,048
  float*  s2   = (float*)(wsb + 118032512);    //      2,048
  float2* ab   = (float2*)(wsb + 118034560);   //      4,096
  bf16*   wbb  = (bf16*) (wsb + 118038656);    //    786,432  (bneck W bf16, 512x768)
  bf16*   wc2  = (bf16*) (wsb + 118825088);    //    262,144  (conv2 W bf16, 256x512)
  bf16*   wv   = (bf16*) (wsb + 119087232);    //    131,072  (v W bf16, 256x256)
  bf16*   v_t  = (bf16*) (wsb + 119218304);    // 37,748,736
  bf16*   att  = (bf16*) (wsb + 156967040);    // 28,311,552
  bf16*   accb = (bf16*) (wsb + 185278592);    // 37,748,736 -> ends 223,027,328
  bf16*   k_t  = (bf16*) (wsb + 185278592);    //  4,718,592 (aliases accb head; dead before accb written)
  bf16*   bt   = (bf16*) (wsb + 119218304);    // 75,497,472 (aliases v_t/att/accb-head; all dead at bneck)

  k_zero<<<4, 256, 0, stream>>>(s1);
  k_cvt<<<1536, 256, 0, stream>>>(bw,  wbb, 393216);
  k_cvt<<<512,  256, 0, stream>>>(c2w, wc2, 131072);
  k_cvt<<<256,  256, 0, stream>>>(vw,  wv,  65536);
  k_cvt<<<32,   256, 0, stream>>>(kw,  wk,  8192);
  k_upsample<<<dim3(96, 8), 256, 0, stream>>>(high, hf_t);
  k_qqw<<<64, 256, 0, stream>>>(qw, c1w, qq_wb);
  k_qqb<<<1, 64, 0, stream>>>(qw, c1b, qb, qq_b);
  k_mfma_gemm<<<dim3(72, 2, 8), 256, 0, stream>>>(hf_t, wc2, c2b, vf_t, 512, 256);
  k_qmfma<<<dim3(144, 8), 256, 0, stream>>>(low, qq_wb, qq_b, q_t);

  for (int r = 0; r < 2; r++){
    k_kmfma<<<dim3(72, 8), 256, 0, stream>>>(vf_t, wk, kb, k_t);
    k_mfma_gemm<<<dim3(72, 2, 8), 256, 0, stream>>>(vf_t, wv, vb, v_t, 256, 256);
    k_eH<<<dim3(96, 8), 256, 0, stream>>>(q_t, k_t, att);
    k_eW<<<dim3(96, 8), 256, 0, stream>>>(q_t, k_t, att);
    k_softmax<<<18432, 256, 0, stream>>>(att);
    k_outH_mfma<<<dim3(96, 8), 256, 0, stream>>>(att, v_t, accb);
    k_outW_mfma<<<dim3(96, 8), 256, 0, stream>>>(att, v_t, accb, gamma, vf_t);
  }

  k_bneck_mfma<<<dim3(72, 4, 8), 256, 0, stream>>>(vf_t, hf_t, wbb, bt, s1, s2);
  k_bnprep<<<2, 256, 0, stream>>>(s1, s2, bns, bnb, ab);
  k_bnout<<<dim3(3, 96, 8), 256, 0, stream>>>(bt, ab, out);
}

// Round 9
// 942.970 us; speedup vs baseline: 1.2800x; 1.0142x over previous
//
#include <hip/hip_runtime.h>
#include <hip/hip_bf16.h>

typedef __hip_bfloat16 bf16;
typedef __attribute__((ext_vector_type(8))) short short8;
typedef __attribute__((ext_vector_type(4))) float f32x4;

constexpr int kHW = 96 * 96;   // 9216

__device__ __forceinline__ float b2f(bf16 x){ return __bfloat162float(x); }
__device__ __forceinline__ bf16  f2b(float x){ return __float2bfloat16(x); }
__device__ __forceinline__ unsigned short b2u(bf16 x){ return *(unsigned short*)&x; }
__device__ __forceinline__ float s2f(short u){ return __uint_as_float(((unsigned)(unsigned short)u) << 16); }

// Swizzled LDS addressing for 32-element (64B) bf16 rows, 16B granules.
#define SW(r, g) ((r)*32 + ((((g) ^ (((r) >> 1) & 3))) << 3))

// 4x4 16x16x32 MFMA block from swizzled dbuf LDS buffer cb
#define MFMA_STEP(cb) do { \
  short8 af_[4], bf_[4]; \
  _Pragma("unroll") for (int i_ = 0; i_ < 4; i_++){ \
    af_[i_] = *(const short8*)&As[cb][SW(m_off + i_*16 + lm, lk)]; \
    bf_[i_] = *(const short8*)&Ws[cb][SW(o_off + i_*16 + lm, lk)]; } \
  _Pragma("unroll") for (int i_ = 0; i_ < 4; i_++) \
    _Pragma("unroll") for (int j_ = 0; j_ < 4; j_++) \
      acc[i_][j_] = __builtin_amdgcn_mfma_f32_16x16x32_bf16(af_[i_], bf_[j_], acc[i_][j_], 0, 0, 0); \
} while(0)

// NOTE: __builtin_amdgcn_global_load_lds is permanently abandoned in this
// session: 3/3 container failures with it, 2/2 passes without.

// ---------------------------------------------------------------------------
__global__ void k_zero(float* __restrict__ p){
  int i = blockIdx.x*256 + threadIdx.x;
  if (i < 1024) p[i] = 0.0f;
}

__global__ void k_cvt(const float* __restrict__ s, bf16* __restrict__ d, int n){
  int i = blockIdx.x*256 + threadIdx.x;
  if (i < n) d[i] = f2b(s[i]);
}

// ---------------------------------------------------------------------------
// bilinear 2x upsample: high (b,512,48,48) fp32 -> hf_t (b, x96*96+y, c512) bf16
__global__ __launch_bounds__(256) void k_upsample(const float* __restrict__ hi,
                                                  bf16* __restrict__ hf_t){
  int y = blockIdx.x, b = blockIdx.y, t = threadIdx.x;
  int j = y >> 1;
  int j0, j1; float wy0, wy1;
  if ((y & 1) == 0){ j0 = j - 1; if (j0 < 0) j0 = 0; j1 = j; wy0 = 0.25f; wy1 = 0.75f; }
  else             { j0 = j; j1 = j + 1; if (j1 > 47) j1 = 47; wy0 = 0.75f; wy1 = 0.25f; }
  __shared__ __align__(16) float sm[2][128][49];
  for (int c0 = 0; c0 < 512; c0 += 128){
    for (int e = t; e < 2*128*48; e += 256){
      int cl = e / 96; int r = e % 96; int jj = r / 48; int i = r % 48;
      int row = jj ? j1 : j0;
      sm[jj][cl][i] = hi[(((size_t)b*512 + c0 + cl)*48 + row)*48 + i];
    }
    __syncthreads();
    for (int e = t; e < 96*128; e += 256){
      int x = e >> 7; int cl = e & 127;
      int i = x >> 1; int i0, i1; float wx0, wx1;
      if ((x & 1) == 0){ i0 = i - 1; if (i0 < 0) i0 = 0; i1 = i; wx0 = 0.25f; wx1 = 0.75f; }
      else             { i0 = i; i1 = i + 1; if (i1 > 47) i1 = 47; wx0 = 0.75f; wx1 = 0.25f; }
      float v = wy0*(wx0*sm[0][cl][i0] + wx1*sm[0][cl][i1])
              + wy1*(wx0*sm[1][cl][i0] + wx1*sm[1][cl][i1]);
      hf_t[(((size_t)b*96 + x)*96 + y)*512 + c0 + cl] = f2b(v);
    }
    __syncthreads();
  }
}

// ---------------------------------------------------------------------------
__global__ void k_qqw(const float* __restrict__ q_w, const float* __restrict__ c1_w,
                      bf16* __restrict__ qq_wb){
  int gid = blockIdx.x*256 + threadIdx.x;      // 16384
  int o = gid >> 9, c = gid & 511;
  float acc = 0.f;
  for (int k = 0; k < 256; k++) acc += q_w[o*256 + k] * c1_w[k*512 + c];
  qq_wb[gid] = f2b(acc);
}
__global__ void k_qqb(const float* __restrict__ q_w, const float* __restrict__ c1_b,
                      const float* __restrict__ q_b, float* __restrict__ qq_b){
  int o = threadIdx.x; if (o >= 32) return;
  float acc = q_b[o];
  for (int k = 0; k < 256; k++) acc += q_w[o*256 + k] * c1_b[k];
  qq_b[o] = acc;
}

// ---------------------------------------------------------------------------
// MFMA GEMM: 128x128 tile, 4 waves of 64x64, BK=32, swizzled dbuf LDS,
// 3-stage pipeline: A loaded 2 K-steps ahead (2 reg sets), W 1 step ahead.
__global__ __launch_bounds__(256) void k_mfma_gemm(const bf16* __restrict__ A,
                                                   const bf16* __restrict__ Wb,
                                                   const float* __restrict__ bias,
                                                   bf16* __restrict__ out,
                                                   int K, int O){
  int b = blockIdx.z, n0 = blockIdx.x*128, o0 = blockIdx.y*128;
  int t = threadIdx.x, lane = t & 63, wv = t >> 6;
  int m_off = (wv & 1)*64, o_off = (wv >> 1)*64;
  int lm = lane & 15, lk = lane >> 4;
  __shared__ __align__(16) bf16 As[2][128*32];
  __shared__ __align__(16) bf16 Ws[2][128*32];
  f32x4 acc[4][4] = {};
  const bf16* Ab = A + (size_t)b*kHW*K;
  int nl0 = t >> 2, gp = t & 3, p0 = gp*8;
  const bf16* ar0 = Ab + (size_t)(n0+nl0)*K + p0;
  const bf16* ar1 = Ab + (size_t)(n0+nl0+64)*K + p0;
  const bf16* wr0 = Wb + (size_t)(o0+nl0)*K + p0;
  const bf16* wr1 = Wb + (size_t)(o0+nl0+64)*K + p0;
  int NS = K >> 5;   // 8 or 16, always even >= 8
  // prologue: step 0 -> L0
  {
    uint4 t0 = *(const uint4*)ar0;
    uint4 t1 = *(const uint4*)ar1;
    uint4 t2 = *(const uint4*)wr0;
    uint4 t3 = *(const uint4*)wr1;
    *(uint4*)&As[0][SW(nl0, gp)]    = t0;
    *(uint4*)&As[0][SW(nl0+64, gp)] = t1;
    *(uint4*)&Ws[0][SW(nl0, gp)]    = t2;
    *(uint4*)&Ws[0][SW(nl0+64, gp)] = t3;
  }
  uint4 Aa0, Aa1, Ab0, Ab1, Wx0, Wx1, Wy0, Wy1;
  Aa0 = *(const uint4*)(ar0 + 32);   // step 1
  Aa1 = *(const uint4*)(ar1 + 32);
  for (int s = 0; s < NS; s += 2){
    // even step s: compute L0, fill L1 with step s+1
    if (s+2 < NS){ Ab0 = *(const uint4*)(ar0 + (s+2)*32); Ab1 = *(const uint4*)(ar1 + (s+2)*32); }
    Wx0 = *(const uint4*)(wr0 + (s+1)*32);
    Wx1 = *(const uint4*)(wr1 + (s+1)*32);
    __syncthreads();
    MFMA_STEP(0);
    *(uint4*)&As[1][SW(nl0, gp)]    = Aa0;
    *(uint4*)&As[1][SW(nl0+64, gp)] = Aa1;
    *(uint4*)&Ws[1][SW(nl0, gp)]    = Wx0;
    *(uint4*)&Ws[1][SW(nl0+64, gp)] = Wx1;
    // odd step s+1: compute L1, fill L0 with step s+2
    if (s+3 < NS){ Aa0 = *(const uint4*)(ar0 + (s+3)*32); Aa1 = *(const uint4*)(ar1 + (s+3)*32); }
    if (s+2 < NS){ Wy0 = *(const uint4*)(wr0 + (s+2)*32); Wy1 = *(const uint4*)(wr1 + (s+2)*32); }
    __syncthreads();
    MFMA_STEP(1);
    if (s+2 < NS){
      *(uint4*)&As[0][SW(nl0, gp)]    = Ab0;
      *(uint4*)&As[0][SW(nl0+64, gp)] = Ab1;
      *(uint4*)&Ws[0][SW(nl0, gp)]    = Wy0;
      *(uint4*)&Ws[0][SW(nl0+64, gp)] = Wy1;
    }
  }
  #pragma unroll
  for (int j = 0; j < 4; j++){
    int oc = o0 + o_off + j*16 + lm;
    float bs = bias ? bias[oc] : 0.0f;
    #pragma unroll
    for (int i = 0; i < 4; i++){
      int rbase = n0 + m_off + i*16 + lk*4;
      #pragma unroll
      for (int r = 0; r < 4; r++)
        out[((size_t)b*kHW + rbase + r)*(size_t)O + oc] = f2b(acc[i][j][r] + bs);
    }
  }
}

// bottleneck MFMA: K=768 split A-source; 3-stage pipeline; fused BN stats
__device__ __forceinline__ const bf16* bneck_aptr(const bf16* vfb, const bf16* hfb,
                                                  int nrow, int p0, int s){
  int c0 = s*32;
  return (c0 < 256) ? vfb + (size_t)nrow*256 + c0 + p0
                    : hfb + (size_t)nrow*512 + (c0 - 256) + p0;
}

__global__ __launch_bounds__(256) void k_bneck_mfma(const bf16* __restrict__ vf,
                                                    const bf16* __restrict__ hf,
                                                    const bf16* __restrict__ Wb,
                                                    bf16* __restrict__ out,
                                                    float* __restrict__ s1,
                                                    float* __restrict__ s2){
  int b = blockIdx.z, n0 = blockIdx.x*128, o0 = blockIdx.y*128;
  int t = threadIdx.x, lane = t & 63, wv = t >> 6;
  int m_off = (wv & 1)*64, o_off = (wv >> 1)*64;
  int lm = lane & 15, lk = lane >> 4;
  __shared__ __align__(16) bf16 As[2][128*32];
  __shared__ __align__(16) bf16 Ws[2][128*32];
  __shared__ float l1[128];
  __shared__ float l2[128];
  if (t < 128){ l1[t] = 0.f; l2[t] = 0.f; }
  f32x4 acc[4][4] = {};
  int nl0 = t >> 2, gp = t & 3, p0 = gp*8;
  const bf16* vfb = vf + (size_t)b*kHW*256;
  const bf16* hfb = hf + (size_t)b*kHW*512;
  const bf16* wr0 = Wb + (size_t)(o0+nl0)*768 + p0;
  const bf16* wr1 = Wb + (size_t)(o0+nl0+64)*768 + p0;
  int r0 = n0 + nl0, r1 = n0 + nl0 + 64;
  // prologue: step 0 -> L0
  {
    uint4 t0 = *(const uint4*)bneck_aptr(vfb, hfb, r0, p0, 0);
    uint4 t1 = *(const uint4*)bneck_aptr(vfb, hfb, r1, p0, 0);
    uint4 t2 = *(const uint4*)wr0;
    uint4 t3 = *(const uint4*)wr1;
    *(uint4*)&As[0][SW(nl0, gp)]    = t0;
    *(uint4*)&As[0][SW(nl0+64, gp)] = t1;
    *(uint4*)&Ws[0][SW(nl0, gp)]    = t2;
    *(uint4*)&Ws[0][SW(nl0+64, gp)] = t3;
  }
  uint4 Aa0, Aa1, Ab0, Ab1, Wx0, Wx1, Wy0, Wy1;
  Aa0 = *(const uint4*)bneck_aptr(vfb, hfb, r0, p0, 1);
  Aa1 = *(const uint4*)bneck_aptr(vfb, hfb, r1, p0, 1);
  for (int s = 0; s < 24; s += 2){
    if (s+2 < 24){
      Ab0 = *(const uint4*)bneck_aptr(vfb, hfb, r0, p0, s+2);
      Ab1 = *(const uint4*)bneck_aptr(vfb, hfb, r1, p0, s+2);
    }
    Wx0 = *(const uint4*)(wr0 + (s+1)*32);
    Wx1 = *(const uint4*)(wr1 + (s+1)*32);
    __syncthreads();
    MFMA_STEP(0);
    *(uint4*)&As[1][SW(nl0, gp)]    = Aa0;
    *(uint4*)&As[1][SW(nl0+64, gp)] = Aa1;
    *(uint4*)&Ws[1][SW(nl0, gp)]    = Wx0;
    *(uint4*)&Ws[1][SW(nl0+64, gp)] = Wx1;
    if (s+3 < 24){
      Aa0 = *(const uint4*)bneck_aptr(vfb, hfb, r0, p0, s+3);
      Aa1 = *(const uint4*)bneck_aptr(vfb, hfb, r1, p0, s+3);
    }
    if (s+2 < 24){
      Wy0 = *(const uint4*)(wr0 + (s+2)*32);
      Wy1 = *(const uint4*)(wr1 + (s+2)*32);
    }
    __syncthreads();
    MFMA_STEP(1);
    if (s+2 < 24){
      *(uint4*)&As[0][SW(nl0, gp)]    = Ab0;
      *(uint4*)&As[0][SW(nl0+64, gp)] = Ab1;
      *(uint4*)&Ws[0][SW(nl0, gp)]    = Wy0;
      *(uint4*)&Ws[0][SW(nl0+64, gp)] = Wy1;
    }
  }
  // epilogue: C-write + fused BN stats (fp32, pre-rounding)
  #pragma unroll
  for (int j = 0; j < 4; j++){
    int oc = o0 + o_off + j*16 + lm;
    float p1 = 0.f, p2 = 0.f;
    #pragma unroll
    for (int i = 0; i < 4; i++){
      int rbase = n0 + m_off + i*16 + lk*4;
      #pragma unroll
      for (int r = 0; r < 4; r++){
        float v = acc[i][j][r];
        p1 += v; p2 += v*v;
        out[((size_t)b*kHW + rbase + r)*512 + oc] = f2b(v);
      }
    }
    int cl = o_off + j*16 + lm;
    atomicAdd(&l1[cl], p1);
    atomicAdd(&l2[cl], p2);
  }
  __syncthreads();
  if (t < 128){
    atomicAdd(&s1[o0 + t], l1[t]);
    atomicAdd(&s2[o0 + t], l2[t]);
  }
}

// ---------------------------------------------------------------------------
// q via MFMA: q_t[b,x,h,o] = sum_c low[b,c,n]*qqw[o,c] + qq_b[o], n = h*96+x
__global__ __launch_bounds__(256) void k_qmfma(const float* __restrict__ low,
                                               const bf16* __restrict__ qq_wb,
                                               const float* __restrict__ qq_b,
                                               bf16* __restrict__ q_t){
  int n0 = blockIdx.x*64, b = blockIdx.y, t = threadIdx.x;
  int lane = t & 63, wv = t >> 6;
  int m_off = wv*16;
  int lm = lane & 15, lk = lane >> 4;
  __shared__ __align__(16) bf16 As[64*36];
  __shared__ __align__(16) bf16 Ws[32*40];
  f32x4 acc[2] = {};
  const float* low_b = low + (size_t)b*512*kHW;
  int c2 = (t & 15)*2;
  int xg = t >> 4;
  for (int c0 = 0; c0 < 512; c0 += 32){
    const float* p0 = low_b + (size_t)(c0 + c2)*kHW + n0 + xg*4;
    float4 a0 = *(const float4*)p0;
    float4 a1 = *(const float4*)(p0 + kHW);
    float f0[4] = {a0.x, a0.y, a0.z, a0.w};
    float f1[4] = {a1.x, a1.y, a1.z, a1.w};
    #pragma unroll
    for (int u = 0; u < 4; u++){
      ushort2 pr;
      bf16 v0 = f2b(f0[u]), v1 = f2b(f1[u]);
      pr.x = b2u(v0); pr.y = b2u(v1);
      *(ushort2*)&As[(xg*4 + u)*36 + c2] = pr;
    }
    if (t < 128){
      int ol = t >> 2, p = t & 3;
      *(uint4*)&Ws[ol*40 + p*8] = *(const uint4*)&qq_wb[(size_t)ol*512 + c0 + p*8];
    }
    __syncthreads();
    short8 af = *(const short8*)&As[(m_off + lm)*36 + lk*8];
    short8 b0 = *(const short8*)&Ws[lm*40 + lk*8];
    short8 b1 = *(const short8*)&Ws[(16 + lm)*40 + lk*8];
    acc[0] = __builtin_amdgcn_mfma_f32_16x16x32_bf16(af, b0, acc[0], 0, 0, 0);
    acc[1] = __builtin_amdgcn_mfma_f32_16x16x32_bf16(af, b1, acc[1], 0, 0, 0);
    __syncthreads();
  }
  #pragma unroll
  for (int j = 0; j < 2; j++){
    int oc = j*16 + lm;
    float bs = qq_b[oc];
    #pragma unroll
    for (int r = 0; r < 4; r++){
      int ng = n0 + m_off + lk*4 + r;
      int h = ng / 96, x = ng - h*96;
      q_t[(((size_t)b*96 + x)*96 + h)*32 + oc] = f2b(acc[j][r] + bs);
    }
  }
}

// ---------------------------------------------------------------------------
// k-projection via MFMA: O=32, K=256; swizzled dbuf LDS
__global__ __launch_bounds__(256) void k_kmfma(const bf16* __restrict__ A,
                                               const bf16* __restrict__ Wk,
                                               const float* __restrict__ bias,
                                               bf16* __restrict__ out){
  int n0 = blockIdx.x*128, b = blockIdx.y;
  int t = threadIdx.x, lane = t & 63, wv = t >> 6;
  int m_off = wv*32;
  int lm = lane & 15, lk = lane >> 4;
  __shared__ __align__(16) bf16 As[2][128*32];
  __shared__ __align__(16) bf16 Ws[2][32*32];
  f32x4 acc[2][2] = {};
  const bf16* Ab = A + (size_t)b*kHW*256;
  int nl0 = t >> 2, gp = t & 3, p0 = gp*8;
  int ol = t >> 2;
  uint4 pa0, pa1, pw;
  pa0 = *(const uint4*)&Ab[(size_t)(n0+nl0)*256 + p0];
  pa1 = *(const uint4*)&Ab[(size_t)(n0+nl0+64)*256 + p0];
  if (t < 128) pw = *(const uint4*)&Wk[(size_t)ol*256 + p0];
  *(uint4*)&As[0][SW(nl0, gp)]    = pa0;
  *(uint4*)&As[0][SW(nl0+64, gp)] = pa1;
  if (t < 128) *(uint4*)&Ws[0][SW(ol, gp)] = pw;
  int cur = 0;
  for (int s = 0; s < 8; s++){
    if (s+1 < 8){
      int c0 = (s+1)*32;
      pa0 = *(const uint4*)&Ab[(size_t)(n0+nl0)*256 + c0 + p0];
      pa1 = *(const uint4*)&Ab[(size_t)(n0+nl0+64)*256 + c0 + p0];
      if (t < 128) pw = *(const uint4*)&Wk[(size_t)ol*256 + c0 + p0];
    }
    __syncthreads();
    short8 af[2], bfr[2];
    #pragma unroll
    for (int i = 0; i < 2; i++)
      af[i] = *(const short8*)&As[cur][SW(m_off + i*16 + lm, lk)];
    #pragma unroll
    for (int j = 0; j < 2; j++)
      bfr[j] = *(const short8*)&Ws[cur][SW(j*16 + lm, lk)];
    #pragma unroll
    for (int i = 0; i < 2; i++)
      #pragma unroll
      for (int j = 0; j < 2; j++)
        acc[i][j] = __builtin_amdgcn_mfma_f32_16x16x32_bf16(af[i], bfr[j], acc[i][j], 0, 0, 0);
    if (s+1 < 8){
      int nx = cur ^ 1;
      *(uint4*)&As[nx][SW(nl0, gp)]    = pa0;
      *(uint4*)&As[nx][SW(nl0+64, gp)] = pa1;
      if (t < 128) *(uint4*)&Ws[nx][SW(ol, gp)] = pw;
      cur = nx;
    }
  }
  #pragma unroll
  for (int j = 0; j < 2; j++){
    int oc = j*16 + lm;
    float bs = bias[oc];
    #pragma unroll
    for (int i = 0; i < 2; i++){
      int rbase = n0 + m_off + i*16 + lk*4;
      #pragma unroll
      for (int r = 0; r < 4; r++)
        out[((size_t)b*kHW + rbase + r)*32 + oc] = f2b(acc[i][j][r] + bs);
    }
  }
}

// ---------------------------------------------------------------------------
// eH: att[b,h,w,j] = sum_c q_t[b,w,h,c]*k_t[b,w,j,c]  (-1e9 if j==h); grid (96 w, 8 b)
__global__ __launch_bounds__(256) void k_eH(const bf16* __restrict__ q_t,
                                            const bf16* __restrict__ k_t,
                                            bf16* __restrict__ att){
  int w = blockIdx.x, b = blockIdx.y, t = threadIdx.x;
  __shared__ __align__(16) float Qs[96][36];
  __shared__ __align__(16) float Ks[96][36];
  const bf16* Qp = q_t + (((size_t)b*96 + w)*96)*32;
  const bf16* Kp = k_t + (((size_t)b*96 + w)*96)*32;
  for (int e = t; e < 384; e += 256){
    int row = e >> 2, cg = (e & 3)*8;
    short8 qv = *(const short8*)&Qp[row*32 + cg];
    short8 kv = *(const short8*)&Kp[row*32 + cg];
    float4 q0 = {s2f(qv[0]), s2f(qv[1]), s2f(qv[2]), s2f(qv[3])};
    float4 q1 = {s2f(qv[4]), s2f(qv[5]), s2f(qv[6]), s2f(qv[7])};
    float4 k0 = {s2f(kv[0]), s2f(kv[1]), s2f(kv[2]), s2f(kv[3])};
    float4 k1 = {s2f(kv[4]), s2f(kv[5]), s2f(kv[6]), s2f(kv[7])};
    *(float4*)&Qs[row][cg]     = q0;
    *(float4*)&Qs[row][cg + 4] = q1;
    *(float4*)&Ks[row][cg]     = k0;
    *(float4*)&Ks[row][cg + 4] = k1;
  }
  __syncthreads();
  int tj = t % 16, th = t / 16;
  float acc[6][6] = {};
  #pragma unroll 4
  for (int c = 0; c < 32; c++){
    float qa[6], kb[6];
    #pragma unroll
    for (int i = 0; i < 6; i++) qa[i] = Qs[th*6 + i][c];
    #pragma unroll
    for (int jj = 0; jj < 6; jj++) kb[jj] = Ks[tj*6 + jj][c];
    #pragma unroll
    for (int i = 0; i < 6; i++)
      #pragma unroll
      for (int jj = 0; jj < 6; jj++) acc[i][jj] += qa[i]*kb[jj];
  }
  #pragma unroll
  for (int i = 0; i < 6; i++){
    int h = th*6 + i;
    size_t base = (((size_t)b*96 + h)*96 + w)*192;
    #pragma unroll
    for (int jj = 0; jj < 6; jj++){
      int jg = tj*6 + jj;
      float e = acc[i][jj];
      if (jg == h) e += -1000000000.0f;
      att[base + jg] = f2b(e);
    }
  }
}

// eW: att[b,h,w,96+j] = sum_c q_t[b,w,h,c]*k_t[b,j,h,c]; grid (96 h, 8 b)
__global__ __launch_bounds__(256) void k_eW(const bf16* __restrict__ q_t,
                                            const bf16* __restrict__ k_t,
                                            bf16* __restrict__ att){
  int h = blockIdx.x, b = blockIdx.y, t = threadIdx.x;
  __shared__ __align__(16) float Qs[96][36];
  __shared__ __align__(16) float Ks[96][36];
  for (int e = t; e < 384; e += 256){
    int wl = e >> 2, cg = (e & 3)*8;
    size_t idx = (((size_t)b*96 + wl)*96 + h)*32 + cg;
    short8 qv = *(const short8*)&q_t[idx];
    short8 kv = *(const short8*)&k_t[idx];
    float4 q0 = {s2f(qv[0]), s2f(qv[1]), s2f(qv[2]), s2f(qv[3])};
    float4 q1 = {s2f(qv[4]), s2f(qv[5]), s2f(qv[6]), s2f(qv[7])};
    float4 k0 = {s2f(kv[0]), s2f(kv[1]), s2f(kv[2]), s2f(kv[3])};
    float4 k1 = {s2f(kv[4]), s2f(kv[5]), s2f(kv[6]), s2f(kv[7])};
    *(float4*)&Qs[wl][cg]     = q0;
    *(float4*)&Qs[wl][cg + 4] = q1;
    *(float4*)&Ks[wl][cg]     = k0;
    *(float4*)&Ks[wl][cg + 4] = k1;
  }
  __syncthreads();
  int tj = t % 16, tw = t / 16;
  float acc[6][6] = {};
  #pragma unroll 4
  for (int c = 0; c < 32; c++){
    float qa[6], kb[6];
    #pragma unroll
    for (int i = 0; i < 6; i++) qa[i] = Qs[tw*6 + i][c];
    #pragma unroll
    for (int jj = 0; jj < 6; jj++) kb[jj] = Ks[tj*6 + jj][c];
    #pragma unroll
    for (int i = 0; i < 6; i++)
      #pragma unroll
      for (int jj = 0; jj < 6; jj++) acc[i][jj] += qa[i]*kb[jj];
  }
  #pragma unroll
  for (int i = 0; i < 6; i++){
    int wl = tw*6 + i;
    size_t base = (((size_t)b*96 + h)*96 + wl)*192 + 96;
    #pragma unroll
    for (int jj = 0; jj < 6; jj++) att[base + tj*6 + jj] = f2b(acc[i][jj]);
  }
}

// softmax over 192, one wave per row; grid 18432
__global__ __launch_bounds__(256) void k_softmax(bf16* __restrict__ att){
  int t = threadIdx.x;
  int row = blockIdx.x*4 + (t >> 6);
  int lane = t & 63;
  size_t base = (size_t)row * 192;
  float x0 = b2f(att[base + lane]);
  float x1 = b2f(att[base + 64 + lane]);
  float x2 = b2f(att[base + 128 + lane]);
  float m = fmaxf(x0, fmaxf(x1, x2));
  #pragma unroll
  for (int off = 32; off; off >>= 1) m = fmaxf(m, __shfl_xor(m, off));
  float e0 = __expf(x0 - m), e1 = __expf(x1 - m), e2 = __expf(x2 - m);
  float s = e0 + e1 + e2;
  #pragma unroll
  for (int off = 32; off; off >>= 1) s += __shfl_xor(s, off);
  float inv = 1.0f / s;
  att[base + lane]       = f2b(e0 * inv);
  att[base + 64 + lane]  = f2b(e1 * inv);
  att[base + 128 + lane] = f2b(e2 * inv);
}

// ---------------------------------------------------------------------------
// outH via MFMA: accb[b,w,h,c] = sum_j att[b,h,w,j]*v_t[b,w,j,c]; grid (96 w, 8 b)
__global__ __launch_bounds__(256) void k_outH_mfma(const bf16* __restrict__ att,
                                                   const bf16* __restrict__ v_t,
                                                   bf16* __restrict__ accb){
  int w = blockIdx.x, b = blockIdx.y, t = threadIdx.x;
  int lane = t & 63, wv = t >> 6;
  int m_off = (wv & 1)*48, o_off = (wv >> 1)*128;
  int lm = lane & 15, lk = lane >> 4;
  __shared__ __align__(16) bf16 As[96*36];
  __shared__ __align__(16) bf16 Vt[256*36];
  f32x4 acc[3][8] = {};
  const bf16* Vb = v_t + ((size_t)b*96 + w)*96*256;
  for (int j0 = 0; j0 < 96; j0 += 32){
    for (int e = t; e < 384; e += 256){
      int h = e >> 2, p = e & 3;
      *(uint4*)&As[h*36 + p*8] =
        *(const uint4*)&att[(((size_t)b*96 + h)*96 + w)*192 + j0 + p*8];
    }
    for (int e = t; e < 512; e += 256){
      int jj2 = (e & 15)*2, cg = e >> 4;
      const bf16* p = Vb + (size_t)(j0 + jj2)*256 + cg*8;
      uint4 a0 = *(const uint4*)p;
      uint4 a1 = *(const uint4*)(p + 256);
      const unsigned short* u0 = (const unsigned short*)&a0;
      const unsigned short* u1 = (const unsigned short*)&a1;
      #pragma unroll
      for (int u = 0; u < 8; u++){
        ushort2 pr; pr.x = u0[u]; pr.y = u1[u];
        *(ushort2*)&Vt[(cg*8 + u)*36 + jj2] = pr;
      }
    }
    __syncthreads();
    short8 af[3], bfr[8];
    #pragma unroll
    for (int i = 0; i < 3; i++)
      af[i] = *(const short8*)&As[(m_off + i*16 + lm)*36 + lk*8];
    #pragma unroll
    for (int j = 0; j < 8; j++)
      bfr[j] = *(const short8*)&Vt[(o_off + j*16 + lm)*36 + lk*8];
    #pragma unroll
    for (int i = 0; i < 3; i++)
      #pragma unroll
      for (int j = 0; j < 8; j++)
        acc[i][j] = __builtin_amdgcn_mfma_f32_16x16x32_bf16(af[i], bfr[j], acc[i][j], 0, 0, 0);
    __syncthreads();
  }
  #pragma unroll
  for (int j = 0; j < 8; j++){
    int c = o_off + j*16 + lm;
    #pragma unroll
    for (int i = 0; i < 3; i++){
      int hbase = m_off + i*16 + lk*4;
      #pragma unroll
      for (int r = 0; r < 4; r++)
        accb[(((size_t)b*96 + w)*96 + hbase + r)*256 + c] = f2b(acc[i][j][r]);
    }
  }
}

// outW via MFMA + residual; grid (96 h, 8 b)
__global__ __launch_bounds__(256) void k_outW_mfma(const bf16* __restrict__ att,
                                                   const bf16* __restrict__ v_t,
                                                   const bf16* __restrict__ accb,
                                                   const float* __restrict__ gamma_p,
                                                   bf16* __restrict__ vf_t){
  int h = blockIdx.x, b = blockIdx.y, t = threadIdx.x;
  int lane = t & 63, wv = t >> 6;
  int m_off = (wv & 1)*48, o_off = (wv >> 1)*128;
  int lm = lane & 15, lk = lane >> 4;
  __shared__ __align__(16) bf16 As[96*36];
  __shared__ __align__(16) bf16 Vt[256*36];
  f32x4 acc[3][8] = {};
  for (int j0 = 0; j0 < 96; j0 += 32){
    for (int e = t; e < 384; e += 256){
      int wl = e >> 2, p = e & 3;
      *(uint4*)&As[wl*36 + p*8] =
        *(const uint4*)&att[(((size_t)b*96 + h)*96 + wl)*192 + 96 + j0 + p*8];
    }
    for (int e = t; e < 512; e += 256){
      int jj2 = (e & 15)*2, cg = e >> 4;
      const bf16* p = v_t + (((size_t)b*96 + j0 + jj2)*96 + h)*256 + cg*8;
      uint4 a0 = *(const uint4*)p;
      uint4 a1 = *(const uint4*)(p + 96*256);
      const unsigned short* u0 = (const unsigned short*)&a0;
      const unsigned short* u1 = (const unsigned short*)&a1;
      #pragma unroll
      for (int u = 0; u < 8; u++){
        ushort2 pr; pr.x = u0[u]; pr.y = u1[u];
        *(ushort2*)&Vt[(cg*8 + u)*36 + jj2] = pr;
      }
    }
    __syncthreads();
    short8 af[3], bfr[8];
    #pragma unroll
    for (int i = 0; i < 3; i++)
      af[i] = *(const short8*)&As[(m_off + i*16 + lm)*36 + lk*8];
    #pragma unroll
    for (int j = 0; j < 8; j++)
      bfr[j] = *(const short8*)&Vt[(o_off + j*16 + lm)*36 + lk*8];
    #pragma unroll
    for (int i = 0; i < 3; i++)
      #pragma unroll
      for (int j = 0; j < 8; j++)
        acc[i][j] = __builtin_amdgcn_mfma_f32_16x16x32_bf16(af[i], bfr[j], acc[i][j], 0, 0, 0);
    __syncthreads();
  }
  float g = gamma_p[0];
  #pragma unroll
  for (int j = 0; j < 8; j++){
    int c = o_off + j*16 + lm;
    #pragma unroll
    for (int i = 0; i < 3; i++){
      int wbase = m_off + i*16 + lk*4;
      #pragma unroll
      for (int r = 0; r < 4; r++){
        size_t idx = (((size_t)b*96 + wbase + r)*96 + h)*256 + c;
        vf_t[idx] = f2b(b2f(vf_t[idx]) + g*(acc[i][j][r] + b2f(accb[idx])));
      }
    }
  }
}

// ---------------------------------------------------------------------------
__global__ void k_bnprep(const float* __restrict__ s1, const float* __restrict__ s2,
                         const float* __restrict__ sc, const float* __restrict__ bi,
                         float2* __restrict__ ab){
  int co = blockIdx.x*256 + threadIdx.x;
  if (co >= 512) return;
  const float N = 73728.0f;
  float mean = s1[co] / N;
  float var  = s2[co] / N - mean*mean;
  if (var < 0.f) var = 0.f;
  float a = rsqrtf(var + 1e-5f) * sc[co];
  ab[co] = make_float2(a, bi[co] - mean*a);
}

// BN + relu + transpose (b,w,h,co) -> (b,co,h,w) fp32; grid (3, 96, 8)
// input loads vectorized uint4 (8 co/thread); LDS pad 65 (reads conflict-free)
__global__ __launch_bounds__(256) void k_bnout(const bf16* __restrict__ bt,
                                               const float2* __restrict__ ab,
                                               float* __restrict__ out){
  int w0 = blockIdx.x*32, h = blockIdx.y, b = blockIdx.z, t = threadIdx.x;
  __shared__ float Tl[32][65];
  int wl0 = t >> 3, cg0 = (t & 7)*8;
  for (int co0 = 0; co0 < 512; co0 += 64){
    uint4 d = *(const uint4*)&bt[(((size_t)b*96 + w0 + wl0)*96 + h)*512 + co0 + cg0];
    const unsigned short* us = (const unsigned short*)&d;
    #pragma unroll
    for (int u = 0; u < 8; u++)
      Tl[wl0][cg0 + u] = __uint_as_float(((unsigned)us[u]) << 16);
    __syncthreads();
    for (int e = t; e < 2048; e += 256){
      int co = e >> 5, wl = e & 31;
      float2 s = ab[co0 + co];
      float v = fmaxf(Tl[wl][co]*s.x + s.y, 0.0f);
      out[(((size_t)b*512 + co0 + co)*96 + h)*96 + w0 + wl] = v;
    }
    __syncthreads();
  }
}

// ---------------------------------------------------------------------------
extern "C" void kernel_launch(void* const* d_in, const int* in_sizes, int n_in,
                              void* d_out, int out_size, void* d_ws, size_t ws_size,
                              hipStream_t stream){
  (void)in_sizes; (void)n_in; (void)out_size; (void)ws_size;
  const float* low   = (const float*)d_in[0];
  const float* high  = (const float*)d_in[1];
  const float* c1w   = (const float*)d_in[2];
  const float* c1b   = (const float*)d_in[3];
  const float* c2w   = (const float*)d_in[4];
  const float* c2b   = (const float*)d_in[5];
  const float* qw    = (const float*)d_in[6];
  const float* qb    = (const float*)d_in[7];
  const float* kw    = (const float*)d_in[8];
  const float* kb    = (const float*)d_in[9];
  const float* vw    = (const float*)d_in[10];
  const float* vb    = (const float*)d_in[11];
  const float* gamma = (const float*)d_in[12];
  const float* bw    = (const float*)d_in[13];
  const float* bns   = (const float*)d_in[14];
  const float* bnb   = (const float*)d_in[15];
  float* out = (float*)d_out;

  char* wsb = (char*)d_ws;
  // workspace layout — total 223,027,328 bytes (~212.7 MB)
  bf16*   hf_t = (bf16*) (wsb + 0);            // 75,497,472  (b, x*96+y, 512)
  bf16*   vf_t = (bf16*) (wsb + 75497472);     // 37,748,736  (b, x*96+y, 256)
  bf16*   q_t  = (bf16*) (wsb + 113246208);    //  4,718,592
  bf16*   qq_wb= (bf16*) (wsb + 117964800);    //     32,768  (folded q weights, bf16 32x512)
  bf16*   wk   = (bf16*) (wsb + 117997568);    //     16,384  (k weights bf16, 32x256)
  float*  qq_b = (float*)(wsb + 118030336);    //        128
  float*  s1   = (float*)(wsb + 118030464);    //      2,048
  float*  s2   = (float*)(wsb + 118032512);    //      2,048
  float2* ab   = (float2*)(wsb + 118034560);   //      4,096
  bf16*   wbb  = (bf16*) (wsb + 118038656);    //    786,432  (bneck W bf16, 512x768)
  bf16*   wc2  = (bf16*) (wsb + 118825088);    //    262,144  (conv2 W bf16, 256x512)
  bf16*   wv   = (bf16*) (wsb + 119087232);    //    131,072  (v W bf16, 256x256)
  bf16*   v_t  = (bf16*) (wsb + 119218304);    // 37,748,736
  bf16*   att  = (bf16*) (wsb + 156967040);    // 28,311,552
  bf16*   accb = (bf16*) (wsb + 185278592);    // 37,748,736 -> ends 223,027,328
  bf16*   k_t  = (bf16*) (wsb + 185278592);    //  4,718,592 (aliases accb head; dead before accb written)
  bf16*   bt   = (bf16*) (wsb + 119218304);    // 75,497,472 (aliases v_t/att/accb-head; all dead at bneck)

  k_zero<<<4, 256, 0, stream>>>(s1);
  k_cvt<<<1536, 256, 0, stream>>>(bw,  wbb, 393216);
  k_cvt<<<512,  256, 0, stream>>>(c2w, wc2, 131072);
  k_cvt<<<256,  256, 0, stream>>>(vw,  wv,  65536);
  k_cvt<<<32,   256, 0, stream>>>(kw,  wk,  8192);
  k_upsample<<<dim3(96, 8), 256, 0, stream>>>(high, hf_t);
  k_qqw<<<64, 256, 0, stream>>>(qw, c1w, qq_wb);
  k_qqb<<<1, 64, 0, stream>>>(qw, c1b, qb, qq_b);
  k_mfma_gemm<<<dim3(72, 2, 8), 256, 0, stream>>>(hf_t, wc2, c2b, vf_t, 512, 256);
  k_qmfma<<<dim3(144, 8), 256, 0, stream>>>(low, qq_wb, qq_b, q_t);

  for (int r = 0; r < 2; r++){
    k_kmfma<<<dim3(72, 8), 256, 0, stream>>>(vf_t, wk, kb, k_t);
    k_mfma_gemm<<<dim3(72, 2, 8), 256, 0, stream>>>(vf_t, wv, vb, v_t, 256, 256);
    k_eH<<<dim3(96, 8), 256, 0, stream>>>(q_t, k_t, att);
    k_eW<<<dim3(96, 8), 256, 0, stream>>>(q_t, k_t, att);
    k_softmax<<<18432, 256, 0, stream>>>(att);
    k_outH_mfma<<<dim3(96, 8), 256, 0, stream>>>(att, v_t, accb);
    k_outW_mfma<<<dim3(96, 8), 256, 0, stream>>>(att, v_t, accb, gamma, vf_t);
  }

  k_bneck_mfma<<<dim3(72, 4, 8), 256, 0, stream>>>(vf_t, hf_t, wbb, bt, s1, s2);
  k_bnprep<<<2, 256, 0, stream>>>(s1, s2, bns, bnb, ab);
  k_bnout<<<dim3(3, 96, 8), 256, 0, stream>>>(bt, ab, out);
}

// Round 10
// 934.638 us; speedup vs baseline: 1.2914x; 1.0089x over previous
//
#include <hip/hip_runtime.h>
#include <hip/hip_bf16.h>

typedef __hip_bfloat16 bf16;
typedef __attribute__((ext_vector_type(8))) short short8;
typedef __attribute__((ext_vector_type(4))) float f32x4;

constexpr int kHW = 96 * 96;   // 9216

__device__ __forceinline__ float b2f(bf16 x){ return __bfloat162float(x); }
__device__ __forceinline__ bf16  f2b(float x){ return __float2bfloat16(x); }
__device__ __forceinline__ unsigned short b2u(bf16 x){ return *(unsigned short*)&x; }
__device__ __forceinline__ float s2f(short u){ return __uint_as_float(((unsigned)(unsigned short)u) << 16); }

// Swizzled LDS addressing for 32-element (64B) bf16 rows, 16B granules.
#define SW(r, g) ((r)*32 + ((((g) ^ (((r) >> 1) & 3))) << 3))

// NOTE: __builtin_amdgcn_global_load_lds is permanently abandoned in this
// session (3/3 fails with it). 3-stage prefetch also abandoned: r9 showed
// +8 VGPR -> occupancy 26.5->18.7% and bneck 110.5->113.8 (TLP loss > ILP gain).

// ---------------------------------------------------------------------------
__global__ void k_zero(float* __restrict__ p){
  int i = blockIdx.x*256 + threadIdx.x;
  if (i < 1024) p[i] = 0.0f;
}

__global__ void k_cvt(const float* __restrict__ s, bf16* __restrict__ d, int n){
  int i = blockIdx.x*256 + threadIdx.x;
  if (i < n) d[i] = f2b(s[i]);
}

// ---------------------------------------------------------------------------
// bilinear 2x upsample: high (b,512,48,48) fp32 -> hf_t (b, x96*96+y, c512) bf16
__global__ __launch_bounds__(256) void k_upsample(const float* __restrict__ hi,
                                                  bf16* __restrict__ hf_t){
  int y = blockIdx.x, b = blockIdx.y, t = threadIdx.x;
  int j = y >> 1;
  int j0, j1; float wy0, wy1;
  if ((y & 1) == 0){ j0 = j - 1; if (j0 < 0) j0 = 0; j1 = j; wy0 = 0.25f; wy1 = 0.75f; }
  else             { j0 = j; j1 = j + 1; if (j1 > 47) j1 = 47; wy0 = 0.75f; wy1 = 0.25f; }
  __shared__ __align__(16) float sm[2][128][49];
  for (int c0 = 0; c0 < 512; c0 += 128){
    for (int e = t; e < 2*128*48; e += 256){
      int cl = e / 96; int r = e % 96; int jj = r / 48; int i = r % 48;
      int row = jj ? j1 : j0;
      sm[jj][cl][i] = hi[(((size_t)b*512 + c0 + cl)*48 + row)*48 + i];
    }
    __syncthreads();
    for (int e = t; e < 96*128; e += 256){
      int x = e >> 7; int cl = e & 127;
      int i = x >> 1; int i0, i1; float wx0, wx1;
      if ((x & 1) == 0){ i0 = i - 1; if (i0 < 0) i0 = 0; i1 = i; wx0 = 0.25f; wx1 = 0.75f; }
      else             { i0 = i; i1 = i + 1; if (i1 > 47) i1 = 47; wx0 = 0.75f; wx1 = 0.25f; }
      float v = wy0*(wx0*sm[0][cl][i0] + wx1*sm[0][cl][i1])
              + wy1*(wx0*sm[1][cl][i0] + wx1*sm[1][cl][i1]);
      hf_t[(((size_t)b*96 + x)*96 + y)*512 + c0 + cl] = f2b(v);
    }
    __syncthreads();
  }
}

// ---------------------------------------------------------------------------
__global__ void k_qqw(const float* __restrict__ q_w, const float* __restrict__ c1_w,
                      bf16* __restrict__ qq_wb){
  int gid = blockIdx.x*256 + threadIdx.x;      // 16384
  int o = gid >> 9, c = gid & 511;
  float acc = 0.f;
  for (int k = 0; k < 256; k++) acc += q_w[o*256 + k] * c1_w[k*512 + c];
  qq_wb[gid] = f2b(acc);
}
__global__ void k_qqb(const float* __restrict__ q_w, const float* __restrict__ c1_b,
                      const float* __restrict__ q_b, float* __restrict__ qq_b){
  int o = threadIdx.x; if (o >= 32) return;
  float acc = q_b[o];
  for (int k = 0; k < 256; k++) acc += q_w[o*256 + k] * c1_b[k];
  qq_b[o] = acc;
}

// ---------------------------------------------------------------------------
// MFMA GEMM: 128x128 tile, 4 waves of 64x64, BK=32, 2-stage swizzled dbuf LDS
// (round-7 verified structure: bneck 110.5 us, 0 bank conflicts, VGPR 80)
__global__ __launch_bounds__(256) void k_mfma_gemm(const bf16* __restrict__ A,
                                                   const bf16* __restrict__ Wb,
                                                   const float* __restrict__ bias,
                                                   bf16* __restrict__ out,
                                                   int K, int O){
  int b = blockIdx.z, n0 = blockIdx.x*128, o0 = blockIdx.y*128;
  int t = threadIdx.x, lane = t & 63, wv = t >> 6;
  int m_off = (wv & 1)*64, o_off = (wv >> 1)*64;
  int lm = lane & 15, lk = lane >> 4;
  __shared__ __align__(16) bf16 As[2][128*32];
  __shared__ __align__(16) bf16 Ws[2][128*32];
  f32x4 acc[4][4] = {};
  const bf16* Ab = A + (size_t)b*kHW*K;
  int nl0 = t >> 2, gp = t & 3, p0 = gp*8;
  uint4 pa0, pa1, pw0, pw1;
  pa0 = *(const uint4*)&Ab[(size_t)(n0+nl0)*K + p0];
  pa1 = *(const uint4*)&Ab[(size_t)(n0+nl0+64)*K + p0];
  pw0 = *(const uint4*)&Wb[(size_t)(o0+nl0)*K + p0];
  pw1 = *(const uint4*)&Wb[(size_t)(o0+nl0+64)*K + p0];
  *(uint4*)&As[0][SW(nl0, gp)]    = pa0;
  *(uint4*)&As[0][SW(nl0+64, gp)] = pa1;
  *(uint4*)&Ws[0][SW(nl0, gp)]    = pw0;
  *(uint4*)&Ws[0][SW(nl0+64, gp)] = pw1;
  int cur = 0;
  int NS = K >> 5;
  for (int s = 0; s < NS; s++){
    if (s+1 < NS){
      int c0 = (s+1)*32;
      pa0 = *(const uint4*)&Ab[(size_t)(n0+nl0)*K + c0 + p0];
      pa1 = *(const uint4*)&Ab[(size_t)(n0+nl0+64)*K + c0 + p0];
      pw0 = *(const uint4*)&Wb[(size_t)(o0+nl0)*K + c0 + p0];
      pw1 = *(const uint4*)&Wb[(size_t)(o0+nl0+64)*K + c0 + p0];
    }
    __syncthreads();
    short8 af[4], bfr[4];
    #pragma unroll
    for (int i = 0; i < 4; i++){
      af[i]  = *(const short8*)&As[cur][SW(m_off + i*16 + lm, lk)];
      bfr[i] = *(const short8*)&Ws[cur][SW(o_off + i*16 + lm, lk)];
    }
    #pragma unroll
    for (int i = 0; i < 4; i++)
      #pragma unroll
      for (int j = 0; j < 4; j++)
        acc[i][j] = __builtin_amdgcn_mfma_f32_16x16x32_bf16(af[i], bfr[j], acc[i][j], 0, 0, 0);
    if (s+1 < NS){
      int nx = cur ^ 1;
      *(uint4*)&As[nx][SW(nl0, gp)]    = pa0;
      *(uint4*)&As[nx][SW(nl0+64, gp)] = pa1;
      *(uint4*)&Ws[nx][SW(nl0, gp)]    = pw0;
      *(uint4*)&Ws[nx][SW(nl0+64, gp)] = pw1;
      cur = nx;
    }
  }
  #pragma unroll
  for (int j = 0; j < 4; j++){
    int oc = o0 + o_off + j*16 + lm;
    float bs = bias ? bias[oc] : 0.0f;
    #pragma unroll
    for (int i = 0; i < 4; i++){
      int rbase = n0 + m_off + i*16 + lk*4;
      #pragma unroll
      for (int r = 0; r < 4; r++)
        out[((size_t)b*kHW + rbase + r)*(size_t)O + oc] = f2b(acc[i][j][r] + bs);
    }
  }
}

// bottleneck MFMA: K=768 split A-source; 2-stage swizzled dbuf; fused BN stats
__global__ __launch_bounds__(256) void k_bneck_mfma(const bf16* __restrict__ vf,
                                                    const bf16* __restrict__ hf,
                                                    const bf16* __restrict__ Wb,
                                                    bf16* __restrict__ out,
                                                    float* __restrict__ s1,
                                                    float* __restrict__ s2){
  int b = blockIdx.z, n0 = blockIdx.x*128, o0 = blockIdx.y*128;
  int t = threadIdx.x, lane = t & 63, wv = t >> 6;
  int m_off = (wv & 1)*64, o_off = (wv >> 1)*64;
  int lm = lane & 15, lk = lane >> 4;
  __shared__ __align__(16) bf16 As[2][128*32];
  __shared__ __align__(16) bf16 Ws[2][128*32];
  __shared__ float l1[128];
  __shared__ float l2[128];
  if (t < 128){ l1[t] = 0.f; l2[t] = 0.f; }
  f32x4 acc[4][4] = {};
  int nl0 = t >> 2, gp = t & 3, p0 = gp*8;
  const bf16* vfb = vf + (size_t)b*kHW*256;
  const bf16* hfb = hf + (size_t)b*kHW*512;
  uint4 pa0, pa1, pw0, pw1;
  pa0 = *(const uint4*)&vfb[(size_t)(n0+nl0)*256 + p0];
  pa1 = *(const uint4*)&vfb[(size_t)(n0+nl0+64)*256 + p0];
  pw0 = *(const uint4*)&Wb[(size_t)(o0+nl0)*768 + p0];
  pw1 = *(const uint4*)&Wb[(size_t)(o0+nl0+64)*768 + p0];
  *(uint4*)&As[0][SW(nl0, gp)]    = pa0;
  *(uint4*)&As[0][SW(nl0+64, gp)] = pa1;
  *(uint4*)&Ws[0][SW(nl0, gp)]    = pw0;
  *(uint4*)&Ws[0][SW(nl0+64, gp)] = pw1;
  int cur = 0;
  for (int s = 0; s < 24; s++){
    if (s+1 < 24){
      int c0 = (s+1)*32;
      if (c0 < 256){
        pa0 = *(const uint4*)&vfb[(size_t)(n0+nl0)*256 + c0 + p0];
        pa1 = *(const uint4*)&vfb[(size_t)(n0+nl0+64)*256 + c0 + p0];
      } else {
        int cc = c0 - 256;
        pa0 = *(const uint4*)&hfb[(size_t)(n0+nl0)*512 + cc + p0];
        pa1 = *(const uint4*)&hfb[(size_t)(n0+nl0+64)*512 + cc + p0];
      }
      pw0 = *(const uint4*)&Wb[(size_t)(o0+nl0)*768 + c0 + p0];
      pw1 = *(const uint4*)&Wb[(size_t)(o0+nl0+64)*768 + c0 + p0];
    }
    __syncthreads();
    short8 af[4], bfr[4];
    #pragma unroll
    for (int i = 0; i < 4; i++){
      af[i]  = *(const short8*)&As[cur][SW(m_off + i*16 + lm, lk)];
      bfr[i] = *(const short8*)&Ws[cur][SW(o_off + i*16 + lm, lk)];
    }
    #pragma unroll
    for (int i = 0; i < 4; i++)
      #pragma unroll
      for (int j = 0; j < 4; j++)
        acc[i][j] = __builtin_amdgcn_mfma_f32_16x16x32_bf16(af[i], bfr[j], acc[i][j], 0, 0, 0);
    if (s+1 < 24){
      int nx = cur ^ 1;
      *(uint4*)&As[nx][SW(nl0, gp)]    = pa0;
      *(uint4*)&As[nx][SW(nl0+64, gp)] = pa1;
      *(uint4*)&Ws[nx][SW(nl0, gp)]    = pw0;
      *(uint4*)&Ws[nx][SW(nl0+64, gp)] = pw1;
      cur = nx;
    }
  }
  #pragma unroll
  for (int j = 0; j < 4; j++){
    int oc = o0 + o_off + j*16 + lm;
    float p1 = 0.f, p2 = 0.f;
    #pragma unroll
    for (int i = 0; i < 4; i++){
      int rbase = n0 + m_off + i*16 + lk*4;
      #pragma unroll
      for (int r = 0; r < 4; r++){
        float v = acc[i][j][r];
        p1 += v; p2 += v*v;
        out[((size_t)b*kHW + rbase + r)*512 + oc] = f2b(v);
      }
    }
    int cl = o_off + j*16 + lm;
    atomicAdd(&l1[cl], p1);
    atomicAdd(&l2[cl], p2);
  }
  __syncthreads();
  if (t < 128){
    atomicAdd(&s1[o0 + t], l1[t]);
    atomicAdd(&s2[o0 + t], l2[t]);
  }
}

// ---------------------------------------------------------------------------
// q via MFMA: q_t[b,x,h,o] = sum_c low[b,c,n]*qqw[o,c] + qq_b[o], n = h*96+x
__global__ __launch_bounds__(256) void k_qmfma(const float* __restrict__ low,
                                               const bf16* __restrict__ qq_wb,
                                               const float* __restrict__ qq_b,
                                               bf16* __restrict__ q_t){
  int n0 = blockIdx.x*64, b = blockIdx.y, t = threadIdx.x;
  int lane = t & 63, wv = t >> 6;
  int m_off = wv*16;
  int lm = lane & 15, lk = lane >> 4;
  __shared__ __align__(16) bf16 As[64*36];
  __shared__ __align__(16) bf16 Ws[32*40];
  f32x4 acc[2] = {};
  const float* low_b = low + (size_t)b*512*kHW;
  int c2 = (t & 15)*2;
  int xg = t >> 4;
  for (int c0 = 0; c0 < 512; c0 += 32){
    const float* p0 = low_b + (size_t)(c0 + c2)*kHW + n0 + xg*4;
    float4 a0 = *(const float4*)p0;
    float4 a1 = *(const float4*)(p0 + kHW);
    float f0[4] = {a0.x, a0.y, a0.z, a0.w};
    float f1[4] = {a1.x, a1.y, a1.z, a1.w};
    #pragma unroll
    for (int u = 0; u < 4; u++){
      ushort2 pr;
      bf16 v0 = f2b(f0[u]), v1 = f2b(f1[u]);
      pr.x = b2u(v0); pr.y = b2u(v1);
      *(ushort2*)&As[(xg*4 + u)*36 + c2] = pr;
    }
    if (t < 128){
      int ol = t >> 2, p = t & 3;
      *(uint4*)&Ws[ol*40 + p*8] = *(const uint4*)&qq_wb[(size_t)ol*512 + c0 + p*8];
    }
    __syncthreads();
    short8 af = *(const short8*)&As[(m_off + lm)*36 + lk*8];
    short8 b0 = *(const short8*)&Ws[lm*40 + lk*8];
    short8 b1 = *(const short8*)&Ws[(16 + lm)*40 + lk*8];
    acc[0] = __builtin_amdgcn_mfma_f32_16x16x32_bf16(af, b0, acc[0], 0, 0, 0);
    acc[1] = __builtin_amdgcn_mfma_f32_16x16x32_bf16(af, b1, acc[1], 0, 0, 0);
    __syncthreads();
  }
  #pragma unroll
  for (int j = 0; j < 2; j++){
    int oc = j*16 + lm;
    float bs = qq_b[oc];
    #pragma unroll
    for (int r = 0; r < 4; r++){
      int ng = n0 + m_off + lk*4 + r;
      int h = ng / 96, x = ng - h*96;
      q_t[(((size_t)b*96 + x)*96 + h)*32 + oc] = f2b(acc[j][r] + bs);
    }
  }
}

// ---------------------------------------------------------------------------
// k-projection via MFMA: O=32, K=256; swizzled dbuf LDS
__global__ __launch_bounds__(256) void k_kmfma(const bf16* __restrict__ A,
                                               const bf16* __restrict__ Wk,
                                               const float* __restrict__ bias,
                                               bf16* __restrict__ out){
  int n0 = blockIdx.x*128, b = blockIdx.y;
  int t = threadIdx.x, lane = t & 63, wv = t >> 6;
  int m_off = wv*32;
  int lm = lane & 15, lk = lane >> 4;
  __shared__ __align__(16) bf16 As[2][128*32];
  __shared__ __align__(16) bf16 Ws[2][32*32];
  f32x4 acc[2][2] = {};
  const bf16* Ab = A + (size_t)b*kHW*256;
  int nl0 = t >> 2, gp = t & 3, p0 = gp*8;
  int ol = t >> 2;
  uint4 pa0, pa1, pw;
  pa0 = *(const uint4*)&Ab[(size_t)(n0+nl0)*256 + p0];
  pa1 = *(const uint4*)&Ab[(size_t)(n0+nl0+64)*256 + p0];
  if (t < 128) pw = *(const uint4*)&Wk[(size_t)ol*256 + p0];
  *(uint4*)&As[0][SW(nl0, gp)]    = pa0;
  *(uint4*)&As[0][SW(nl0+64, gp)] = pa1;
  if (t < 128) *(uint4*)&Ws[0][SW(ol, gp)] = pw;
  int cur = 0;
  for (int s = 0; s < 8; s++){
    if (s+1 < 8){
      int c0 = (s+1)*32;
      pa0 = *(const uint4*)&Ab[(size_t)(n0+nl0)*256 + c0 + p0];
      pa1 = *(const uint4*)&Ab[(size_t)(n0+nl0+64)*256 + c0 + p0];
      if (t < 128) pw = *(const uint4*)&Wk[(size_t)ol*256 + c0 + p0];
    }
    __syncthreads();
    short8 af[2], bfr[2];
    #pragma unroll
    for (int i = 0; i < 2; i++)
      af[i] = *(const short8*)&As[cur][SW(m_off + i*16 + lm, lk)];
    #pragma unroll
    for (int j = 0; j < 2; j++)
      bfr[j] = *(const short8*)&Ws[cur][SW(j*16 + lm, lk)];
    #pragma unroll
    for (int i = 0; i < 2; i++)
      #pragma unroll
      for (int j = 0; j < 2; j++)
        acc[i][j] = __builtin_amdgcn_mfma_f32_16x16x32_bf16(af[i], bfr[j], acc[i][j], 0, 0, 0);
    if (s+1 < 8){
      int nx = cur ^ 1;
      *(uint4*)&As[nx][SW(nl0, gp)]    = pa0;
      *(uint4*)&As[nx][SW(nl0+64, gp)] = pa1;
      if (t < 128) *(uint4*)&Ws[nx][SW(ol, gp)] = pw;
      cur = nx;
    }
  }
  #pragma unroll
  for (int j = 0; j < 2; j++){
    int oc = j*16 + lm;
    float bs = bias[oc];
    #pragma unroll
    for (int i = 0; i < 2; i++){
      int rbase = n0 + m_off + i*16 + lk*4;
      #pragma unroll
      for (int r = 0; r < 4; r++)
        out[((size_t)b*kHW + rbase + r)*32 + oc] = f2b(acc[i][j][r] + bs);
    }
  }
}

// ---------------------------------------------------------------------------
// eH: att[b,h,w,j] = sum_c q_t[b,w,h,c]*k_t[b,w,j,c]  (-1e9 if j==h); grid (96 w, 8 b)
__global__ __launch_bounds__(256) void k_eH(const bf16* __restrict__ q_t,
                                            const bf16* __restrict__ k_t,
                                            bf16* __restrict__ att){
  int w = blockIdx.x, b = blockIdx.y, t = threadIdx.x;
  __shared__ __align__(16) float Qs[96][36];
  __shared__ __align__(16) float Ks[96][36];
  const bf16* Qp = q_t + (((size_t)b*96 + w)*96)*32;
  const bf16* Kp = k_t + (((size_t)b*96 + w)*96)*32;
  for (int e = t; e < 384; e += 256){
    int row = e >> 2, cg = (e & 3)*8;
    short8 qv = *(const short8*)&Qp[row*32 + cg];
    short8 kv = *(const short8*)&Kp[row*32 + cg];
    float4 q0 = {s2f(qv[0]), s2f(qv[1]), s2f(qv[2]), s2f(qv[3])};
    float4 q1 = {s2f(qv[4]), s2f(qv[5]), s2f(qv[6]), s2f(qv[7])};
    float4 k0 = {s2f(kv[0]), s2f(kv[1]), s2f(kv[2]), s2f(kv[3])};
    float4 k1 = {s2f(kv[4]), s2f(kv[5]), s2f(kv[6]), s2f(kv[7])};
    *(float4*)&Qs[row][cg]     = q0;
    *(float4*)&Qs[row][cg + 4] = q1;
    *(float4*)&Ks[row][cg]     = k0;
    *(float4*)&Ks[row][cg + 4] = k1;
  }
  __syncthreads();
  int tj = t % 16, th = t / 16;
  float acc[6][6] = {};
  #pragma unroll 4
  for (int c = 0; c < 32; c++){
    float qa[6], kb[6];
    #pragma unroll
    for (int i = 0; i < 6; i++) qa[i] = Qs[th*6 + i][c];
    #pragma unroll
    for (int jj = 0; jj < 6; jj++) kb[jj] = Ks[tj*6 + jj][c];
    #pragma unroll
    for (int i = 0; i < 6; i++)
      #pragma unroll
      for (int jj = 0; jj < 6; jj++) acc[i][jj] += qa[i]*kb[jj];
  }
  #pragma unroll
  for (int i = 0; i < 6; i++){
    int h = th*6 + i;
    size_t base = (((size_t)b*96 + h)*96 + w)*192;
    #pragma unroll
    for (int jj = 0; jj < 6; jj++){
      int jg = tj*6 + jj;
      float e = acc[i][jj];
      if (jg == h) e += -1000000000.0f;
      att[base + jg] = f2b(e);
    }
  }
}

// eW: att[b,h,w,96+j] = sum_c q_t[b,w,h,c]*k_t[b,j,h,c]; grid (96 h, 8 b)
__global__ __launch_bounds__(256) void k_eW(const bf16* __restrict__ q_t,
                                            const bf16* __restrict__ k_t,
                                            bf16* __restrict__ att){
  int h = blockIdx.x, b = blockIdx.y, t = threadIdx.x;
  __shared__ __align__(16) float Qs[96][36];
  __shared__ __align__(16) float Ks[96][36];
  for (int e = t; e < 384; e += 256){
    int wl = e >> 2, cg = (e & 3)*8;
    size_t idx = (((size_t)b*96 + wl)*96 + h)*32 + cg;
    short8 qv = *(const short8*)&q_t[idx];
    short8 kv = *(const short8*)&k_t[idx];
    float4 q0 = {s2f(qv[0]), s2f(qv[1]), s2f(qv[2]), s2f(qv[3])};
    float4 q1 = {s2f(qv[4]), s2f(qv[5]), s2f(qv[6]), s2f(qv[7])};
    float4 k0 = {s2f(kv[0]), s2f(kv[1]), s2f(kv[2]), s2f(kv[3])};
    float4 k1 = {s2f(kv[4]), s2f(kv[5]), s2f(kv[6]), s2f(kv[7])};
    *(float4*)&Qs[wl][cg]     = q0;
    *(float4*)&Qs[wl][cg + 4] = q1;
    *(float4*)&Ks[wl][cg]     = k0;
    *(float4*)&Ks[wl][cg + 4] = k1;
  }
  __syncthreads();
  int tj = t % 16, tw = t / 16;
  float acc[6][6] = {};
  #pragma unroll 4
  for (int c = 0; c < 32; c++){
    float qa[6], kb[6];
    #pragma unroll
    for (int i = 0; i < 6; i++) qa[i] = Qs[tw*6 + i][c];
    #pragma unroll
    for (int jj = 0; jj < 6; jj++) kb[jj] = Ks[tj*6 + jj][c];
    #pragma unroll
    for (int i = 0; i < 6; i++)
      #pragma unroll
      for (int jj = 0; jj < 6; jj++) acc[i][jj] += qa[i]*kb[jj];
  }
  #pragma unroll
  for (int i = 0; i < 6; i++){
    int wl = tw*6 + i;
    size_t base = (((size_t)b*96 + h)*96 + wl)*192 + 96;
    #pragma unroll
    for (int jj = 0; jj < 6; jj++) att[base + tj*6 + jj] = f2b(acc[i][jj]);
  }
}

// softmax over 192, one wave per row; grid 18432 (fallback path)
__global__ __launch_bounds__(256) void k_softmax(bf16* __restrict__ att){
  int t = threadIdx.x;
  int row = blockIdx.x*4 + (t >> 6);
  int lane = t & 63;
  size_t base = (size_t)row * 192;
  float x0 = b2f(att[base + lane]);
  float x1 = b2f(att[base + 64 + lane]);
  float x2 = b2f(att[base + 128 + lane]);
  float m = fmaxf(x0, fmaxf(x1, x2));
  #pragma unroll
  for (int off = 32; off; off >>= 1) m = fmaxf(m, __shfl_xor(m, off));
  float e0 = __expf(x0 - m), e1 = __expf(x1 - m), e2 = __expf(x2 - m);
  float s = e0 + e1 + e2;
  #pragma unroll
  for (int off = 32; off; off >>= 1) s += __shfl_xor(s, off);
  float inv = 1.0f / s;
  att[base + lane]       = f2b(e0 * inv);
  att[base + 64 + lane]  = f2b(e1 * inv);
  att[base + 128 + lane] = f2b(e2 * inv);
}

// row stats only: rstat[row] = (max, 1/sum); att left as raw scores
__global__ __launch_bounds__(256) void k_rowstat(const bf16* __restrict__ att,
                                                 float2* __restrict__ rstat){
  int t = threadIdx.x;
  int row = blockIdx.x*4 + (t >> 6);
  int lane = t & 63;
  size_t base = (size_t)row * 192;
  float x0 = b2f(att[base + lane]);
  float x1 = b2f(att[base + 64 + lane]);
  float x2 = b2f(att[base + 128 + lane]);
  float m = fmaxf(x0, fmaxf(x1, x2));
  #pragma unroll
  for (int off = 32; off; off >>= 1) m = fmaxf(m, __shfl_xor(m, off));
  float s = __expf(x0 - m) + __expf(x1 - m) + __expf(x2 - m);
  #pragma unroll
  for (int off = 32; off; off >>= 1) s += __shfl_xor(s, off);
  if (lane == 0) rstat[row] = make_float2(m, 1.0f / s);
}

// ---------------------------------------------------------------------------
// outH via MFMA: accb[b,w,h,c] = sum_j p[b,h,w,j]*v_t[b,w,j,c]; grid (96 w, 8 b)
// RS: att holds raw scores; apply p = exp(x-m)*inv during LDS staging.
template<bool RS>
__global__ __launch_bounds__(256) void k_outH_mfma(const bf16* __restrict__ att,
                                                   const bf16* __restrict__ v_t,
                                                   const float2* __restrict__ rstat,
                                                   bf16* __restrict__ accb){
  int w = blockIdx.x, b = blockIdx.y, t = threadIdx.x;
  int lane = t & 63, wv = t >> 6;
  int m_off = (wv & 1)*48, o_off = (wv >> 1)*128;
  int lm = lane & 15, lk = lane >> 4;
  __shared__ __align__(16) bf16 As[96*36];
  __shared__ __align__(16) bf16 Vt[256*36];
  __shared__ float2 Ls[96];
  if (RS){
    if (t < 96) Ls[t] = rstat[((size_t)b*96 + t)*96 + w];
    __syncthreads();
  }
  f32x4 acc[3][8] = {};
  const bf16* Vb = v_t + ((size_t)b*96 + w)*96*256;
  for (int j0 = 0; j0 < 96; j0 += 32){
    for (int e = t; e < 384; e += 256){
      int h = e >> 2, p = e & 3;
      const bf16* src = &att[(((size_t)b*96 + h)*96 + w)*192 + j0 + p*8];
      if (RS){
        short8 rv = *(const short8*)src;
        float2 st = Ls[h];
        short8 ov;
        #pragma unroll
        for (int u = 0; u < 8; u++)
          ov[u] = (short)b2u(f2b(__expf(s2f(rv[u]) - st.x) * st.y));
        *(short8*)&As[h*36 + p*8] = ov;
      } else {
        *(uint4*)&As[h*36 + p*8] = *(const uint4*)src;
      }
    }
    for (int e = t; e < 512; e += 256){
      int jj2 = (e & 15)*2, cg = e >> 4;
      const bf16* p = Vb + (size_t)(j0 + jj2)*256 + cg*8;
      uint4 a0 = *(const uint4*)p;
      uint4 a1 = *(const uint4*)(p + 256);
      const unsigned short* u0 = (const unsigned short*)&a0;
      const unsigned short* u1 = (const unsigned short*)&a1;
      #pragma unroll
      for (int u = 0; u < 8; u++){
        ushort2 pr; pr.x = u0[u]; pr.y = u1[u];
        *(ushort2*)&Vt[(cg*8 + u)*36 + jj2] = pr;
      }
    }
    __syncthreads();
    short8 af[3], bfr[8];
    #pragma unroll
    for (int i = 0; i < 3; i++)
      af[i] = *(const short8*)&As[(m_off + i*16 + lm)*36 + lk*8];
    #pragma unroll
    for (int j = 0; j < 8; j++)
      bfr[j] = *(const short8*)&Vt[(o_off + j*16 + lm)*36 + lk*8];
    #pragma unroll
    for (int i = 0; i < 3; i++)
      #pragma unroll
      for (int j = 0; j < 8; j++)
        acc[i][j] = __builtin_amdgcn_mfma_f32_16x16x32_bf16(af[i], bfr[j], acc[i][j], 0, 0, 0);
    __syncthreads();
  }
  #pragma unroll
  for (int j = 0; j < 8; j++){
    int c = o_off + j*16 + lm;
    #pragma unroll
    for (int i = 0; i < 3; i++){
      int hbase = m_off + i*16 + lk*4;
      #pragma unroll
      for (int r = 0; r < 4; r++)
        accb[(((size_t)b*96 + w)*96 + hbase + r)*256 + c] = f2b(acc[i][j][r]);
    }
  }
}

// outW via MFMA + residual; grid (96 h, 8 b)
template<bool RS>
__global__ __launch_bounds__(256) void k_outW_mfma(const bf16* __restrict__ att,
                                                   const bf16* __restrict__ v_t,
                                                   const float2* __restrict__ rstat,
                                                   const bf16* __restrict__ accb,
                                                   const float* __restrict__ gamma_p,
                                                   bf16* __restrict__ vf_t){
  int h = blockIdx.x, b = blockIdx.y, t = threadIdx.x;
  int lane = t & 63, wv = t >> 6;
  int m_off = (wv & 1)*48, o_off = (wv >> 1)*128;
  int lm = lane & 15, lk = lane >> 4;
  __shared__ __align__(16) bf16 As[96*36];
  __shared__ __align__(16) bf16 Vt[256*36];
  __shared__ float2 Ls[96];
  if (RS){
    if (t < 96) Ls[t] = rstat[((size_t)b*96 + h)*96 + t];
    __syncthreads();
  }
  f32x4 acc[3][8] = {};
  for (int j0 = 0; j0 < 96; j0 += 32){
    for (int e = t; e < 384; e += 256){
      int wl = e >> 2, p = e & 3;
      const bf16* src = &att[(((size_t)b*96 + h)*96 + wl)*192 + 96 + j0 + p*8];
      if (RS){
        short8 rv = *(const short8*)src;
        float2 st = Ls[wl];
        short8 ov;
        #pragma unroll
        for (int u = 0; u < 8; u++)
          ov[u] = (short)b2u(f2b(__expf(s2f(rv[u]) - st.x) * st.y));
        *(short8*)&As[wl*36 + p*8] = ov;
      } else {
        *(uint4*)&As[wl*36 + p*8] = *(const uint4*)src;
      }
    }
    for (int e = t; e < 512; e += 256){
      int jj2 = (e & 15)*2, cg = e >> 4;
      const bf16* p = v_t + (((size_t)b*96 + j0 + jj2)*96 + h)*256 + cg*8;
      uint4 a0 = *(const uint4*)p;
      uint4 a1 = *(const uint4*)(p + 96*256);
      const unsigned short* u0 = (const unsigned short*)&a0;
      const unsigned short* u1 = (const unsigned short*)&a1;
      #pragma unroll
      for (int u = 0; u < 8; u++){
        ushort2 pr; pr.x = u0[u]; pr.y = u1[u];
        *(ushort2*)&Vt[(cg*8 + u)*36 + jj2] = pr;
      }
    }
    __syncthreads();
    short8 af[3], bfr[8];
    #pragma unroll
    for (int i = 0; i < 3; i++)
      af[i] = *(const short8*)&As[(m_off + i*16 + lm)*36 + lk*8];
    #pragma unroll
    for (int j = 0; j < 8; j++)
      bfr[j] = *(const short8*)&Vt[(o_off + j*16 + lm)*36 + lk*8];
    #pragma unroll
    for (int i = 0; i < 3; i++)
      #pragma unroll
      for (int j = 0; j < 8; j++)
        acc[i][j] = __builtin_amdgcn_mfma_f32_16x16x32_bf16(af[i], bfr[j], acc[i][j], 0, 0, 0);
    __syncthreads();
  }
  float g = gamma_p[0];
  #pragma unroll
  for (int j = 0; j < 8; j++){
    int c = o_off + j*16 + lm;
    #pragma unroll
    for (int i = 0; i < 3; i++){
      int wbase = m_off + i*16 + lk*4;
      #pragma unroll
      for (int r = 0; r < 4; r++){
        size_t idx = (((size_t)b*96 + wbase + r)*96 + h)*256 + c;
        vf_t[idx] = f2b(b2f(vf_t[idx]) + g*(acc[i][j][r] + b2f(accb[idx])));
      }
    }
  }
}

// ---------------------------------------------------------------------------
__global__ void k_bnprep(const float* __restrict__ s1, const float* __restrict__ s2,
                         const float* __restrict__ sc, const float* __restrict__ bi,
                         float2* __restrict__ ab){
  int co = blockIdx.x*256 + threadIdx.x;
  if (co >= 512) return;
  const float N = 73728.0f;
  float mean = s1[co] / N;
  float var  = s2[co] / N - mean*mean;
  if (var < 0.f) var = 0.f;
  float a = rsqrtf(var + 1e-5f) * sc[co];
  ab[co] = make_float2(a, bi[co] - mean*a);
}

// BN + relu + transpose (b,w,h,co) -> (b,co,h,w) fp32; grid (3, 96, 8)
__global__ __launch_bounds__(256) void k_bnout(const bf16* __restrict__ bt,
                                               const float2* __restrict__ ab,
                                               float* __restrict__ out){
  int w0 = blockIdx.x*32, h = blockIdx.y, b = blockIdx.z, t = threadIdx.x;
  __shared__ float Tl[32][65];
  int wl0 = t >> 3, cg0 = (t & 7)*8;
  for (int co0 = 0; co0 < 512; co0 += 64){
    uint4 d = *(const uint4*)&bt[(((size_t)b*96 + w0 + wl0)*96 + h)*512 + co0 + cg0];
    const unsigned short* us = (const unsigned short*)&d;
    #pragma unroll
    for (int u = 0; u < 8; u++)
      Tl[wl0][cg0 + u] = __uint_as_float(((unsigned)us[u]) << 16);
    __syncthreads();
    for (int e = t; e < 2048; e += 256){
      int co = e >> 5, wl = e & 31;
      float2 s = ab[co0 + co];
      float v = fmaxf(Tl[wl][co]*s.x + s.y, 0.0f);
      out[(((size_t)b*512 + co0 + co)*96 + h)*96 + w0 + wl] = v;
    }
    __syncthreads();
  }
}

// ---------------------------------------------------------------------------
extern "C" void kernel_launch(void* const* d_in, const int* in_sizes, int n_in,
                              void* d_out, int out_size, void* d_ws, size_t ws_size,
                              hipStream_t stream){
  (void)in_sizes; (void)n_in; (void)out_size;
  const float* low   = (const float*)d_in[0];
  const float* high  = (const float*)d_in[1];
  const float* c1w   = (const float*)d_in[2];
  const float* c1b   = (const float*)d_in[3];
  const float* c2w   = (const float*)d_in[4];
  const float* c2b   = (const float*)d_in[5];
  const float* qw    = (const float*)d_in[6];
  const float* qb    = (const float*)d_in[7];
  const float* kw    = (const float*)d_in[8];
  const float* kb    = (const float*)d_in[9];
  const float* vw    = (const float*)d_in[10];
  const float* vb    = (const float*)d_in[11];
  const float* gamma = (const float*)d_in[12];
  const float* bw    = (const float*)d_in[13];
  const float* bns   = (const float*)d_in[14];
  const float* bnb   = (const float*)d_in[15];
  float* out = (float*)d_out;

  char* wsb = (char*)d_ws;
  // workspace layout — base 223,027,328 bytes (~212.7 MB); rstat optional tail
  bf16*   hf_t = (bf16*) (wsb + 0);            // 75,497,472  (b, x*96+y, 512)
  bf16*   vf_t = (bf16*) (wsb + 75497472);     // 37,748,736  (b, x*96+y, 256)
  bf16*   q_t  = (bf16*) (wsb + 113246208);    //  4,718,592
  bf16*   qq_wb= (bf16*) (wsb + 117964800);    //     32,768  (folded q weights, bf16 32x512)
  bf16*   wk   = (bf16*) (wsb + 117997568);    //     16,384  (k weights bf16, 32x256)
  float*  qq_b = (float*)(wsb + 118030336);    //        128
  float*  s1   = (float*)(wsb + 118030464);    //      2,048
  float*  s2   = (float*)(wsb + 118032512);    //      2,048
  float2* ab   = (float2*)(wsb + 118034560);   //      4,096
  bf16*   wbb  = (bf16*) (wsb + 118038656);    //    786,432  (bneck W bf16, 512x768)
  bf16*   wc2  = (bf16*) (wsb + 118825088);    //    262,144  (conv2 W bf16, 256x512)
  bf16*   wv   = (bf16*) (wsb + 119087232);    //    131,072  (v W bf16, 256x256)
  bf16*   v_t  = (bf16*) (wsb + 119218304);    // 37,748,736
  bf16*   att  = (bf16*) (wsb + 156967040);    // 28,311,552
  bf16*   accb = (bf16*) (wsb + 185278592);    // 37,748,736 -> ends 223,027,328
  bf16*   k_t  = (bf16*) (wsb + 185278592);    //  4,718,592 (aliases accb head; dead before accb written)
  bf16*   bt   = (bf16*) (wsb + 119218304);    // 75,497,472 (aliases v_t/att/accb-head; all dead at bneck)
  const size_t RS_OFF = 223027328;
  float2* rstat = (float2*)(wsb + RS_OFF);     //    589,824 (optional, if ws_size allows)
  bool have_rs = ws_size >= RS_OFF + 73728*sizeof(float2);

  k_zero<<<4, 256, 0, stream>>>(s1);
  k_cvt<<<1536, 256, 0, stream>>>(bw,  wbb, 393216);
  k_cvt<<<512,  256, 0, stream>>>(c2w, wc2, 131072);
  k_cvt<<<256,  256, 0, stream>>>(vw,  wv,  65536);
  k_cvt<<<32,   256, 0, stream>>>(kw,  wk,  8192);
  k_upsample<<<dim3(96, 8), 256, 0, stream>>>(high, hf_t);
  k_qqw<<<64, 256, 0, stream>>>(qw, c1w, qq_wb);
  k_qqb<<<1, 64, 0, stream>>>(qw, c1b, qb, qq_b);
  k_mfma_gemm<<<dim3(72, 2, 8), 256, 0, stream>>>(hf_t, wc2, c2b, vf_t, 512, 256);
  k_qmfma<<<dim3(144, 8), 256, 0, stream>>>(low, qq_wb, qq_b, q_t);

  for (int r = 0; r < 2; r++){
    k_kmfma<<<dim3(72, 8), 256, 0, stream>>>(vf_t, wk, kb, k_t);
    k_mfma_gemm<<<dim3(72, 2, 8), 256, 0, stream>>>(vf_t, wv, vb, v_t, 256, 256);
    k_eH<<<dim3(96, 8), 256, 0, stream>>>(q_t, k_t, att);
    k_eW<<<dim3(96, 8), 256, 0, stream>>>(q_t, k_t, att);
    if (have_rs){
      k_rowstat<<<18432, 256, 0, stream>>>(att, rstat);
      k_outH_mfma<true><<<dim3(96, 8), 256, 0, stream>>>(att, v_t, rstat, accb);
      k_outW_mfma<true><<<dim3(96, 8), 256, 0, stream>>>(att, v_t, rstat, accb, gamma, vf_t);
    } else {
      k_softmax<<<18432, 256, 0, stream>>>(att);
      k_outH_mfma<false><<<dim3(96, 8), 256, 0, stream>>>(att, v_t, nullptr, accb);
      k_outW_mfma<false><<<dim3(96, 8), 256, 0, stream>>>(att, v_t, nullptr, accb, gamma, vf_t);
    }
  }

  k_bneck_mfma<<<dim3(72, 4, 8), 256, 0, stream>>>(vf_t, hf_t, wbb, bt, s1, s2);
  k_bnprep<<<2, 256, 0, stream>>>(s1, s2, bns, bnb, ab);
  k_bnout<<<dim3(3, 96, 8), 256, 0, stream>>>(bt, ab, out);
}